// Round 9
// baseline (901.924 us; speedup 1.0000x reference)
//
#include <hip/hip_runtime.h>
#include <math.h>

#define BB 512
#define SS 200
#define DDIM 64
#define HD 32
#define LL 2
#define NROWS (BB * SS)   // 102400
#define EPS 1e-8f
#define CC 0.001f
#define GRAM_NB 256

// ---------------- static device buffers (activations) ----------------
__device__ float g_x[NROWS * DDIM];
__device__ float g_qin[NROWS * DDIM];
__device__ float g_q[NROWS * DDIM];
__device__ float g_k[NROWS * DDIM];
__device__ float g_v[NROWS * DDIM];
__device__ float g_ctx[NROWS * DDIM];
__device__ float g_gpart[GRAM_NB * 4096];   // gram per-block partials

// ---------------- helpers ----------------
__device__ __forceinline__ float wave_sum(float v) {
#pragma unroll
    for (int o = 32; o > 0; o >>= 1) v += __shfl_xor(v, o, 64);
    return v;
}
__device__ __forceinline__ float wave_max(float v) {
#pragma unroll
    for (int o = 32; o > 0; o >>= 1) v = fmaxf(v, __shfl_xor(v, o, 64));
    return v;
}

// bf16 pack (RNE)
__device__ __forceinline__ unsigned short f2b(float f) {
    unsigned u = __float_as_uint(f);
    return (unsigned short)((u + 0x7FFFu + ((u >> 16) & 1u)) >> 16);
}

// ---------------- embedding (float4) ----------------
__global__ __launch_bounds__(256) void embed_kernel(const int* __restrict__ log_seqs,
                                                    const float* __restrict__ item_emb,
                                                    const float* __restrict__ pos_emb,
                                                    float* __restrict__ x) {
    int tid = blockIdx.x * 256 + threadIdx.x;   // over NROWS*16
    int row = tid >> 4, q4 = tid & 15;
    int s = row % SS;
    int li = log_seqs[row];
    int poss = li ? (s + 1) : 0;
    float4 e = *(const float4*)&item_emb[li * DDIM + q4 * 4];
    float4 p = *(const float4*)&pos_emb[poss * DDIM + q4 * 4];
    float4 o;
    o.x = e.x * 8.0f + p.x; o.y = e.y * 8.0f + p.y;
    o.z = e.z * 8.0f + p.z; o.w = e.w * 8.0f + p.w;
    *(float4*)&x[row * DDIM + q4 * 4] = o;
}

// ---------------- tile staging helpers ----------------
__device__ __forceinline__ void stage_in(const float* __restrict__ G, float (* __restrict__ tile)[68],
                                         int t, long row0) {
#pragma unroll
    for (int rep = 0; rep < 4; ++rep) {
        int idx = t + rep * 256;
        int c = idx >> 4, d4 = (idx & 15) * 4;
        *(float4*)&tile[c][d4] = *(const float4*)&G[(row0 + c) * DDIM + d4];
    }
}

// Stage W (64 out x 64 in, row-major) TRANSPOSED into wt[d][c], via 4x4 block transpose.
__device__ __forceinline__ void stage_wT(const float* __restrict__ Wg, float (* __restrict__ wt)[68], int t) {
    int bi = t & 15, bj = t >> 4;   // bi: c-block, bj: d-block
    float rv[4][4];
#pragma unroll
    for (int e = 0; e < 4; ++e)
        *(float4*)rv[e] = *(const float4*)&Wg[(bi * 4 + e) * DDIM + bj * 4];
#pragma unroll
    for (int e = 0; e < 4; ++e) {
        float4 o;
        o.x = rv[0][e]; o.y = rv[1][e]; o.z = rv[2][e]; o.w = rv[3][e];
        *(float4*)&wt[bj * 4 + e][bi * 4] = o;
    }
}

// acc[i][j] += sum_d A[r0+i][d] * W[d][c0+j]   (W stored transposed: wt[d][c])
__device__ __forceinline__ void gemm_tile(const float (* __restrict__ A)[68],
                                          const float (* __restrict__ W)[68],
                                          int r0, int c0, float acc[4][4]) {
#pragma unroll
    for (int d = 0; d < 64; d += 4) {
        float4 a[4], wv[4];
#pragma unroll
        for (int i = 0; i < 4; ++i) a[i] = *(const float4*)&A[r0 + i][d];
#pragma unroll
        for (int tt = 0; tt < 4; ++tt) wv[tt] = *(const float4*)&W[d + tt][c0];
#pragma unroll
        for (int i = 0; i < 4; ++i) {
            float av[4] = {a[i].x, a[i].y, a[i].z, a[i].w};
#pragma unroll
            for (int tt = 0; tt < 4; ++tt) {
                acc[i][0] += av[tt] * wv[tt].x;
                acc[i][1] += av[tt] * wv[tt].y;
                acc[i][2] += av[tt] * wv[tt].z;
                acc[i][3] += av[tt] * wv[tt].w;
            }
        }
    }
}

// LayerNorm rows of src -> dst (thread t owns row t>>2, 16-col chunk (t&3)*16).
__device__ __forceinline__ void ln_rows(const float (* __restrict__ src)[68], float (* __restrict__ dst)[68],
                                        const float* __restrict__ w_s, const float* __restrict__ b_s,
                                        int t, float* __restrict__ save) {
    int rr = t >> 2, qd = (t & 3) * 16;
    float4 v[4];
#pragma unroll
    for (int g = 0; g < 4; ++g) v[g] = *(const float4*)&src[rr][qd + g * 4];
    float s1 = 0.f, s2 = 0.f;
#pragma unroll
    for (int g = 0; g < 4; ++g) {
        s1 += (v[g].x + v[g].y) + (v[g].z + v[g].w);
        s2 += (v[g].x * v[g].x + v[g].y * v[g].y) + (v[g].z * v[g].z + v[g].w * v[g].w);
    }
    s1 += __shfl_xor(s1, 1, 64); s1 += __shfl_xor(s1, 2, 64);
    s2 += __shfl_xor(s2, 1, 64); s2 += __shfl_xor(s2, 2, 64);
    float m = s1 * (1.f / 64.f);
    float var = s2 * (1.f / 64.f) - m * m;
    float rs = rsqrtf(var + EPS);
#pragma unroll
    for (int g = 0; g < 4; ++g) {
        float4 w4 = *(const float4*)&w_s[qd + g * 4];
        float4 b4 = *(const float4*)&b_s[qd + g * 4];
        float4 o;
        o.x = (v[g].x - m) * rs * w4.x + b4.x;
        o.y = (v[g].y - m) * rs * w4.y + b4.y;
        o.z = (v[g].z - m) * rs * w4.z + b4.z;
        o.w = (v[g].w - m) * rs * w4.w + b4.w;
        *(float4*)&dst[rr][qd + g * 4] = o;
        if (save) *(float4*)&save[rr * DDIM + qd + g * 4] = o;
    }
}

// Dual LayerNorm: a := LN1(a), b := LN2(a_old)
__device__ __forceinline__ void ln_rows2(float (* __restrict__ a)[68], float (* __restrict__ b)[68],
                                         const float* __restrict__ w1, const float* __restrict__ b1,
                                         const float* __restrict__ w2, const float* __restrict__ b2, int t) {
    int rr = t >> 2, qd = (t & 3) * 16;
    float4 v[4];
#pragma unroll
    for (int g = 0; g < 4; ++g) v[g] = *(const float4*)&a[rr][qd + g * 4];
    float s1 = 0.f, s2 = 0.f;
#pragma unroll
    for (int g = 0; g < 4; ++g) {
        s1 += (v[g].x + v[g].y) + (v[g].z + v[g].w);
        s2 += (v[g].x * v[g].x + v[g].y * v[g].y) + (v[g].z * v[g].z + v[g].w * v[g].w);
    }
    s1 += __shfl_xor(s1, 1, 64); s1 += __shfl_xor(s1, 2, 64);
    s2 += __shfl_xor(s2, 1, 64); s2 += __shfl_xor(s2, 2, 64);
    float m = s1 * (1.f / 64.f);
    float var = s2 * (1.f / 64.f) - m * m;
    float rs = rsqrtf(var + EPS);
#pragma unroll
    for (int g = 0; g < 4; ++g) {
        float4 w14 = *(const float4*)&w1[qd + g * 4];
        float4 b14 = *(const float4*)&b1[qd + g * 4];
        float4 w24 = *(const float4*)&w2[qd + g * 4];
        float4 b24 = *(const float4*)&b2[qd + g * 4];
        float nx = (v[g].x - m) * rs, ny = (v[g].y - m) * rs, nz = (v[g].z - m) * rs, nw = (v[g].w - m) * rs;
        float4 o1, o2;
        o1.x = nx * w14.x + b14.x; o1.y = ny * w14.y + b14.y; o1.z = nz * w14.z + b14.z; o1.w = nw * w14.w + b14.w;
        o2.x = nx * w24.x + b24.x; o2.y = ny * w24.y + b24.y; o2.z = nz * w24.z + b24.z; o2.w = nw * w24.w + b24.w;
        *(float4*)&a[rr][qd + g * 4] = o1;
        *(float4*)&b[rr][qd + g * 4] = o2;
    }
}

// ---------------- fused QKV ----------------
__global__ __launch_bounds__(256) void qkv_fused(const float* __restrict__ x,
                                                 const float* __restrict__ Wqkv,
                                                 const float* __restrict__ Bqkv,
                                                 const float* __restrict__ lnw,
                                                 const float* __restrict__ lnb,
                                                 float* __restrict__ qin,
                                                 float* __restrict__ qo,
                                                 float* __restrict__ ko,
                                                 float* __restrict__ vo) {
    __shared__ float A[64][68], B[64][68], W[64][68];
    __shared__ float lw[64], lb[64];
    int t = threadIdx.x;
    long row0 = (long)blockIdx.x * 64;
    stage_in(x, A, t, row0);
    stage_wT(Wqkv, W, t);
    if (t < 64) { lw[t] = lnw[t]; lb[t] = lnb[t]; }
    __syncthreads();
    ln_rows(A, B, lw, lb, t, qin + row0 * DDIM);
    __syncthreads();
    int tx = t & 15, ty = t >> 4, r0 = ty * 4, c0 = tx * 4;
    {
        float acc[4][4] = {};
        gemm_tile(B, W, r0, c0, acc);
        float4 b4 = *(const float4*)&Bqkv[c0];
        float bv[4] = {b4.x, b4.y, b4.z, b4.w};
#pragma unroll
        for (int i = 0; i < 4; ++i) {
            float4 o; o.x = acc[i][0] + bv[0]; o.y = acc[i][1] + bv[1]; o.z = acc[i][2] + bv[2]; o.w = acc[i][3] + bv[3];
            *(float4*)&qo[(row0 + r0 + i) * DDIM + c0] = o;
        }
    }
    __syncthreads();
    stage_wT(Wqkv + 4096, W, t);
    __syncthreads();
    {
        float acc[4][4] = {};
        gemm_tile(A, W, r0, c0, acc);
        float4 b4 = *(const float4*)&Bqkv[64 + c0];
        float bv[4] = {b4.x, b4.y, b4.z, b4.w};
#pragma unroll
        for (int i = 0; i < 4; ++i) {
            float4 o; o.x = acc[i][0] + bv[0]; o.y = acc[i][1] + bv[1]; o.z = acc[i][2] + bv[2]; o.w = acc[i][3] + bv[3];
            *(float4*)&ko[(row0 + r0 + i) * DDIM + c0] = o;
        }
    }
    __syncthreads();
    stage_wT(Wqkv + 8192, W, t);
    __syncthreads();
    {
        float acc[4][4] = {};
        gemm_tile(A, W, r0, c0, acc);
        float4 b4 = *(const float4*)&Bqkv[128 + c0];
        float bv[4] = {b4.x, b4.y, b4.z, b4.w};
#pragma unroll
        for (int i = 0; i < 4; ++i) {
            float4 o; o.x = acc[i][0] + bv[0]; o.y = acc[i][1] + bv[1]; o.z = acc[i][2] + bv[2]; o.w = acc[i][3] + bv[3];
            *(float4*)&vo[(row0 + r0 + i) * DDIM + c0] = o;
        }
    }
}

// ---------------- fused out-proj + FFN ----------------
__global__ __launch_bounds__(256) void ffn_fused(const float* __restrict__ ctx,
                                                 const float* __restrict__ qin,
                                                 const float* __restrict__ Wo, const float* __restrict__ bo,
                                                 const float* __restrict__ W1, const float* __restrict__ b1,
                                                 const float* __restrict__ W2, const float* __restrict__ b2,
                                                 const float* __restrict__ l1w, const float* __restrict__ l1b,
                                                 const float* __restrict__ l2w, const float* __restrict__ l2b,
                                                 float* __restrict__ xout) {
    __shared__ float A[64][68], B[64][68], W[64][68];
    __shared__ float w1s[64], b1s[64], w2s[64], b2s[64];
    int t = threadIdx.x;
    long row0 = (long)blockIdx.x * 64;
    stage_in(ctx, A, t, row0);
    stage_in(qin, B, t, row0);
    stage_wT(Wo, W, t);
    if (t < 64) { w1s[t] = l1w[t]; b1s[t] = l1b[t]; w2s[t] = l2w[t]; b2s[t] = l2b[t]; }
    __syncthreads();
    int tx = t & 15, ty = t >> 4, r0 = ty * 4, c0 = tx * 4;
    float x1[4][4] = {};
    gemm_tile(A, W, r0, c0, x1);
    {
        float4 b4 = *(const float4*)&bo[c0];
        float bv[4] = {b4.x, b4.y, b4.z, b4.w};
#pragma unroll
        for (int i = 0; i < 4; ++i)
#pragma unroll
            for (int j = 0; j < 4; ++j) x1[i][j] += bv[j] + B[r0 + i][c0 + j];
    }
    __syncthreads();
#pragma unroll
    for (int i = 0; i < 4; ++i) {
        float4 o; o.x = x1[i][0]; o.y = x1[i][1]; o.z = x1[i][2]; o.w = x1[i][3];
        *(float4*)&A[r0 + i][c0] = o;
    }
    __syncthreads();
    ln_rows2(A, B, w1s, b1s, w2s, b2s, t);
    stage_wT(W1, W, t);
    __syncthreads();
    float h[4][4] = {};
    gemm_tile(A, W, r0, c0, h);
    {
        float4 b4 = *(const float4*)&b1[c0];
        float bv[4] = {b4.x, b4.y, b4.z, b4.w};
#pragma unroll
        for (int i = 0; i < 4; ++i)
#pragma unroll
            for (int j = 0; j < 4; ++j) h[i][j] = fmaxf(h[i][j] + bv[j], 0.f);
    }
    __syncthreads();
#pragma unroll
    for (int i = 0; i < 4; ++i) {
        float4 o; o.x = h[i][0]; o.y = h[i][1]; o.z = h[i][2]; o.w = h[i][3];
        *(float4*)&A[r0 + i][c0] = o;
    }
    stage_wT(W2, W, t);
    __syncthreads();
    float o3[4][4] = {};
    gemm_tile(A, W, r0, c0, o3);
    {
        float4 b4 = *(const float4*)&b2[c0];
        float bv[4] = {b4.x, b4.y, b4.z, b4.w};
#pragma unroll
        for (int i = 0; i < 4; ++i) {
            float4 o;
            o.x = o3[i][0] + bv[0] + B[r0 + i][c0 + 0];
            o.y = o3[i][1] + bv[1] + B[r0 + i][c0 + 1];
            o.z = o3[i][2] + bv[2] + B[r0 + i][c0 + 2];
            o.w = o3[i][3] + bv[3] + B[r0 + i][c0 + 3];
            *(float4*)&xout[(row0 + r0 + i) * DDIM + c0] = o;
        }
    }
}

// ---------------- causal attention, one block per (b, head), 16 waves ----------------
// R7 QK/PV structure (fp32 K/V in LDS, 64 VGPR) + 1024-thread blocks for occupancy.
// A_s stored bf16 (r8 proved 0.0 absmax). LDS = 25.6K + 25.6K + 25.6K = 76.8 KB
// -> 2 blocks/CU x 16 waves = 32 waves/CU (100% theoretical occupancy).
__global__ __launch_bounds__(1024, 8) void attn_kernel(const float* __restrict__ q,
                                                       const float* __restrict__ k,
                                                       const float* __restrict__ v,
                                                       float* __restrict__ ctx) {
    __shared__ float K4[SS * 32];           // [(kk*8 + (dq^(kk&7)))*4 + e]
    __shared__ float V4[SS * 32];           // [(kk*8 + ((dq+kk)&7))*4 + e]
    __shared__ unsigned short As[16][4][SS];
    int b = blockIdx.x >> 1, h = blockIdx.x & 1;
    int t = threadIdx.x;
    const long base = (long)b * (SS * DDIM) + h * HD;
    for (int i = t; i < SS * 8; i += 1024) {
        int kk = i >> 3, dq = i & 7;
        float4 k4 = *(const float4*)&k[base + kk * DDIM + dq * 4];
        *(float4*)&K4[(kk * 8 + (dq ^ (kk & 7))) * 4] = k4;
        float4 v4 = *(const float4*)&v[base + kk * DDIM + dq * 4];
        *(float4*)&V4[(kk * 8 + ((dq + kk) & 7)) * 4] = v4;
    }
    __syncthreads();
    int w = t >> 6, lane = t & 63;
    const float scale = 0.17677669529663687f;   // 1/sqrt(32)
    for (int G = w; G < SS / 4; G += 16) {
        int r3 = 4 * G + 3;
        int ncb3 = (r3 >> 6) + 1;            // 1..4
        float sc[4][4];
#pragma unroll
        for (int i = 0; i < 4; ++i)
#pragma unroll
            for (int c = 0; c < 4; ++c) sc[i][c] = -1e30f;
        // ---- QK, chunk-major: K row regs reused across 4 Q-rows ----
#pragma unroll
        for (int c = 0; c < 4; ++c) {
            if (c < ncb3) {
                int kk = lane + c * 64;
                if (kk <= r3) {
                    int sw = kk & 7;
                    float4 kv[8];
#pragma unroll
                    for (int dq = 0; dq < 8; ++dq)
                        kv[dq] = *(const float4*)&K4[(kk * 8 + (dq ^ sw)) * 4];
#pragma unroll
                    for (int i = 0; i < 4; ++i) {
                        int r = 4 * G + i;
                        if (kk <= r) {
                            const float4* qp = (const float4*)&q[base + r * DDIM];
                            float d0 = 0.f, d1 = 0.f, d2 = 0.f, d3 = 0.f;
#pragma unroll
                            for (int dq = 0; dq < 8; ++dq) {
                                float4 q4 = qp[dq];
                                d0 += q4.x * kv[dq].x;
                                d1 += q4.y * kv[dq].y;
                                d2 += q4.z * kv[dq].z;
                                d3 += q4.w * kv[dq].w;
                            }
                            sc[i][c] = ((d0 + d1) + (d2 + d3)) * scale;
                        }
                    }
                }
            }
        }
        // ---- softmax per row, bf16 weights ----
#pragma unroll
        for (int i = 0; i < 4; ++i) {
            int r = 4 * G + i;
            float m = -1e30f;
#pragma unroll
            for (int c = 0; c < 4; ++c) if (c < ncb3) m = fmaxf(m, sc[i][c]);
            m = wave_max(m);
            float sum = 0.f;
#pragma unroll
            for (int c = 0; c < 4; ++c) {
                if (c < ncb3) {
                    int kk = lane + c * 64;
                    if (kk <= r) { sc[i][c] = __expf(sc[i][c] - m); sum += sc[i][c]; }
                }
            }
            sum = wave_sum(sum);
            float inv = 1.f / sum;
#pragma unroll
            for (int c = 0; c < 4; ++c) {
                if (c < ncb3) {
                    int kk = lane + c * 64;
                    if (kk <= r3) As[w][i][kk] = (kk <= r) ? f2b(sc[i][c] * inv) : (unsigned short)0;
                }
            }
        }
        // ---- PV: 4 rows share each V read ----
        int d4 = lane & 7, ko = lane >> 3;
        float4 acc0 = {0,0,0,0}, acc1 = {0,0,0,0}, acc2 = {0,0,0,0}, acc3 = {0,0,0,0};
        for (int kk = ko; kk <= r3; kk += 8) {
            float4 v4 = *(const float4*)&V4[(kk * 8 + ((d4 + kk) & 7)) * 4];
            float a0 = __uint_as_float(((unsigned)As[w][0][kk]) << 16);
            float a1 = __uint_as_float(((unsigned)As[w][1][kk]) << 16);
            float a2 = __uint_as_float(((unsigned)As[w][2][kk]) << 16);
            float a3 = __uint_as_float(((unsigned)As[w][3][kk]) << 16);
            acc0.x += a0 * v4.x; acc0.y += a0 * v4.y; acc0.z += a0 * v4.z; acc0.w += a0 * v4.w;
            acc1.x += a1 * v4.x; acc1.y += a1 * v4.y; acc1.z += a1 * v4.z; acc1.w += a1 * v4.w;
            acc2.x += a2 * v4.x; acc2.y += a2 * v4.y; acc2.z += a2 * v4.z; acc2.w += a2 * v4.w;
            acc3.x += a3 * v4.x; acc3.y += a3 * v4.y; acc3.z += a3 * v4.z; acc3.w += a3 * v4.w;
        }
        float4* accs[4] = {&acc0, &acc1, &acc2, &acc3};
#pragma unroll
        for (int i = 0; i < 4; ++i) {
            float4& a = *accs[i];
#pragma unroll
            for (int o = 8; o <= 32; o <<= 1) {
                a.x += __shfl_xor(a.x, o, 64);
                a.y += __shfl_xor(a.y, o, 64);
                a.z += __shfl_xor(a.z, o, 64);
                a.w += __shfl_xor(a.w, o, 64);
            }
        }
        if (ko == 0) {
#pragma unroll
            for (int i = 0; i < 4; ++i) {
                int r = 4 * G + i;
                *(float4*)&ctx[base + r * DDIM + d4 * 4] = *accs[i];
            }
        }
    }
}

// ---------------- Gram matrix partials ----------------
__global__ __launch_bounds__(256) void gram_kernel(const float* __restrict__ A, int nrows,
                                                   float* __restrict__ part) {
    __shared__ float rows[16][64];
    int t = threadIdx.x;
    int i = t >> 2;            // 0..63
    int jb = (t & 3) * 16;     // 0/16/32/48
    float acc[16] = {};
    for (long base = (long)blockIdx.x * 16; base < nrows; base += (long)GRAM_NB * 16) {
        {
            int rr = t >> 4, d4 = (t & 15) * 4;
            long gr = base + rr;
            float4 vv = make_float4(0.f, 0.f, 0.f, 0.f);
            if (gr < nrows) vv = *(const float4*)&A[gr * DDIM + d4];
            *(float4*)&rows[rr][d4] = vv;
        }
        __syncthreads();
#pragma unroll
        for (int rr = 0; rr < 16; ++rr) {
            float ai = rows[rr][i];
            float4 r0 = *(const float4*)&rows[rr][jb];
            float4 r1 = *(const float4*)&rows[rr][jb + 4];
            float4 r2 = *(const float4*)&rows[rr][jb + 8];
            float4 r3 = *(const float4*)&rows[rr][jb + 12];
            acc[0] += ai * r0.x; acc[1] += ai * r0.y; acc[2] += ai * r0.z; acc[3] += ai * r0.w;
            acc[4] += ai * r1.x; acc[5] += ai * r1.y; acc[6] += ai * r1.z; acc[7] += ai * r1.w;
            acc[8] += ai * r2.x; acc[9] += ai * r2.y; acc[10] += ai * r2.z; acc[11] += ai * r2.w;
            acc[12] += ai * r3.x; acc[13] += ai * r3.y; acc[14] += ai * r3.z; acc[15] += ai * r3.w;
        }
        __syncthreads();
    }
    float* slab = part + (long)blockIdx.x * 4096 + i * 64 + jb;
#pragma unroll
    for (int g = 0; g < 4; ++g) {
        float4 o; o.x = acc[g * 4]; o.y = acc[g * 4 + 1]; o.z = acc[g * 4 + 2]; o.w = acc[g * 4 + 3];
        *(float4*)&slab[g * 4] = o;
    }
}

// out[p] = sum_b part[b*4096+p]
__global__ __launch_bounds__(256) void gram_reduce(const float* __restrict__ part,
                                                   float* __restrict__ out) {
    int p = blockIdx.x * 256 + threadIdx.x;   // 16 blocks
    float s = 0.f;
    for (int b = 0; b < GRAM_NB; ++b) s += part[(long)b * 4096 + p];
    out[p] = s;
}

// ---------------- right(): per-block partial sums of (1-C)ps^2 - 2ps ----------------
__global__ __launch_bounds__(256) void right_kernel(const float* __restrict__ x,
                                                    const float* __restrict__ item_emb,
                                                    const int* __restrict__ pos_seqs,
                                                    const float* __restrict__ pred_w,
                                                    float* __restrict__ rpart) {
    __shared__ float p_s[64];
    __shared__ float red[4];
    int t = threadIdx.x;
    if (t < 64) p_s[t] = pred_w[t];
    __syncthreads();
    int w = t >> 6, lane = t & 63;
    float local = 0.f;
    for (long row = (long)blockIdx.x * 4 + w; row < NROWS; row += (long)gridDim.x * 4) {
        int pi = pos_seqs[row];
        float val = x[row * DDIM + lane] * item_emb[(long)pi * DDIM + lane] * p_s[lane];
        float ps = wave_sum(val);           // lane-uniform
        local += (1.0f - CC) * ps * ps - 2.0f * ps;   // identical on all 64 lanes
    }
    if (lane == 0) red[w] = local;
    __syncthreads();
    if (t == 0) rpart[blockIdx.x] = red[0] + red[1] + red[2] + red[3];
}

// ---------------- per-parameter sum-of-squares ----------------
struct NormEntry { const float* p; int n; };
struct NormArgs { NormEntry e[30]; };

__global__ __launch_bounds__(256) void norms_kernel(NormArgs args, float* __restrict__ norms) {
    __shared__ float red[256];
    NormEntry en = args.e[blockIdx.x];
    float s = 0.f;
    for (int i = threadIdx.x; i < en.n; i += 256) { float v = en.p[i]; s += v * v; }
    red[threadIdx.x] = s;
    for (int o = 128; o > 0; o >>= 1) {
        __syncthreads();
        if (threadIdx.x < o) red[threadIdx.x] += red[threadIdx.x + o];
    }
    __syncthreads();
    if (threadIdx.x == 0) norms[blockIdx.x] = red[0];
}

// ---------------- final scalar ----------------
__global__ __launch_bounds__(256) void final_kernel(const float* __restrict__ EE,
                                                    const float* __restrict__ FF,
                                                    const float* __restrict__ pred_w,
                                                    const float* __restrict__ rpart,
                                                    const float* __restrict__ norms,
                                                    float* __restrict__ out) {
    __shared__ float p_s[64];
    __shared__ float redL[256];
    __shared__ float redT[256];
    __shared__ float redR[256];
    int t = threadIdx.x;
    if (t < 64) p_s[t] = pred_w[t];
    __syncthreads();
    float lf = 0.f, tr = 0.f, rs = 0.f;
    for (int p = t; p < 4096; p += 256) {
        int i = p >> 6, j = p & 63;
        float ee = EE[p];
        lf += FF[p] * ee * p_s[i] * p_s[j];
        if (i == j) tr += ee;
    }
    for (int i = t; i < 1024; i += 256) rs += rpart[i];
    redL[t] = lf; redT[t] = tr; redR[t] = rs;
    for (int o = 128; o > 0; o >>= 1) {
        __syncthreads();
        if (t < o) { redL[t] += redL[t + o]; redT[t] += redT[t + o]; redR[t] += redR[t + o]; }
    }
    __syncthreads();
    if (t == 0) {
        float reg = sqrtf(redT[0]);   // ||item_emb||_F = sqrt(trace(EE))
        for (int s = 0; s < 30; ++s) reg += sqrtf(norms[s]);
        out[0] = CC * redL[0] + redR[0] + 0.1f * reg;
    }
}

// ---------------- host ----------------
struct DevPtrs { float *x, *qin, *q, *k, *v, *ctx, *gpart; };

static DevPtrs fetch_ptrs() {
    DevPtrs p;
    (void)hipGetSymbolAddress((void**)&p.x,    HIP_SYMBOL(g_x));
    (void)hipGetSymbolAddress((void**)&p.qin,  HIP_SYMBOL(g_qin));
    (void)hipGetSymbolAddress((void**)&p.q,    HIP_SYMBOL(g_q));
    (void)hipGetSymbolAddress((void**)&p.k,    HIP_SYMBOL(g_k));
    (void)hipGetSymbolAddress((void**)&p.v,    HIP_SYMBOL(g_v));
    (void)hipGetSymbolAddress((void**)&p.ctx,  HIP_SYMBOL(g_ctx));
    (void)hipGetSymbolAddress((void**)&p.gpart,HIP_SYMBOL(g_gpart));
    return p;
}

extern "C" void kernel_launch(void* const* d_in, const int* in_sizes, int n_in,
                              void* d_out, int out_size, void* d_ws, size_t ws_size,
                              hipStream_t stream) {
    const int*   log_seqs = (const int*)d_in[1];
    const int*   pos_seqs = (const int*)d_in[2];
    const float* item_emb = (const float*)d_in[3];
    const float* pos_emb  = (const float*)d_in[4];
    const float* pred_w   = (const float*)d_in[5];
    const float* ln_w     = (const float*)d_in[6];
    const float* ln_b     = (const float*)d_in[7];
    const float* qkv_w    = (const float*)d_in[8];
    const float* qkv_b    = (const float*)d_in[9];
    const float* out_w    = (const float*)d_in[10];
    const float* out_b    = (const float*)d_in[11];
    const float* fc1_w    = (const float*)d_in[12];
    const float* fc1_b    = (const float*)d_in[13];
    const float* ffln_w   = (const float*)d_in[14];
    const float* ffln_b   = (const float*)d_in[15];
    const float* fc2_w    = (const float*)d_in[16];
    const float* fc2_b    = (const float*)d_in[17];
    const float* ffln2_w  = (const float*)d_in[18];
    const float* ffln2_b  = (const float*)d_in[19];

    static DevPtrs P = fetch_ptrs();   // first call is the uncaptured correctness call

    float* ws    = (float*)d_ws;
    float* rpart = ws;            // 1024
    float* nrm   = ws + 1024;     // 30
    float* EE    = ws + 2048;     // 4096
    float* FF    = ws + 6144;     // 4096

    embed_kernel<<<NROWS * 16 / 256, 256, 0, stream>>>(log_seqs, item_emb, pos_emb, P.x);

    const int GEMM_GRID = NROWS / 64;   // 1600

    for (int l = 0; l < LL; ++l) {
        const float* Wqkv = qkv_w + (long)l * 3 * 64 * 64;
        const float* Bqkv = qkv_b + (long)l * 192;
        qkv_fused<<<GEMM_GRID, 256, 0, stream>>>(
            P.x, Wqkv, Bqkv, ln_w + l * 64, ln_b + l * 64, P.qin, P.q, P.k, P.v);
        attn_kernel<<<BB * 2, 1024, 0, stream>>>(P.q, P.k, P.v, P.ctx);
        ffn_fused<<<GEMM_GRID, 256, 0, stream>>>(
            P.ctx, P.qin,
            out_w + (long)l * 4096, out_b + l * 64,
            fc1_w + (long)l * 4096, fc1_b + l * 64,
            fc2_w + (long)l * 4096, fc2_b + l * 64,
            ffln_w + l * 64, ffln_b + l * 64,
            ffln2_w + l * 64, ffln2_b + l * 64,
            P.x);
    }

    gram_kernel<<<GRAM_NB, 256, 0, stream>>>(item_emb, 100001, P.gpart);
    gram_reduce<<<16, 256, 0, stream>>>(P.gpart, EE);
    gram_kernel<<<GRAM_NB, 256, 0, stream>>>(P.x, NROWS, P.gpart);
    gram_reduce<<<16, 256, 0, stream>>>(P.gpart, FF);
    right_kernel<<<1024, 256, 0, stream>>>(P.x, item_emb, pos_seqs, pred_w, rpart);

    NormArgs na;
    int s = 0;
    na.e[s++] = {pos_emb, (SS + 1) * DDIM};
    na.e[s++] = {pred_w, DDIM};
    for (int l = 0; l < LL; ++l) {
        na.e[s++] = {ln_w + l * 64, 64};
        na.e[s++] = {ln_b + l * 64, 64};
        na.e[s++] = {qkv_w + (long)l * 12288, 12288};
        na.e[s++] = {qkv_b + (long)l * 192, 192};
        na.e[s++] = {out_w + (long)l * 4096, 4096};
        na.e[s++] = {out_b + l * 64, 64};
        na.e[s++] = {fc1_w + (long)l * 4096, 4096};
        na.e[s++] = {fc1_b + l * 64, 64};
        na.e[s++] = {ffln_w + l * 64, 64};
        na.e[s++] = {ffln_b + l * 64, 64};
        na.e[s++] = {fc2_w + (long)l * 4096, 4096};
        na.e[s++] = {fc2_b + l * 64, 64};
        na.e[s++] = {ffln2_w + l * 64, 64};
        na.e[s++] = {ffln2_b + l * 64, 64};
    }
    norms_kernel<<<30, 256, 0, stream>>>(na, nrm);

    final_kernel<<<1, 256, 0, stream>>>(EE, FF, pred_w, rpart, nrm, (float*)d_out);
}

// Round 10
// 744.725 us; speedup vs baseline: 1.2111x; 1.2111x over previous
//
#include <hip/hip_runtime.h>
#include <math.h>

#define BB 512
#define SS 200
#define DDIM 64
#define HD 32
#define LL 2
#define NROWS (BB * SS)   // 102400
#define EPS 1e-8f
#define CC 0.001f
#define GRAM_NB 256

// ---------------- static device buffers (activations) ----------------
__device__ float g_x[NROWS * DDIM];
__device__ float g_qin[NROWS * DDIM];
__device__ float g_q[NROWS * DDIM];
__device__ float g_k[NROWS * DDIM];
__device__ float g_v[NROWS * DDIM];
__device__ float g_ctx[NROWS * DDIM];
__device__ float g_gpart[GRAM_NB * 4096];   // gram per-block partials

// ---------------- helpers ----------------
__device__ __forceinline__ float wave_sum(float v) {
#pragma unroll
    for (int o = 32; o > 0; o >>= 1) v += __shfl_xor(v, o, 64);
    return v;
}
__device__ __forceinline__ float wave_max(float v) {
#pragma unroll
    for (int o = 32; o > 0; o >>= 1) v = fmaxf(v, __shfl_xor(v, o, 64));
    return v;
}

// bf16 pack (RNE)
__device__ __forceinline__ unsigned short f2b(float f) {
    unsigned u = __float_as_uint(f);
    return (unsigned short)((u + 0x7FFFu + ((u >> 16) & 1u)) >> 16);
}

// ---------------- embedding (float4) ----------------
__global__ __launch_bounds__(256) void embed_kernel(const int* __restrict__ log_seqs,
                                                    const float* __restrict__ item_emb,
                                                    const float* __restrict__ pos_emb,
                                                    float* __restrict__ x) {
    int tid = blockIdx.x * 256 + threadIdx.x;   // over NROWS*16
    int row = tid >> 4, q4 = tid & 15;
    int s = row % SS;
    int li = log_seqs[row];
    int poss = li ? (s + 1) : 0;
    float4 e = *(const float4*)&item_emb[li * DDIM + q4 * 4];
    float4 p = *(const float4*)&pos_emb[poss * DDIM + q4 * 4];
    float4 o;
    o.x = e.x * 8.0f + p.x; o.y = e.y * 8.0f + p.y;
    o.z = e.z * 8.0f + p.z; o.w = e.w * 8.0f + p.w;
    *(float4*)&x[row * DDIM + q4 * 4] = o;
}

// ---------------- tile staging helpers ----------------
__device__ __forceinline__ void stage_in(const float* __restrict__ G, float (* __restrict__ tile)[68],
                                         int t, long row0) {
#pragma unroll
    for (int rep = 0; rep < 4; ++rep) {
        int idx = t + rep * 256;
        int c = idx >> 4, d4 = (idx & 15) * 4;
        *(float4*)&tile[c][d4] = *(const float4*)&G[(row0 + c) * DDIM + d4];
    }
}

// Stage W (64 out x 64 in, row-major) TRANSPOSED into wt[d][c], via 4x4 block transpose.
__device__ __forceinline__ void stage_wT(const float* __restrict__ Wg, float (* __restrict__ wt)[68], int t) {
    int bi = t & 15, bj = t >> 4;   // bi: c-block, bj: d-block
    float rv[4][4];
#pragma unroll
    for (int e = 0; e < 4; ++e)
        *(float4*)rv[e] = *(const float4*)&Wg[(bi * 4 + e) * DDIM + bj * 4];
#pragma unroll
    for (int e = 0; e < 4; ++e) {
        float4 o;
        o.x = rv[0][e]; o.y = rv[1][e]; o.z = rv[2][e]; o.w = rv[3][e];
        *(float4*)&wt[bj * 4 + e][bi * 4] = o;
    }
}

// acc[i][j] += sum_d A[r0+i][d] * W[d][c0+j]   (W stored transposed: wt[d][c])
__device__ __forceinline__ void gemm_tile(const float (* __restrict__ A)[68],
                                          const float (* __restrict__ W)[68],
                                          int r0, int c0, float acc[4][4]) {
#pragma unroll
    for (int d = 0; d < 64; d += 4) {
        float4 a[4], wv[4];
#pragma unroll
        for (int i = 0; i < 4; ++i) a[i] = *(const float4*)&A[r0 + i][d];
#pragma unroll
        for (int tt = 0; tt < 4; ++tt) wv[tt] = *(const float4*)&W[d + tt][c0];
#pragma unroll
        for (int i = 0; i < 4; ++i) {
            float av[4] = {a[i].x, a[i].y, a[i].z, a[i].w};
#pragma unroll
            for (int tt = 0; tt < 4; ++tt) {
                acc[i][0] += av[tt] * wv[tt].x;
                acc[i][1] += av[tt] * wv[tt].y;
                acc[i][2] += av[tt] * wv[tt].z;
                acc[i][3] += av[tt] * wv[tt].w;
            }
        }
    }
}

// LayerNorm rows of src -> dst (thread t owns row t>>2, 16-col chunk (t&3)*16).
__device__ __forceinline__ void ln_rows(const float (* __restrict__ src)[68], float (* __restrict__ dst)[68],
                                        const float* __restrict__ w_s, const float* __restrict__ b_s,
                                        int t, float* __restrict__ save) {
    int rr = t >> 2, qd = (t & 3) * 16;
    float4 v[4];
#pragma unroll
    for (int g = 0; g < 4; ++g) v[g] = *(const float4*)&src[rr][qd + g * 4];
    float s1 = 0.f, s2 = 0.f;
#pragma unroll
    for (int g = 0; g < 4; ++g) {
        s1 += (v[g].x + v[g].y) + (v[g].z + v[g].w);
        s2 += (v[g].x * v[g].x + v[g].y * v[g].y) + (v[g].z * v[g].z + v[g].w * v[g].w);
    }
    s1 += __shfl_xor(s1, 1, 64); s1 += __shfl_xor(s1, 2, 64);
    s2 += __shfl_xor(s2, 1, 64); s2 += __shfl_xor(s2, 2, 64);
    float m = s1 * (1.f / 64.f);
    float var = s2 * (1.f / 64.f) - m * m;
    float rs = rsqrtf(var + EPS);
#pragma unroll
    for (int g = 0; g < 4; ++g) {
        float4 w4 = *(const float4*)&w_s[qd + g * 4];
        float4 b4 = *(const float4*)&b_s[qd + g * 4];
        float4 o;
        o.x = (v[g].x - m) * rs * w4.x + b4.x;
        o.y = (v[g].y - m) * rs * w4.y + b4.y;
        o.z = (v[g].z - m) * rs * w4.z + b4.z;
        o.w = (v[g].w - m) * rs * w4.w + b4.w;
        *(float4*)&dst[rr][qd + g * 4] = o;
        if (save) *(float4*)&save[rr * DDIM + qd + g * 4] = o;
    }
}

// Dual LayerNorm: a := LN1(a), b := LN2(a_old)
__device__ __forceinline__ void ln_rows2(float (* __restrict__ a)[68], float (* __restrict__ b)[68],
                                         const float* __restrict__ w1, const float* __restrict__ b1,
                                         const float* __restrict__ w2, const float* __restrict__ b2, int t) {
    int rr = t >> 2, qd = (t & 3) * 16;
    float4 v[4];
#pragma unroll
    for (int g = 0; g < 4; ++g) v[g] = *(const float4*)&a[rr][qd + g * 4];
    float s1 = 0.f, s2 = 0.f;
#pragma unroll
    for (int g = 0; g < 4; ++g) {
        s1 += (v[g].x + v[g].y) + (v[g].z + v[g].w);
        s2 += (v[g].x * v[g].x + v[g].y * v[g].y) + (v[g].z * v[g].z + v[g].w * v[g].w);
    }
    s1 += __shfl_xor(s1, 1, 64); s1 += __shfl_xor(s1, 2, 64);
    s2 += __shfl_xor(s2, 1, 64); s2 += __shfl_xor(s2, 2, 64);
    float m = s1 * (1.f / 64.f);
    float var = s2 * (1.f / 64.f) - m * m;
    float rs = rsqrtf(var + EPS);
#pragma unroll
    for (int g = 0; g < 4; ++g) {
        float4 w14 = *(const float4*)&w1[qd + g * 4];
        float4 b14 = *(const float4*)&b1[qd + g * 4];
        float4 w24 = *(const float4*)&w2[qd + g * 4];
        float4 b24 = *(const float4*)&b2[qd + g * 4];
        float nx = (v[g].x - m) * rs, ny = (v[g].y - m) * rs, nz = (v[g].z - m) * rs, nw = (v[g].w - m) * rs;
        float4 o1, o2;
        o1.x = nx * w14.x + b14.x; o1.y = ny * w14.y + b14.y; o1.z = nz * w14.z + b14.z; o1.w = nw * w14.w + b14.w;
        o2.x = nx * w24.x + b24.x; o2.y = ny * w24.y + b24.y; o2.z = nz * w24.z + b24.z; o2.w = nw * w24.w + b24.w;
        *(float4*)&a[rr][qd + g * 4] = o1;
        *(float4*)&b[rr][qd + g * 4] = o2;
    }
}

// ---------------- fused QKV ----------------
__global__ __launch_bounds__(256) void qkv_fused(const float* __restrict__ x,
                                                 const float* __restrict__ Wqkv,
                                                 const float* __restrict__ Bqkv,
                                                 const float* __restrict__ lnw,
                                                 const float* __restrict__ lnb,
                                                 float* __restrict__ qin,
                                                 float* __restrict__ qo,
                                                 float* __restrict__ ko,
                                                 float* __restrict__ vo) {
    __shared__ float A[64][68], B[64][68], W[64][68];
    __shared__ float lw[64], lb[64];
    int t = threadIdx.x;
    long row0 = (long)blockIdx.x * 64;
    stage_in(x, A, t, row0);
    stage_wT(Wqkv, W, t);
    if (t < 64) { lw[t] = lnw[t]; lb[t] = lnb[t]; }
    __syncthreads();
    ln_rows(A, B, lw, lb, t, qin + row0 * DDIM);
    __syncthreads();
    int tx = t & 15, ty = t >> 4, r0 = ty * 4, c0 = tx * 4;
    {
        float acc[4][4] = {};
        gemm_tile(B, W, r0, c0, acc);
        float4 b4 = *(const float4*)&Bqkv[c0];
        float bv[4] = {b4.x, b4.y, b4.z, b4.w};
#pragma unroll
        for (int i = 0; i < 4; ++i) {
            float4 o; o.x = acc[i][0] + bv[0]; o.y = acc[i][1] + bv[1]; o.z = acc[i][2] + bv[2]; o.w = acc[i][3] + bv[3];
            *(float4*)&qo[(row0 + r0 + i) * DDIM + c0] = o;
        }
    }
    __syncthreads();
    stage_wT(Wqkv + 4096, W, t);
    __syncthreads();
    {
        float acc[4][4] = {};
        gemm_tile(A, W, r0, c0, acc);
        float4 b4 = *(const float4*)&Bqkv[64 + c0];
        float bv[4] = {b4.x, b4.y, b4.z, b4.w};
#pragma unroll
        for (int i = 0; i < 4; ++i) {
            float4 o; o.x = acc[i][0] + bv[0]; o.y = acc[i][1] + bv[1]; o.z = acc[i][2] + bv[2]; o.w = acc[i][3] + bv[3];
            *(float4*)&ko[(row0 + r0 + i) * DDIM + c0] = o;
        }
    }
    __syncthreads();
    stage_wT(Wqkv + 8192, W, t);
    __syncthreads();
    {
        float acc[4][4] = {};
        gemm_tile(A, W, r0, c0, acc);
        float4 b4 = *(const float4*)&Bqkv[128 + c0];
        float bv[4] = {b4.x, b4.y, b4.z, b4.w};
#pragma unroll
        for (int i = 0; i < 4; ++i) {
            float4 o; o.x = acc[i][0] + bv[0]; o.y = acc[i][1] + bv[1]; o.z = acc[i][2] + bv[2]; o.w = acc[i][3] + bv[3];
            *(float4*)&vo[(row0 + r0 + i) * DDIM + c0] = o;
        }
    }
}

// ---------------- fused out-proj + FFN ----------------
__global__ __launch_bounds__(256) void ffn_fused(const float* __restrict__ ctx,
                                                 const float* __restrict__ qin,
                                                 const float* __restrict__ Wo, const float* __restrict__ bo,
                                                 const float* __restrict__ W1, const float* __restrict__ b1,
                                                 const float* __restrict__ W2, const float* __restrict__ b2,
                                                 const float* __restrict__ l1w, const float* __restrict__ l1b,
                                                 const float* __restrict__ l2w, const float* __restrict__ l2b,
                                                 float* __restrict__ xout) {
    __shared__ float A[64][68], B[64][68], W[64][68];
    __shared__ float w1s[64], b1s[64], w2s[64], b2s[64];
    int t = threadIdx.x;
    long row0 = (long)blockIdx.x * 64;
    stage_in(ctx, A, t, row0);
    stage_in(qin, B, t, row0);
    stage_wT(Wo, W, t);
    if (t < 64) { w1s[t] = l1w[t]; b1s[t] = l1b[t]; w2s[t] = l2w[t]; b2s[t] = l2b[t]; }
    __syncthreads();
    int tx = t & 15, ty = t >> 4, r0 = ty * 4, c0 = tx * 4;
    float x1[4][4] = {};
    gemm_tile(A, W, r0, c0, x1);
    {
        float4 b4 = *(const float4*)&bo[c0];
        float bv[4] = {b4.x, b4.y, b4.z, b4.w};
#pragma unroll
        for (int i = 0; i < 4; ++i)
#pragma unroll
            for (int j = 0; j < 4; ++j) x1[i][j] += bv[j] + B[r0 + i][c0 + j];
    }
    __syncthreads();
#pragma unroll
    for (int i = 0; i < 4; ++i) {
        float4 o; o.x = x1[i][0]; o.y = x1[i][1]; o.z = x1[i][2]; o.w = x1[i][3];
        *(float4*)&A[r0 + i][c0] = o;
    }
    __syncthreads();
    ln_rows2(A, B, w1s, b1s, w2s, b2s, t);
    stage_wT(W1, W, t);
    __syncthreads();
    float h[4][4] = {};
    gemm_tile(A, W, r0, c0, h);
    {
        float4 b4 = *(const float4*)&b1[c0];
        float bv[4] = {b4.x, b4.y, b4.z, b4.w};
#pragma unroll
        for (int i = 0; i < 4; ++i)
#pragma unroll
            for (int j = 0; j < 4; ++j) h[i][j] = fmaxf(h[i][j] + bv[j], 0.f);
    }
    __syncthreads();
#pragma unroll
    for (int i = 0; i < 4; ++i) {
        float4 o; o.x = h[i][0]; o.y = h[i][1]; o.z = h[i][2]; o.w = h[i][3];
        *(float4*)&A[r0 + i][c0] = o;
    }
    stage_wT(W2, W, t);
    __syncthreads();
    float o3[4][4] = {};
    gemm_tile(A, W, r0, c0, o3);
    {
        float4 b4 = *(const float4*)&b2[c0];
        float bv[4] = {b4.x, b4.y, b4.z, b4.w};
#pragma unroll
        for (int i = 0; i < 4; ++i) {
            float4 o;
            o.x = o3[i][0] + bv[0] + B[r0 + i][c0 + 0];
            o.y = o3[i][1] + bv[1] + B[r0 + i][c0 + 1];
            o.z = o3[i][2] + bv[2] + B[r0 + i][c0 + 2];
            o.w = o3[i][3] + bv[3] + B[r0 + i][c0 + 3];
            *(float4*)&xout[(row0 + r0 + i) * DDIM + c0] = o;
        }
    }
}

// ---------------- causal attention, one block per (b, head), 16 waves ----------------
// R7 QK/PV body (fp32 K/V in LDS, natural ~64 VGPR) at 1024 threads.
// NO min-waves bound: r8/r9 proved any VGPR cap below the natural allocation
// spills to scratch (hbm_bytes 2-6x). LDS 76.8 KB -> 2 blocks/CU; at 64 VGPR
// both LDS and VGPR axes allow 32 waves/CU.
__global__ __launch_bounds__(1024) void attn_kernel(const float* __restrict__ q,
                                                    const float* __restrict__ k,
                                                    const float* __restrict__ v,
                                                    float* __restrict__ ctx) {
    __shared__ float K4[SS * 32];           // [(kk*8 + (dq^(kk&7)))*4 + e]
    __shared__ float V4[SS * 32];           // [(kk*8 + ((dq+kk)&7))*4 + e]
    __shared__ unsigned short As[16][4][SS];
    int b = blockIdx.x >> 1, h = blockIdx.x & 1;
    int t = threadIdx.x;
    const long base = (long)b * (SS * DDIM) + h * HD;
    for (int i = t; i < SS * 8; i += 1024) {
        int kk = i >> 3, dq = i & 7;
        float4 k4 = *(const float4*)&k[base + kk * DDIM + dq * 4];
        *(float4*)&K4[(kk * 8 + (dq ^ (kk & 7))) * 4] = k4;
        float4 v4 = *(const float4*)&v[base + kk * DDIM + dq * 4];
        *(float4*)&V4[(kk * 8 + ((dq + kk) & 7)) * 4] = v4;
    }
    __syncthreads();
    int w = t >> 6, lane = t & 63;
    const float scale = 0.17677669529663687f;   // 1/sqrt(32)
    for (int G = w; G < SS / 4; G += 16) {
        int r3 = 4 * G + 3;
        int ncb3 = (r3 >> 6) + 1;            // 1..4
        float sc[4][4];
#pragma unroll
        for (int i = 0; i < 4; ++i)
#pragma unroll
            for (int c = 0; c < 4; ++c) sc[i][c] = -1e30f;
        // ---- QK, chunk-major: K row regs reused across 4 Q-rows ----
#pragma unroll
        for (int c = 0; c < 4; ++c) {
            if (c < ncb3) {
                int kk = lane + c * 64;
                if (kk <= r3) {
                    int sw = kk & 7;
                    float4 kv[8];
#pragma unroll
                    for (int dq = 0; dq < 8; ++dq)
                        kv[dq] = *(const float4*)&K4[(kk * 8 + (dq ^ sw)) * 4];
#pragma unroll
                    for (int i = 0; i < 4; ++i) {
                        int r = 4 * G + i;
                        if (kk <= r) {
                            const float4* qp = (const float4*)&q[base + r * DDIM];
                            float d0 = 0.f, d1 = 0.f, d2 = 0.f, d3 = 0.f;
#pragma unroll
                            for (int dq = 0; dq < 8; ++dq) {
                                float4 q4 = qp[dq];
                                d0 += q4.x * kv[dq].x;
                                d1 += q4.y * kv[dq].y;
                                d2 += q4.z * kv[dq].z;
                                d3 += q4.w * kv[dq].w;
                            }
                            sc[i][c] = ((d0 + d1) + (d2 + d3)) * scale;
                        }
                    }
                }
            }
        }
        // ---- softmax per row, bf16 weights ----
#pragma unroll
        for (int i = 0; i < 4; ++i) {
            int r = 4 * G + i;
            float m = -1e30f;
#pragma unroll
            for (int c = 0; c < 4; ++c) if (c < ncb3) m = fmaxf(m, sc[i][c]);
            m = wave_max(m);
            float sum = 0.f;
#pragma unroll
            for (int c = 0; c < 4; ++c) {
                if (c < ncb3) {
                    int kk = lane + c * 64;
                    if (kk <= r) { sc[i][c] = __expf(sc[i][c] - m); sum += sc[i][c]; }
                }
            }
            sum = wave_sum(sum);
            float inv = 1.f / sum;
#pragma unroll
            for (int c = 0; c < 4; ++c) {
                if (c < ncb3) {
                    int kk = lane + c * 64;
                    if (kk <= r3) As[w][i][kk] = (kk <= r) ? f2b(sc[i][c] * inv) : (unsigned short)0;
                }
            }
        }
        // ---- PV: 4 rows share each V read ----
        int d4 = lane & 7, ko = lane >> 3;
        float4 acc0 = {0,0,0,0}, acc1 = {0,0,0,0}, acc2 = {0,0,0,0}, acc3 = {0,0,0,0};
        for (int kk = ko; kk <= r3; kk += 8) {
            float4 v4 = *(const float4*)&V4[(kk * 8 + ((d4 + kk) & 7)) * 4];
            float a0 = __uint_as_float(((unsigned)As[w][0][kk]) << 16);
            float a1 = __uint_as_float(((unsigned)As[w][1][kk]) << 16);
            float a2 = __uint_as_float(((unsigned)As[w][2][kk]) << 16);
            float a3 = __uint_as_float(((unsigned)As[w][3][kk]) << 16);
            acc0.x += a0 * v4.x; acc0.y += a0 * v4.y; acc0.z += a0 * v4.z; acc0.w += a0 * v4.w;
            acc1.x += a1 * v4.x; acc1.y += a1 * v4.y; acc1.z += a1 * v4.z; acc1.w += a1 * v4.w;
            acc2.x += a2 * v4.x; acc2.y += a2 * v4.y; acc2.z += a2 * v4.z; acc2.w += a2 * v4.w;
            acc3.x += a3 * v4.x; acc3.y += a3 * v4.y; acc3.z += a3 * v4.z; acc3.w += a3 * v4.w;
        }
        float4* accs[4] = {&acc0, &acc1, &acc2, &acc3};
#pragma unroll
        for (int i = 0; i < 4; ++i) {
            float4& a = *accs[i];
#pragma unroll
            for (int o = 8; o <= 32; o <<= 1) {
                a.x += __shfl_xor(a.x, o, 64);
                a.y += __shfl_xor(a.y, o, 64);
                a.z += __shfl_xor(a.z, o, 64);
                a.w += __shfl_xor(a.w, o, 64);
            }
        }
        if (ko == 0) {
#pragma unroll
            for (int i = 0; i < 4; ++i) {
                int r = 4 * G + i;
                *(float4*)&ctx[base + r * DDIM + d4 * 4] = *accs[i];
            }
        }
    }
}

// ---------------- Gram matrix partials ----------------
__global__ __launch_bounds__(256) void gram_kernel(const float* __restrict__ A, int nrows,
                                                   float* __restrict__ part) {
    __shared__ float rows[16][64];
    int t = threadIdx.x;
    int i = t >> 2;            // 0..63
    int jb = (t & 3) * 16;     // 0/16/32/48
    float acc[16] = {};
    for (long base = (long)blockIdx.x * 16; base < nrows; base += (long)GRAM_NB * 16) {
        {
            int rr = t >> 4, d4 = (t & 15) * 4;
            long gr = base + rr;
            float4 vv = make_float4(0.f, 0.f, 0.f, 0.f);
            if (gr < nrows) vv = *(const float4*)&A[gr * DDIM + d4];
            *(float4*)&rows[rr][d4] = vv;
        }
        __syncthreads();
#pragma unroll
        for (int rr = 0; rr < 16; ++rr) {
            float ai = rows[rr][i];
            float4 r0 = *(const float4*)&rows[rr][jb];
            float4 r1 = *(const float4*)&rows[rr][jb + 4];
            float4 r2 = *(const float4*)&rows[rr][jb + 8];
            float4 r3 = *(const float4*)&rows[rr][jb + 12];
            acc[0] += ai * r0.x; acc[1] += ai * r0.y; acc[2] += ai * r0.z; acc[3] += ai * r0.w;
            acc[4] += ai * r1.x; acc[5] += ai * r1.y; acc[6] += ai * r1.z; acc[7] += ai * r1.w;
            acc[8] += ai * r2.x; acc[9] += ai * r2.y; acc[10] += ai * r2.z; acc[11] += ai * r2.w;
            acc[12] += ai * r3.x; acc[13] += ai * r3.y; acc[14] += ai * r3.z; acc[15] += ai * r3.w;
        }
        __syncthreads();
    }
    float* slab = part + (long)blockIdx.x * 4096 + i * 64 + jb;
#pragma unroll
    for (int g = 0; g < 4; ++g) {
        float4 o; o.x = acc[g * 4]; o.y = acc[g * 4 + 1]; o.z = acc[g * 4 + 2]; o.w = acc[g * 4 + 3];
        *(float4*)&slab[g * 4] = o;
    }
}

// out[p] = sum_b part[b*4096+p]
__global__ __launch_bounds__(256) void gram_reduce(const float* __restrict__ part,
                                                   float* __restrict__ out) {
    int p = blockIdx.x * 256 + threadIdx.x;   // 16 blocks
    float s = 0.f;
    for (int b = 0; b < GRAM_NB; ++b) s += part[(long)b * 4096 + p];
    out[p] = s;
}

// ---------------- right(): per-block partial sums of (1-C)ps^2 - 2ps ----------------
__global__ __launch_bounds__(256) void right_kernel(const float* __restrict__ x,
                                                    const float* __restrict__ item_emb,
                                                    const int* __restrict__ pos_seqs,
                                                    const float* __restrict__ pred_w,
                                                    float* __restrict__ rpart) {
    __shared__ float p_s[64];
    __shared__ float red[4];
    int t = threadIdx.x;
    if (t < 64) p_s[t] = pred_w[t];
    __syncthreads();
    int w = t >> 6, lane = t & 63;
    float local = 0.f;
    for (long row = (long)blockIdx.x * 4 + w; row < NROWS; row += (long)gridDim.x * 4) {
        int pi = pos_seqs[row];
        float val = x[row * DDIM + lane] * item_emb[(long)pi * DDIM + lane] * p_s[lane];
        float ps = wave_sum(val);           // lane-uniform
        local += (1.0f - CC) * ps * ps - 2.0f * ps;   // identical on all 64 lanes
    }
    if (lane == 0) red[w] = local;
    __syncthreads();
    if (t == 0) rpart[blockIdx.x] = red[0] + red[1] + red[2] + red[3];
}

// ---------------- per-parameter sum-of-squares ----------------
struct NormEntry { const float* p; int n; };
struct NormArgs { NormEntry e[30]; };

__global__ __launch_bounds__(256) void norms_kernel(NormArgs args, float* __restrict__ norms) {
    __shared__ float red[256];
    NormEntry en = args.e[blockIdx.x];
    float s = 0.f;
    for (int i = threadIdx.x; i < en.n; i += 256) { float v = en.p[i]; s += v * v; }
    red[threadIdx.x] = s;
    for (int o = 128; o > 0; o >>= 1) {
        __syncthreads();
        if (threadIdx.x < o) red[threadIdx.x] += red[threadIdx.x + o];
    }
    __syncthreads();
    if (threadIdx.x == 0) norms[blockIdx.x] = red[0];
}

// ---------------- final scalar ----------------
__global__ __launch_bounds__(256) void final_kernel(const float* __restrict__ EE,
                                                    const float* __restrict__ FF,
                                                    const float* __restrict__ pred_w,
                                                    const float* __restrict__ rpart,
                                                    const float* __restrict__ norms,
                                                    float* __restrict__ out) {
    __shared__ float p_s[64];
    __shared__ float redL[256];
    __shared__ float redT[256];
    __shared__ float redR[256];
    int t = threadIdx.x;
    if (t < 64) p_s[t] = pred_w[t];
    __syncthreads();
    float lf = 0.f, tr = 0.f, rs = 0.f;
    for (int p = t; p < 4096; p += 256) {
        int i = p >> 6, j = p & 63;
        float ee = EE[p];
        lf += FF[p] * ee * p_s[i] * p_s[j];
        if (i == j) tr += ee;
    }
    for (int i = t; i < 1024; i += 256) rs += rpart[i];
    redL[t] = lf; redT[t] = tr; redR[t] = rs;
    for (int o = 128; o > 0; o >>= 1) {
        __syncthreads();
        if (t < o) { redL[t] += redL[t + o]; redT[t] += redT[t + o]; redR[t] += redR[t + o]; }
    }
    __syncthreads();
    if (t == 0) {
        float reg = sqrtf(redT[0]);   // ||item_emb||_F = sqrt(trace(EE))
        for (int s = 0; s < 30; ++s) reg += sqrtf(norms[s]);
        out[0] = CC * redL[0] + redR[0] + 0.1f * reg;
    }
}

// ---------------- host ----------------
struct DevPtrs { float *x, *qin, *q, *k, *v, *ctx, *gpart; };

static DevPtrs fetch_ptrs() {
    DevPtrs p;
    (void)hipGetSymbolAddress((void**)&p.x,    HIP_SYMBOL(g_x));
    (void)hipGetSymbolAddress((void**)&p.qin,  HIP_SYMBOL(g_qin));
    (void)hipGetSymbolAddress((void**)&p.q,    HIP_SYMBOL(g_q));
    (void)hipGetSymbolAddress((void**)&p.k,    HIP_SYMBOL(g_k));
    (void)hipGetSymbolAddress((void**)&p.v,    HIP_SYMBOL(g_v));
    (void)hipGetSymbolAddress((void**)&p.ctx,  HIP_SYMBOL(g_ctx));
    (void)hipGetSymbolAddress((void**)&p.gpart,HIP_SYMBOL(g_gpart));
    return p;
}

extern "C" void kernel_launch(void* const* d_in, const int* in_sizes, int n_in,
                              void* d_out, int out_size, void* d_ws, size_t ws_size,
                              hipStream_t stream) {
    const int*   log_seqs = (const int*)d_in[1];
    const int*   pos_seqs = (const int*)d_in[2];
    const float* item_emb = (const float*)d_in[3];
    const float* pos_emb  = (const float*)d_in[4];
    const float* pred_w   = (const float*)d_in[5];
    const float* ln_w     = (const float*)d_in[6];
    const float* ln_b     = (const float*)d_in[7];
    const float* qkv_w    = (const float*)d_in[8];
    const float* qkv_b    = (const float*)d_in[9];
    const float* out_w    = (const float*)d_in[10];
    const float* out_b    = (const float*)d_in[11];
    const float* fc1_w    = (const float*)d_in[12];
    const float* fc1_b    = (const float*)d_in[13];
    const float* ffln_w   = (const float*)d_in[14];
    const float* ffln_b   = (const float*)d_in[15];
    const float* fc2_w    = (const float*)d_in[16];
    const float* fc2_b    = (const float*)d_in[17];
    const float* ffln2_w  = (const float*)d_in[18];
    const float* ffln2_b  = (const float*)d_in[19];

    static DevPtrs P = fetch_ptrs();   // first call is the uncaptured correctness call

    float* ws    = (float*)d_ws;
    float* rpart = ws;            // 1024
    float* nrm   = ws + 1024;     // 30
    float* EE    = ws + 2048;     // 4096
    float* FF    = ws + 6144;     // 4096

    embed_kernel<<<NROWS * 16 / 256, 256, 0, stream>>>(log_seqs, item_emb, pos_emb, P.x);

    const int GEMM_GRID = NROWS / 64;   // 1600

    for (int l = 0; l < LL; ++l) {
        const float* Wqkv = qkv_w + (long)l * 3 * 64 * 64;
        const float* Bqkv = qkv_b + (long)l * 192;
        qkv_fused<<<GEMM_GRID, 256, 0, stream>>>(
            P.x, Wqkv, Bqkv, ln_w + l * 64, ln_b + l * 64, P.qin, P.q, P.k, P.v);
        attn_kernel<<<BB * 2, 1024, 0, stream>>>(P.q, P.k, P.v, P.ctx);
        ffn_fused<<<GEMM_GRID, 256, 0, stream>>>(
            P.ctx, P.qin,
            out_w + (long)l * 4096, out_b + l * 64,
            fc1_w + (long)l * 4096, fc1_b + l * 64,
            fc2_w + (long)l * 4096, fc2_b + l * 64,
            ffln_w + l * 64, ffln_b + l * 64,
            ffln2_w + l * 64, ffln2_b + l * 64,
            P.x);
    }

    gram_kernel<<<GRAM_NB, 256, 0, stream>>>(item_emb, 100001, P.gpart);
    gram_reduce<<<16, 256, 0, stream>>>(P.gpart, EE);
    gram_kernel<<<GRAM_NB, 256, 0, stream>>>(P.x, NROWS, P.gpart);
    gram_reduce<<<16, 256, 0, stream>>>(P.gpart, FF);
    right_kernel<<<1024, 256, 0, stream>>>(P.x, item_emb, pos_seqs, pred_w, rpart);

    NormArgs na;
    int s = 0;
    na.e[s++] = {pos_emb, (SS + 1) * DDIM};
    na.e[s++] = {pred_w, DDIM};
    for (int l = 0; l < LL; ++l) {
        na.e[s++] = {ln_w + l * 64, 64};
        na.e[s++] = {ln_b + l * 64, 64};
        na.e[s++] = {qkv_w + (long)l * 12288, 12288};
        na.e[s++] = {qkv_b + (long)l * 192, 192};
        na.e[s++] = {out_w + (long)l * 4096, 4096};
        na.e[s++] = {out_b + l * 64, 64};
        na.e[s++] = {fc1_w + (long)l * 4096, 4096};
        na.e[s++] = {fc1_b + l * 64, 64};
        na.e[s++] = {ffln_w + l * 64, 64};
        na.e[s++] = {ffln_b + l * 64, 64};
        na.e[s++] = {fc2_w + (long)l * 4096, 4096};
        na.e[s++] = {fc2_b + l * 64, 64};
        na.e[s++] = {ffln2_w + l * 64, 64};
        na.e[s++] = {ffln2_b + l * 64, 64};
    }
    norms_kernel<<<30, 256, 0, stream>>>(na, nrm);

    final_kernel<<<1, 256, 0, stream>>>(EE, FF, pred_w, rpart, nrm, (float*)d_out);
}

// Round 11
// 528.687 us; speedup vs baseline: 1.7060x; 1.4086x over previous
//
#include <hip/hip_runtime.h>
#include <math.h>

#define BB 512
#define SS 200
#define DDIM 64
#define HD 32
#define LL 2
#define NROWS (BB * SS)   // 102400
#define EPS 1e-8f
#define CC 0.001f
#define GRAM_NB 256

typedef __attribute__((ext_vector_type(8))) short bf16x8;
typedef __attribute__((ext_vector_type(4))) float f32x4;

// ---------------- static device buffers (activations) ----------------
__device__ float g_x[NROWS * DDIM];
__device__ float g_qin[NROWS * DDIM];
__device__ float g_q[NROWS * DDIM];
__device__ float g_k[NROWS * DDIM];
__device__ float g_v[NROWS * DDIM];
__device__ float g_ctx[NROWS * DDIM];
__device__ float g_gpart[GRAM_NB * 4096];   // gram per-block partials

// ---------------- helpers ----------------
__device__ __forceinline__ float wave_sum(float v) {
#pragma unroll
    for (int o = 32; o > 0; o >>= 1) v += __shfl_xor(v, o, 64);
    return v;
}

// bf16 pack (RNE)
__device__ __forceinline__ unsigned short f2b(float f) {
    unsigned u = __float_as_uint(f);
    return (unsigned short)((u + 0x7FFFu + ((u >> 16) & 1u)) >> 16);
}

// ---------------- embedding (float4) ----------------
__global__ __launch_bounds__(256) void embed_kernel(const int* __restrict__ log_seqs,
                                                    const float* __restrict__ item_emb,
                                                    const float* __restrict__ pos_emb,
                                                    float* __restrict__ x) {
    int tid = blockIdx.x * 256 + threadIdx.x;   // over NROWS*16
    int row = tid >> 4, q4 = tid & 15;
    int s = row % SS;
    int li = log_seqs[row];
    int poss = li ? (s + 1) : 0;
    float4 e = *(const float4*)&item_emb[li * DDIM + q4 * 4];
    float4 p = *(const float4*)&pos_emb[poss * DDIM + q4 * 4];
    float4 o;
    o.x = e.x * 8.0f + p.x; o.y = e.y * 8.0f + p.y;
    o.z = e.z * 8.0f + p.z; o.w = e.w * 8.0f + p.w;
    *(float4*)&x[row * DDIM + q4 * 4] = o;
}

// ---------------- tile staging helpers ----------------
__device__ __forceinline__ void stage_in(const float* __restrict__ G, float (* __restrict__ tile)[68],
                                         int t, long row0) {
#pragma unroll
    for (int rep = 0; rep < 4; ++rep) {
        int idx = t + rep * 256;
        int c = idx >> 4, d4 = (idx & 15) * 4;
        *(float4*)&tile[c][d4] = *(const float4*)&G[(row0 + c) * DDIM + d4];
    }
}

// Stage W (64 out x 64 in, row-major) TRANSPOSED into wt[d][c], via 4x4 block transpose.
__device__ __forceinline__ void stage_wT(const float* __restrict__ Wg, float (* __restrict__ wt)[68], int t) {
    int bi = t & 15, bj = t >> 4;   // bi: c-block, bj: d-block
    float rv[4][4];
#pragma unroll
    for (int e = 0; e < 4; ++e)
        *(float4*)rv[e] = *(const float4*)&Wg[(bi * 4 + e) * DDIM + bj * 4];
#pragma unroll
    for (int e = 0; e < 4; ++e) {
        float4 o;
        o.x = rv[0][e]; o.y = rv[1][e]; o.z = rv[2][e]; o.w = rv[3][e];
        *(float4*)&wt[bj * 4 + e][bi * 4] = o;
    }
}

// acc[i][j] += sum_d A[r0+i][d] * W[d][c0+j]   (W stored transposed: wt[d][c])
__device__ __forceinline__ void gemm_tile(const float (* __restrict__ A)[68],
                                          const float (* __restrict__ W)[68],
                                          int r0, int c0, float acc[4][4]) {
#pragma unroll
    for (int d = 0; d < 64; d += 4) {
        float4 a[4], wv[4];
#pragma unroll
        for (int i = 0; i < 4; ++i) a[i] = *(const float4*)&A[r0 + i][d];
#pragma unroll
        for (int tt = 0; tt < 4; ++tt) wv[tt] = *(const float4*)&W[d + tt][c0];
#pragma unroll
        for (int i = 0; i < 4; ++i) {
            float av[4] = {a[i].x, a[i].y, a[i].z, a[i].w};
#pragma unroll
            for (int tt = 0; tt < 4; ++tt) {
                acc[i][0] += av[tt] * wv[tt].x;
                acc[i][1] += av[tt] * wv[tt].y;
                acc[i][2] += av[tt] * wv[tt].z;
                acc[i][3] += av[tt] * wv[tt].w;
            }
        }
    }
}

// LayerNorm rows of src -> dst (thread t owns row t>>2, 16-col chunk (t&3)*16).
__device__ __forceinline__ void ln_rows(const float (* __restrict__ src)[68], float (* __restrict__ dst)[68],
                                        const float* __restrict__ w_s, const float* __restrict__ b_s,
                                        int t, float* __restrict__ save) {
    int rr = t >> 2, qd = (t & 3) * 16;
    float4 v[4];
#pragma unroll
    for (int g = 0; g < 4; ++g) v[g] = *(const float4*)&src[rr][qd + g * 4];
    float s1 = 0.f, s2 = 0.f;
#pragma unroll
    for (int g = 0; g < 4; ++g) {
        s1 += (v[g].x + v[g].y) + (v[g].z + v[g].w);
        s2 += (v[g].x * v[g].x + v[g].y * v[g].y) + (v[g].z * v[g].z + v[g].w * v[g].w);
    }
    s1 += __shfl_xor(s1, 1, 64); s1 += __shfl_xor(s1, 2, 64);
    s2 += __shfl_xor(s2, 1, 64); s2 += __shfl_xor(s2, 2, 64);
    float m = s1 * (1.f / 64.f);
    float var = s2 * (1.f / 64.f) - m * m;
    float rs = rsqrtf(var + EPS);
#pragma unroll
    for (int g = 0; g < 4; ++g) {
        float4 w4 = *(const float4*)&w_s[qd + g * 4];
        float4 b4 = *(const float4*)&b_s[qd + g * 4];
        float4 o;
        o.x = (v[g].x - m) * rs * w4.x + b4.x;
        o.y = (v[g].y - m) * rs * w4.y + b4.y;
        o.z = (v[g].z - m) * rs * w4.z + b4.z;
        o.w = (v[g].w - m) * rs * w4.w + b4.w;
        *(float4*)&dst[rr][qd + g * 4] = o;
        if (save) *(float4*)&save[rr * DDIM + qd + g * 4] = o;
    }
}

// Dual LayerNorm: a := LN1(a), b := LN2(a_old)
__device__ __forceinline__ void ln_rows2(float (* __restrict__ a)[68], float (* __restrict__ b)[68],
                                         const float* __restrict__ w1, const float* __restrict__ b1,
                                         const float* __restrict__ w2, const float* __restrict__ b2, int t) {
    int rr = t >> 2, qd = (t & 3) * 16;
    float4 v[4];
#pragma unroll
    for (int g = 0; g < 4; ++g) v[g] = *(const float4*)&a[rr][qd + g * 4];
    float s1 = 0.f, s2 = 0.f;
#pragma unroll
    for (int g = 0; g < 4; ++g) {
        s1 += (v[g].x + v[g].y) + (v[g].z + v[g].w);
        s2 += (v[g].x * v[g].x + v[g].y * v[g].y) + (v[g].z * v[g].z + v[g].w * v[g].w);
    }
    s1 += __shfl_xor(s1, 1, 64); s1 += __shfl_xor(s1, 2, 64);
    s2 += __shfl_xor(s2, 1, 64); s2 += __shfl_xor(s2, 2, 64);
    float m = s1 * (1.f / 64.f);
    float var = s2 * (1.f / 64.f) - m * m;
    float rs = rsqrtf(var + EPS);
#pragma unroll
    for (int g = 0; g < 4; ++g) {
        float4 w14 = *(const float4*)&w1[qd + g * 4];
        float4 b14 = *(const float4*)&b1[qd + g * 4];
        float4 w24 = *(const float4*)&w2[qd + g * 4];
        float4 b24 = *(const float4*)&b2[qd + g * 4];
        float nx = (v[g].x - m) * rs, ny = (v[g].y - m) * rs, nz = (v[g].z - m) * rs, nw = (v[g].w - m) * rs;
        float4 o1, o2;
        o1.x = nx * w14.x + b14.x; o1.y = ny * w14.y + b14.y; o1.z = nz * w14.z + b14.z; o1.w = nw * w14.w + b14.w;
        o2.x = nx * w24.x + b24.x; o2.y = ny * w24.y + b24.y; o2.z = nz * w24.z + b24.z; o2.w = nw * w24.w + b24.w;
        *(float4*)&a[rr][qd + g * 4] = o1;
        *(float4*)&b[rr][qd + g * 4] = o2;
    }
}

// ---------------- fused QKV ----------------
__global__ __launch_bounds__(256) void qkv_fused(const float* __restrict__ x,
                                                 const float* __restrict__ Wqkv,
                                                 const float* __restrict__ Bqkv,
                                                 const float* __restrict__ lnw,
                                                 const float* __restrict__ lnb,
                                                 float* __restrict__ qin,
                                                 float* __restrict__ qo,
                                                 float* __restrict__ ko,
                                                 float* __restrict__ vo) {
    __shared__ float A[64][68], B[64][68], W[64][68];
    __shared__ float lw[64], lb[64];
    int t = threadIdx.x;
    long row0 = (long)blockIdx.x * 64;
    stage_in(x, A, t, row0);
    stage_wT(Wqkv, W, t);
    if (t < 64) { lw[t] = lnw[t]; lb[t] = lnb[t]; }
    __syncthreads();
    ln_rows(A, B, lw, lb, t, qin + row0 * DDIM);
    __syncthreads();
    int tx = t & 15, ty = t >> 4, r0 = ty * 4, c0 = tx * 4;
    {
        float acc[4][4] = {};
        gemm_tile(B, W, r0, c0, acc);
        float4 b4 = *(const float4*)&Bqkv[c0];
        float bv[4] = {b4.x, b4.y, b4.z, b4.w};
#pragma unroll
        for (int i = 0; i < 4; ++i) {
            float4 o; o.x = acc[i][0] + bv[0]; o.y = acc[i][1] + bv[1]; o.z = acc[i][2] + bv[2]; o.w = acc[i][3] + bv[3];
            *(float4*)&qo[(row0 + r0 + i) * DDIM + c0] = o;
        }
    }
    __syncthreads();
    stage_wT(Wqkv + 4096, W, t);
    __syncthreads();
    {
        float acc[4][4] = {};
        gemm_tile(A, W, r0, c0, acc);
        float4 b4 = *(const float4*)&Bqkv[64 + c0];
        float bv[4] = {b4.x, b4.y, b4.z, b4.w};
#pragma unroll
        for (int i = 0; i < 4; ++i) {
            float4 o; o.x = acc[i][0] + bv[0]; o.y = acc[i][1] + bv[1]; o.z = acc[i][2] + bv[2]; o.w = acc[i][3] + bv[3];
            *(float4*)&ko[(row0 + r0 + i) * DDIM + c0] = o;
        }
    }
    __syncthreads();
    stage_wT(Wqkv + 8192, W, t);
    __syncthreads();
    {
        float acc[4][4] = {};
        gemm_tile(A, W, r0, c0, acc);
        float4 b4 = *(const float4*)&Bqkv[128 + c0];
        float bv[4] = {b4.x, b4.y, b4.z, b4.w};
#pragma unroll
        for (int i = 0; i < 4; ++i) {
            float4 o; o.x = acc[i][0] + bv[0]; o.y = acc[i][1] + bv[1]; o.z = acc[i][2] + bv[2]; o.w = acc[i][3] + bv[3];
            *(float4*)&vo[(row0 + r0 + i) * DDIM + c0] = o;
        }
    }
}

// ---------------- fused out-proj + FFN ----------------
__global__ __launch_bounds__(256) void ffn_fused(const float* __restrict__ ctx,
                                                 const float* __restrict__ qin,
                                                 const float* __restrict__ Wo, const float* __restrict__ bo,
                                                 const float* __restrict__ W1, const float* __restrict__ b1,
                                                 const float* __restrict__ W2, const float* __restrict__ b2,
                                                 const float* __restrict__ l1w, const float* __restrict__ l1b,
                                                 const float* __restrict__ l2w, const float* __restrict__ l2b,
                                                 float* __restrict__ xout) {
    __shared__ float A[64][68], B[64][68], W[64][68];
    __shared__ float w1s[64], b1s[64], w2s[64], b2s[64];
    int t = threadIdx.x;
    long row0 = (long)blockIdx.x * 64;
    stage_in(ctx, A, t, row0);
    stage_in(qin, B, t, row0);
    stage_wT(Wo, W, t);
    if (t < 64) { w1s[t] = l1w[t]; b1s[t] = l1b[t]; w2s[t] = l2w[t]; b2s[t] = l2b[t]; }
    __syncthreads();
    int tx = t & 15, ty = t >> 4, r0 = ty * 4, c0 = tx * 4;
    float x1[4][4] = {};
    gemm_tile(A, W, r0, c0, x1);
    {
        float4 b4 = *(const float4*)&bo[c0];
        float bv[4] = {b4.x, b4.y, b4.z, b4.w};
#pragma unroll
        for (int i = 0; i < 4; ++i)
#pragma unroll
            for (int j = 0; j < 4; ++j) x1[i][j] += bv[j] + B[r0 + i][c0 + j];
    }
    __syncthreads();
#pragma unroll
    for (int i = 0; i < 4; ++i) {
        float4 o; o.x = x1[i][0]; o.y = x1[i][1]; o.z = x1[i][2]; o.w = x1[i][3];
        *(float4*)&A[r0 + i][c0] = o;
    }
    __syncthreads();
    ln_rows2(A, B, w1s, b1s, w2s, b2s, t);
    stage_wT(W1, W, t);
    __syncthreads();
    float h[4][4] = {};
    gemm_tile(A, W, r0, c0, h);
    {
        float4 b4 = *(const float4*)&b1[c0];
        float bv[4] = {b4.x, b4.y, b4.z, b4.w};
#pragma unroll
        for (int i = 0; i < 4; ++i)
#pragma unroll
            for (int j = 0; j < 4; ++j) h[i][j] = fmaxf(h[i][j] + bv[j], 0.f);
    }
    __syncthreads();
#pragma unroll
    for (int i = 0; i < 4; ++i) {
        float4 o; o.x = h[i][0]; o.y = h[i][1]; o.z = h[i][2]; o.w = h[i][3];
        *(float4*)&A[r0 + i][c0] = o;
    }
    stage_wT(W2, W, t);
    __syncthreads();
    float o3[4][4] = {};
    gemm_tile(A, W, r0, c0, o3);
    {
        float4 b4 = *(const float4*)&b2[c0];
        float bv[4] = {b4.x, b4.y, b4.z, b4.w};
#pragma unroll
        for (int i = 0; i < 4; ++i) {
            float4 o;
            o.x = o3[i][0] + bv[0] + B[r0 + i][c0 + 0];
            o.y = o3[i][1] + bv[1] + B[r0 + i][c0 + 1];
            o.z = o3[i][2] + bv[2] + B[r0 + i][c0 + 2];
            o.w = o3[i][3] + bv[3] + B[r0 + i][c0 + 3];
            *(float4*)&xout[(row0 + r0 + i) * DDIM + c0] = o;
        }
    }
}

// ---------------- MFMA flash attention, one block per (b, head), 4 waves ----------------
// mfma_f32_16x16x32_bf16. C/D: col=lane&15, row=(lane>>4)*4+reg [verified].
// A: A[m=lane&15][k=(lane>>4)*8+j] [verified]. B: B[k=(lane>>4)*8+j][n=lane&15].
// K staged bf16 row-major (b128 frags), V staged bf16 TRANSPOSED (stride 232, 2-way=free).
// Each wave owns interleaved Q-tiles; flash online softmax over 32-key pairs:
// 2 QK MFMAs -> softmax in C-layout (quad shfl reduce) -> P via per-wave LDS (C->A) -> 2 PV MFMAs (K=32).
__global__ __launch_bounds__(256) void attn_kernel(const float* __restrict__ q,
                                                   const float* __restrict__ k,
                                                   const float* __restrict__ v,
                                                   float* __restrict__ ctx) {
    __shared__ unsigned short Kb[224 * 32];    // Kb[kk][d], zero for kk>=200
    __shared__ unsigned short Vt[32 * 232];    // Vt[d][kk], zero for kk>=200
    __shared__ unsigned short Ps[4][16 * 32];  // per-wave P buffer (16 rows x 32 kk)
    int b = blockIdx.x >> 1, h = blockIdx.x & 1;
    int t = threadIdx.x;
    const long base = (long)b * (SS * DDIM) + h * HD;
    for (int idx = t; idx < 224 * 32; idx += 256) {
        int kk = idx >> 5, d = idx & 31;
        unsigned short kvb = 0, vvb = 0;
        if (kk < SS) {
            kvb = f2b(k[base + kk * DDIM + d]);
            vvb = f2b(v[base + kk * DDIM + d]);
        }
        Kb[kk * 32 + d] = kvb;
        Vt[d * 232 + kk] = vvb;
    }
    __syncthreads();
    int w = t >> 6, lane = t & 63;
    int m16 = lane & 15, quad = lane >> 4;
    const float scale = 0.17677669529663687f;   // 1/sqrt(32)
    unsigned short* ps = Ps[w];
    for (int qt = w; qt < 13; qt += 4) {
        int q0 = qt * 16;
        // Q A-frag from global (row clamped; clamped rows never stored)
        int qrow = q0 + m16; if (qrow > SS - 1) qrow = SS - 1;
        bf16x8 qa;
        {
            const float* qp = &q[base + qrow * DDIM + quad * 8];
            float4 f0 = *(const float4*)qp;
            float4 f1 = *(const float4*)(qp + 4);
            qa[0] = (short)f2b(f0.x); qa[1] = (short)f2b(f0.y);
            qa[2] = (short)f2b(f0.z); qa[3] = (short)f2b(f0.w);
            qa[4] = (short)f2b(f1.x); qa[5] = (short)f2b(f1.y);
            qa[6] = (short)f2b(f1.z); qa[7] = (short)f2b(f1.w);
        }
        f32x4 o0 = {0.f, 0.f, 0.f, 0.f}, o1 = {0.f, 0.f, 0.f, 0.f};
        float mrow[4] = {-1e30f, -1e30f, -1e30f, -1e30f};
        float lrow[4] = {0.f, 0.f, 0.f, 0.f};
        int np = (qt + 2) >> 1;
        for (int pi = 0; pi < np; ++pi) {
            int p0 = pi * 32;
            // K B-frags for the two 16-key tiles of this pair
            bf16x8 kb0 = *(bf16x8*)&Kb[(p0 + m16) * 32 + quad * 8];
            bf16x8 kb1 = *(bf16x8*)&Kb[(p0 + 16 + m16) * 32 + quad * 8];
            f32x4 z = {0.f, 0.f, 0.f, 0.f};
            f32x4 s0 = __builtin_amdgcn_mfma_f32_16x16x32_bf16(qa, kb0, z, 0, 0, 0);
            f32x4 s1 = __builtin_amdgcn_mfma_f32_16x16x32_bf16(qa, kb1, z, 0, 0, 0);
            int col0 = p0 + m16, col1 = col0 + 16;
            float p0v[4], p1v[4];
#pragma unroll
            for (int rg = 0; rg < 4; ++rg) {
                int rglob = q0 + quad * 4 + rg;
                float v0 = (col0 <= rglob && col0 < SS) ? s0[rg] * scale : -1e30f;
                float v1 = (col1 <= rglob && col1 < SS) ? s1[rg] * scale : -1e30f;
                float mx = fmaxf(v0, v1);
#pragma unroll
                for (int o = 1; o <= 8; o <<= 1) mx = fmaxf(mx, __shfl_xor(mx, o, 64));
                float mn = fmaxf(mrow[rg], mx);
                float al = __expf(mrow[rg] - mn);
                float e0 = __expf(v0 - mn), e1 = __expf(v1 - mn);
                float sm = e0 + e1;
#pragma unroll
                for (int o = 1; o <= 8; o <<= 1) sm += __shfl_xor(sm, o, 64);
                lrow[rg] = lrow[rg] * al + sm;
                mrow[rg] = mn;
                o0[rg] *= al; o1[rg] *= al;
                p0v[rg] = e0; p1v[rg] = e1;
            }
            // P: C-layout -> LDS -> A-layout (in-order DS within wave; fence compiler)
            __builtin_amdgcn_wave_barrier();
#pragma unroll
            for (int rg = 0; rg < 4; ++rg) {
                int row = quad * 4 + rg;
                ps[row * 32 + m16] = f2b(p0v[rg]);
                ps[row * 32 + 16 + m16] = f2b(p1v[rg]);
            }
            __builtin_amdgcn_wave_barrier();
            bf16x8 pa = *(bf16x8*)&ps[m16 * 32 + quad * 8];
            bf16x8 vb0 = *(bf16x8*)&Vt[m16 * 232 + p0 + quad * 8];
            bf16x8 vb1 = *(bf16x8*)&Vt[(m16 + 16) * 232 + p0 + quad * 8];
            o0 = __builtin_amdgcn_mfma_f32_16x16x32_bf16(pa, vb0, o0, 0, 0, 0);
            o1 = __builtin_amdgcn_mfma_f32_16x16x32_bf16(pa, vb1, o1, 0, 0, 0);
        }
#pragma unroll
        for (int rg = 0; rg < 4; ++rg) {
            int rglob = q0 + quad * 4 + rg;
            if (rglob < SS) {
                float inv = 1.f / lrow[rg];
                ctx[base + rglob * DDIM + m16] = o0[rg] * inv;
                ctx[base + rglob * DDIM + 16 + m16] = o1[rg] * inv;
            }
        }
    }
}

// ---------------- Gram matrix partials ----------------
__global__ __launch_bounds__(256) void gram_kernel(const float* __restrict__ A, int nrows,
                                                   float* __restrict__ part) {
    __shared__ float rows[16][64];
    int t = threadIdx.x;
    int i = t >> 2;            // 0..63
    int jb = (t & 3) * 16;     // 0/16/32/48
    float acc[16] = {};
    for (long base = (long)blockIdx.x * 16; base < nrows; base += (long)GRAM_NB * 16) {
        {
            int rr = t >> 4, d4 = (t & 15) * 4;
            long gr = base + rr;
            float4 vv = make_float4(0.f, 0.f, 0.f, 0.f);
            if (gr < nrows) vv = *(const float4*)&A[gr * DDIM + d4];
            *(float4*)&rows[rr][d4] = vv;
        }
        __syncthreads();
#pragma unroll
        for (int rr = 0; rr < 16; ++rr) {
            float ai = rows[rr][i];
            float4 r0 = *(const float4*)&rows[rr][jb];
            float4 r1 = *(const float4*)&rows[rr][jb + 4];
            float4 r2 = *(const float4*)&rows[rr][jb + 8];
            float4 r3 = *(const float4*)&rows[rr][jb + 12];
            acc[0] += ai * r0.x; acc[1] += ai * r0.y; acc[2] += ai * r0.z; acc[3] += ai * r0.w;
            acc[4] += ai * r1.x; acc[5] += ai * r1.y; acc[6] += ai * r1.z; acc[7] += ai * r1.w;
            acc[8] += ai * r2.x; acc[9] += ai * r2.y; acc[10] += ai * r2.z; acc[11] += ai * r2.w;
            acc[12] += ai * r3.x; acc[13] += ai * r3.y; acc[14] += ai * r3.z; acc[15] += ai * r3.w;
        }
        __syncthreads();
    }
    float* slab = part + (long)blockIdx.x * 4096 + i * 64 + jb;
#pragma unroll
    for (int g = 0; g < 4; ++g) {
        float4 o; o.x = acc[g * 4]; o.y = acc[g * 4 + 1]; o.z = acc[g * 4 + 2]; o.w = acc[g * 4 + 3];
        *(float4*)&slab[g * 4] = o;
    }
}

// out[p] = sum_b part[b*4096+p]
__global__ __launch_bounds__(256) void gram_reduce(const float* __restrict__ part,
                                                   float* __restrict__ out) {
    int p = blockIdx.x * 256 + threadIdx.x;   // 16 blocks
    float s = 0.f;
    for (int b = 0; b < GRAM_NB; ++b) s += part[(long)b * 4096 + p];
    out[p] = s;
}

// ---------------- right(): per-block partial sums of (1-C)ps^2 - 2ps ----------------
__global__ __launch_bounds__(256) void right_kernel(const float* __restrict__ x,
                                                    const float* __restrict__ item_emb,
                                                    const int* __restrict__ pos_seqs,
                                                    const float* __restrict__ pred_w,
                                                    float* __restrict__ rpart) {
    __shared__ float p_s[64];
    __shared__ float red[4];
    int t = threadIdx.x;
    if (t < 64) p_s[t] = pred_w[t];
    __syncthreads();
    int w = t >> 6, lane = t & 63;
    float local = 0.f;
    for (long row = (long)blockIdx.x * 4 + w; row < NROWS; row += (long)gridDim.x * 4) {
        int pi = pos_seqs[row];
        float val = x[row * DDIM + lane] * item_emb[(long)pi * DDIM + lane] * p_s[lane];
        float ps = wave_sum(val);           // lane-uniform
        local += (1.0f - CC) * ps * ps - 2.0f * ps;   // identical on all 64 lanes
    }
    if (lane == 0) red[w] = local;
    __syncthreads();
    if (t == 0) rpart[blockIdx.x] = red[0] + red[1] + red[2] + red[3];
}

// ---------------- per-parameter sum-of-squares ----------------
struct NormEntry { const float* p; int n; };
struct NormArgs { NormEntry e[30]; };

__global__ __launch_bounds__(256) void norms_kernel(NormArgs args, float* __restrict__ norms) {
    __shared__ float red[256];
    NormEntry en = args.e[blockIdx.x];
    float s = 0.f;
    for (int i = threadIdx.x; i < en.n; i += 256) { float v = en.p[i]; s += v * v; }
    red[threadIdx.x] = s;
    for (int o = 128; o > 0; o >>= 1) {
        __syncthreads();
        if (threadIdx.x < o) red[threadIdx.x] += red[threadIdx.x + o];
    }
    __syncthreads();
    if (threadIdx.x == 0) norms[blockIdx.x] = red[0];
}

// ---------------- final scalar ----------------
__global__ __launch_bounds__(256) void final_kernel(const float* __restrict__ EE,
                                                    const float* __restrict__ FF,
                                                    const float* __restrict__ pred_w,
                                                    const float* __restrict__ rpart,
                                                    const float* __restrict__ norms,
                                                    float* __restrict__ out) {
    __shared__ float p_s[64];
    __shared__ float redL[256];
    __shared__ float redT[256];
    __shared__ float redR[256];
    int t = threadIdx.x;
    if (t < 64) p_s[t] = pred_w[t];
    __syncthreads();
    float lf = 0.f, tr = 0.f, rs = 0.f;
    for (int p = t; p < 4096; p += 256) {
        int i = p >> 6, j = p & 63;
        float ee = EE[p];
        lf += FF[p] * ee * p_s[i] * p_s[j];
        if (i == j) tr += ee;
    }
    for (int i = t; i < 1024; i += 256) rs += rpart[i];
    redL[t] = lf; redT[t] = tr; redR[t] = rs;
    for (int o = 128; o > 0; o >>= 1) {
        __syncthreads();
        if (t < o) { redL[t] += redL[t + o]; redT[t] += redT[t + o]; redR[t] += redR[t + o]; }
    }
    __syncthreads();
    if (t == 0) {
        float reg = sqrtf(redT[0]);   // ||item_emb||_F = sqrt(trace(EE))
        for (int s = 0; s < 30; ++s) reg += sqrtf(norms[s]);
        out[0] = CC * redL[0] + redR[0] + 0.1f * reg;
    }
}

// ---------------- host ----------------
struct DevPtrs { float *x, *qin, *q, *k, *v, *ctx, *gpart; };

static DevPtrs fetch_ptrs() {
    DevPtrs p;
    (void)hipGetSymbolAddress((void**)&p.x,    HIP_SYMBOL(g_x));
    (void)hipGetSymbolAddress((void**)&p.qin,  HIP_SYMBOL(g_qin));
    (void)hipGetSymbolAddress((void**)&p.q,    HIP_SYMBOL(g_q));
    (void)hipGetSymbolAddress((void**)&p.k,    HIP_SYMBOL(g_k));
    (void)hipGetSymbolAddress((void**)&p.v,    HIP_SYMBOL(g_v));
    (void)hipGetSymbolAddress((void**)&p.ctx,  HIP_SYMBOL(g_ctx));
    (void)hipGetSymbolAddress((void**)&p.gpart,HIP_SYMBOL(g_gpart));
    return p;
}

extern "C" void kernel_launch(void* const* d_in, const int* in_sizes, int n_in,
                              void* d_out, int out_size, void* d_ws, size_t ws_size,
                              hipStream_t stream) {
    const int*   log_seqs = (const int*)d_in[1];
    const int*   pos_seqs = (const int*)d_in[2];
    const float* item_emb = (const float*)d_in[3];
    const float* pos_emb  = (const float*)d_in[4];
    const float* pred_w   = (const float*)d_in[5];
    const float* ln_w     = (const float*)d_in[6];
    const float* ln_b     = (const float*)d_in[7];
    const float* qkv_w    = (const float*)d_in[8];
    const float* qkv_b    = (const float*)d_in[9];
    const float* out_w    = (const float*)d_in[10];
    const float* out_b    = (const float*)d_in[11];
    const float* fc1_w    = (const float*)d_in[12];
    const float* fc1_b    = (const float*)d_in[13];
    const float* ffln_w   = (const float*)d_in[14];
    const float* ffln_b   = (const float*)d_in[15];
    const float* fc2_w    = (const float*)d_in[16];
    const float* fc2_b    = (const float*)d_in[17];
    const float* ffln2_w  = (const float*)d_in[18];
    const float* ffln2_b  = (const float*)d_in[19];

    static DevPtrs P = fetch_ptrs();   // first call is the uncaptured correctness call

    float* ws    = (float*)d_ws;
    float* rpart = ws;            // 1024
    float* nrm   = ws + 1024;     // 30
    float* EE    = ws + 2048;     // 4096
    float* FF    = ws + 6144;     // 4096

    embed_kernel<<<NROWS * 16 / 256, 256, 0, stream>>>(log_seqs, item_emb, pos_emb, P.x);

    const int GEMM_GRID = NROWS / 64;   // 1600

    for (int l = 0; l < LL; ++l) {
        const float* Wqkv = qkv_w + (long)l * 3 * 64 * 64;
        const float* Bqkv = qkv_b + (long)l * 192;
        qkv_fused<<<GEMM_GRID, 256, 0, stream>>>(
            P.x, Wqkv, Bqkv, ln_w + l * 64, ln_b + l * 64, P.qin, P.q, P.k, P.v);
        attn_kernel<<<BB * 2, 256, 0, stream>>>(P.q, P.k, P.v, P.ctx);
        ffn_fused<<<GEMM_GRID, 256, 0, stream>>>(
            P.ctx, P.qin,
            out_w + (long)l * 4096, out_b + l * 64,
            fc1_w + (long)l * 4096, fc1_b + l * 64,
            fc2_w + (long)l * 4096, fc2_b + l * 64,
            ffln_w + l * 64, ffln_b + l * 64,
            ffln2_w + l * 64, ffln2_b + l * 64,
            P.x);
    }

    gram_kernel<<<GRAM_NB, 256, 0, stream>>>(item_emb, 100001, P.gpart);
    gram_reduce<<<16, 256, 0, stream>>>(P.gpart, EE);
    gram_kernel<<<GRAM_NB, 256, 0, stream>>>(P.x, NROWS, P.gpart);
    gram_reduce<<<16, 256, 0, stream>>>(P.gpart, FF);
    right_kernel<<<1024, 256, 0, stream>>>(P.x, item_emb, pos_seqs, pred_w, rpart);

    NormArgs na;
    int s = 0;
    na.e[s++] = {pos_emb, (SS + 1) * DDIM};
    na.e[s++] = {pred_w, DDIM};
    for (int l = 0; l < LL; ++l) {
        na.e[s++] = {ln_w + l * 64, 64};
        na.e[s++] = {ln_b + l * 64, 64};
        na.e[s++] = {qkv_w + (long)l * 12288, 12288};
        na.e[s++] = {qkv_b + (long)l * 192, 192};
        na.e[s++] = {out_w + (long)l * 4096, 4096};
        na.e[s++] = {out_b + l * 64, 64};
        na.e[s++] = {fc1_w + (long)l * 4096, 4096};
        na.e[s++] = {fc1_b + l * 64, 64};
        na.e[s++] = {ffln_w + l * 64, 64};
        na.e[s++] = {ffln_b + l * 64, 64};
        na.e[s++] = {fc2_w + (long)l * 4096, 4096};
        na.e[s++] = {fc2_b + l * 64, 64};
        na.e[s++] = {ffln2_w + l * 64, 64};
        na.e[s++] = {ffln2_b + l * 64, 64};
    }
    norms_kernel<<<30, 256, 0, stream>>>(na, nrm);

    final_kernel<<<1, 256, 0, stream>>>(EE, FF, pred_w, rpart, nrm, (float*)d_out);
}

// Round 12
// 520.091 us; speedup vs baseline: 1.7342x; 1.0165x over previous
//
#include <hip/hip_runtime.h>
#include <math.h>

#define BB 512
#define SS 200
#define DDIM 64
#define HD 32
#define LL 2
#define NROWS (BB * SS)   // 102400
#define EPS 1e-8f
#define CC 0.001f
#define GRAM_NB 256

typedef __attribute__((ext_vector_type(8))) short bf16x8;
typedef __attribute__((ext_vector_type(4))) float f32x4;

// ---------------- static device buffers (activations) ----------------
__device__ float g_x[NROWS * DDIM];
__device__ float g_ctx[NROWS * DDIM];
__device__ unsigned short g_qb[NROWS * DDIM];
__device__ unsigned short g_kb[NROWS * DDIM];
__device__ unsigned short g_vb[NROWS * DDIM];
__device__ float g_gpart[GRAM_NB * 4096];   // gram per-block partials

// ---------------- helpers ----------------
__device__ __forceinline__ float wave_sum(float v) {
#pragma unroll
    for (int o = 32; o > 0; o >>= 1) v += __shfl_xor(v, o, 64);
    return v;
}

// bf16 pack (RNE)
__device__ __forceinline__ unsigned short f2b(float f) {
    unsigned u = __float_as_uint(f);
    return (unsigned short)((u + 0x7FFFu + ((u >> 16) & 1u)) >> 16);
}

// ---------------- embedding (float4) ----------------
__global__ __launch_bounds__(256) void embed_kernel(const int* __restrict__ log_seqs,
                                                    const float* __restrict__ item_emb,
                                                    const float* __restrict__ pos_emb,
                                                    float* __restrict__ x) {
    int tid = blockIdx.x * 256 + threadIdx.x;   // over NROWS*16
    int row = tid >> 4, q4 = tid & 15;
    int s = row % SS;
    int li = log_seqs[row];
    int poss = li ? (s + 1) : 0;
    float4 e = *(const float4*)&item_emb[li * DDIM + q4 * 4];
    float4 p = *(const float4*)&pos_emb[poss * DDIM + q4 * 4];
    float4 o;
    o.x = e.x * 8.0f + p.x; o.y = e.y * 8.0f + p.y;
    o.z = e.z * 8.0f + p.z; o.w = e.w * 8.0f + p.w;
    *(float4*)&x[row * DDIM + q4 * 4] = o;
}

// ---------------- tile staging helpers ----------------
__device__ __forceinline__ void stage_in(const float* __restrict__ G, float (* __restrict__ tile)[68],
                                         int t, long row0) {
#pragma unroll
    for (int rep = 0; rep < 4; ++rep) {
        int idx = t + rep * 256;
        int c = idx >> 4, d4 = (idx & 15) * 4;
        *(float4*)&tile[c][d4] = *(const float4*)&G[(row0 + c) * DDIM + d4];
    }
}

// Stage W (64 out x 64 in, row-major) TRANSPOSED into wt[d][c], via 4x4 block transpose.
__device__ __forceinline__ void stage_wT(const float* __restrict__ Wg, float (* __restrict__ wt)[68], int t) {
    int bi = t & 15, bj = t >> 4;   // bi: c-block, bj: d-block
    float rv[4][4];
#pragma unroll
    for (int e = 0; e < 4; ++e)
        *(float4*)rv[e] = *(const float4*)&Wg[(bi * 4 + e) * DDIM + bj * 4];
#pragma unroll
    for (int e = 0; e < 4; ++e) {
        float4 o;
        o.x = rv[0][e]; o.y = rv[1][e]; o.z = rv[2][e]; o.w = rv[3][e];
        *(float4*)&wt[bj * 4 + e][bi * 4] = o;
    }
}

// acc[i][j] += sum_d A[r0+i][d] * W[d][c0+j]   (W stored transposed: wt[d][c])
__device__ __forceinline__ void gemm_tile(const float (* __restrict__ A)[68],
                                          const float (* __restrict__ W)[68],
                                          int r0, int c0, float acc[4][4]) {
#pragma unroll
    for (int d = 0; d < 64; d += 4) {
        float4 a[4], wv[4];
#pragma unroll
        for (int i = 0; i < 4; ++i) a[i] = *(const float4*)&A[r0 + i][d];
#pragma unroll
        for (int tt = 0; tt < 4; ++tt) wv[tt] = *(const float4*)&W[d + tt][c0];
#pragma unroll
        for (int i = 0; i < 4; ++i) {
            float av[4] = {a[i].x, a[i].y, a[i].z, a[i].w};
#pragma unroll
            for (int tt = 0; tt < 4; ++tt) {
                acc[i][0] += av[tt] * wv[tt].x;
                acc[i][1] += av[tt] * wv[tt].y;
                acc[i][2] += av[tt] * wv[tt].z;
                acc[i][3] += av[tt] * wv[tt].w;
            }
        }
    }
}

// LayerNorm rows of src -> dst (thread t owns row t>>2, 16-col chunk (t&3)*16). In-place safe.
__device__ __forceinline__ void ln_rows(const float (* __restrict__ src)[68], float (* __restrict__ dst)[68],
                                        const float* __restrict__ w_s, const float* __restrict__ b_s,
                                        int t) {
    int rr = t >> 2, qd = (t & 3) * 16;
    float4 v[4];
#pragma unroll
    for (int g = 0; g < 4; ++g) v[g] = *(const float4*)&src[rr][qd + g * 4];
    float s1 = 0.f, s2 = 0.f;
#pragma unroll
    for (int g = 0; g < 4; ++g) {
        s1 += (v[g].x + v[g].y) + (v[g].z + v[g].w);
        s2 += (v[g].x * v[g].x + v[g].y * v[g].y) + (v[g].z * v[g].z + v[g].w * v[g].w);
    }
    s1 += __shfl_xor(s1, 1, 64); s1 += __shfl_xor(s1, 2, 64);
    s2 += __shfl_xor(s2, 1, 64); s2 += __shfl_xor(s2, 2, 64);
    float m = s1 * (1.f / 64.f);
    float var = s2 * (1.f / 64.f) - m * m;
    float rs = rsqrtf(var + EPS);
#pragma unroll
    for (int g = 0; g < 4; ++g) {
        float4 w4 = *(const float4*)&w_s[qd + g * 4];
        float4 b4 = *(const float4*)&b_s[qd + g * 4];
        float4 o;
        o.x = (v[g].x - m) * rs * w4.x + b4.x;
        o.y = (v[g].y - m) * rs * w4.y + b4.y;
        o.z = (v[g].z - m) * rs * w4.z + b4.z;
        o.w = (v[g].w - m) * rs * w4.w + b4.w;
        *(float4*)&dst[rr][qd + g * 4] = o;
    }
}

// Dual LayerNorm: a := LN1(a), b := LN2(a_old)
__device__ __forceinline__ void ln_rows2(float (* __restrict__ a)[68], float (* __restrict__ b)[68],
                                         const float* __restrict__ w1, const float* __restrict__ b1,
                                         const float* __restrict__ w2, const float* __restrict__ b2, int t) {
    int rr = t >> 2, qd = (t & 3) * 16;
    float4 v[4];
#pragma unroll
    for (int g = 0; g < 4; ++g) v[g] = *(const float4*)&a[rr][qd + g * 4];
    float s1 = 0.f, s2 = 0.f;
#pragma unroll
    for (int g = 0; g < 4; ++g) {
        s1 += (v[g].x + v[g].y) + (v[g].z + v[g].w);
        s2 += (v[g].x * v[g].x + v[g].y * v[g].y) + (v[g].z * v[g].z + v[g].w * v[g].w);
    }
    s1 += __shfl_xor(s1, 1, 64); s1 += __shfl_xor(s1, 2, 64);
    s2 += __shfl_xor(s2, 1, 64); s2 += __shfl_xor(s2, 2, 64);
    float m = s1 * (1.f / 64.f);
    float var = s2 * (1.f / 64.f) - m * m;
    float rs = rsqrtf(var + EPS);
#pragma unroll
    for (int g = 0; g < 4; ++g) {
        float4 w14 = *(const float4*)&w1[qd + g * 4];
        float4 b14 = *(const float4*)&b1[qd + g * 4];
        float4 w24 = *(const float4*)&w2[qd + g * 4];
        float4 b24 = *(const float4*)&b2[qd + g * 4];
        float nx = (v[g].x - m) * rs, ny = (v[g].y - m) * rs, nz = (v[g].z - m) * rs, nw = (v[g].w - m) * rs;
        float4 o1, o2;
        o1.x = nx * w14.x + b14.x; o1.y = ny * w14.y + b14.y; o1.z = nz * w14.z + b14.z; o1.w = nw * w14.w + b14.w;
        o2.x = nx * w24.x + b24.x; o2.y = ny * w24.y + b24.y; o2.z = nz * w24.z + b24.z; o2.w = nw * w24.w + b24.w;
        *(float4*)&a[rr][qd + g * 4] = o1;
        *(float4*)&b[rr][qd + g * 4] = o2;
    }
}

// ---------------- fused QKV: q = LN(x)@Wq, k,v = x@{Wk,Wv}; outputs bf16 ----------------
__global__ __launch_bounds__(256) void qkv_fused(const float* __restrict__ x,
                                                 const float* __restrict__ Wqkv,
                                                 const float* __restrict__ Bqkv,
                                                 const float* __restrict__ lnw,
                                                 const float* __restrict__ lnb,
                                                 unsigned short* __restrict__ qo,
                                                 unsigned short* __restrict__ ko,
                                                 unsigned short* __restrict__ vo) {
    __shared__ float A[64][68], B[64][68], W[64][68];
    __shared__ float lw[64], lb[64];
    int t = threadIdx.x;
    long row0 = (long)blockIdx.x * 64;
    stage_in(x, A, t, row0);
    stage_wT(Wqkv, W, t);
    if (t < 64) { lw[t] = lnw[t]; lb[t] = lnb[t]; }
    __syncthreads();
    ln_rows(A, B, lw, lb, t);
    __syncthreads();
    int tx = t & 15, ty = t >> 4, r0 = ty * 4, c0 = tx * 4;
    {
        float acc[4][4] = {};
        gemm_tile(B, W, r0, c0, acc);
        float4 b4 = *(const float4*)&Bqkv[c0];
        float bv[4] = {b4.x, b4.y, b4.z, b4.w};
#pragma unroll
        for (int i = 0; i < 4; ++i) {
            ushort4 o;
            o.x = f2b(acc[i][0] + bv[0]); o.y = f2b(acc[i][1] + bv[1]);
            o.z = f2b(acc[i][2] + bv[2]); o.w = f2b(acc[i][3] + bv[3]);
            *(ushort4*)&qo[(row0 + r0 + i) * DDIM + c0] = o;
        }
    }
    __syncthreads();
    stage_wT(Wqkv + 4096, W, t);
    __syncthreads();
    {
        float acc[4][4] = {};
        gemm_tile(A, W, r0, c0, acc);
        float4 b4 = *(const float4*)&Bqkv[64 + c0];
        float bv[4] = {b4.x, b4.y, b4.z, b4.w};
#pragma unroll
        for (int i = 0; i < 4; ++i) {
            ushort4 o;
            o.x = f2b(acc[i][0] + bv[0]); o.y = f2b(acc[i][1] + bv[1]);
            o.z = f2b(acc[i][2] + bv[2]); o.w = f2b(acc[i][3] + bv[3]);
            *(ushort4*)&ko[(row0 + r0 + i) * DDIM + c0] = o;
        }
    }
    __syncthreads();
    stage_wT(Wqkv + 8192, W, t);
    __syncthreads();
    {
        float acc[4][4] = {};
        gemm_tile(A, W, r0, c0, acc);
        float4 b4 = *(const float4*)&Bqkv[128 + c0];
        float bv[4] = {b4.x, b4.y, b4.z, b4.w};
#pragma unroll
        for (int i = 0; i < 4; ++i) {
            ushort4 o;
            o.x = f2b(acc[i][0] + bv[0]); o.y = f2b(acc[i][1] + bv[1]);
            o.z = f2b(acc[i][2] + bv[2]); o.w = f2b(acc[i][3] + bv[3]);
            *(ushort4*)&vo[(row0 + r0 + i) * DDIM + c0] = o;
        }
    }
}

// ---------------- fused out-proj + FFN (recomputes qin = LN(x; ln0)) ----------------
__global__ __launch_bounds__(256) void ffn_fused(const float* __restrict__ ctx,
                                                 const float* __restrict__ x,
                                                 const float* __restrict__ Wo, const float* __restrict__ bo,
                                                 const float* __restrict__ W1, const float* __restrict__ b1,
                                                 const float* __restrict__ W2, const float* __restrict__ b2,
                                                 const float* __restrict__ l0w, const float* __restrict__ l0b,
                                                 const float* __restrict__ l1w, const float* __restrict__ l1b,
                                                 const float* __restrict__ l2w, const float* __restrict__ l2b,
                                                 float* __restrict__ xout) {
    __shared__ float A[64][68], B[64][68], W[64][68];
    __shared__ float w0s[64], b0s[64], w1s[64], b1s[64], w2s[64], b2s[64];
    int t = threadIdx.x;
    long row0 = (long)blockIdx.x * 64;
    stage_in(ctx, A, t, row0);
    stage_in(x, B, t, row0);
    stage_wT(Wo, W, t);
    if (t < 64) {
        w0s[t] = l0w[t]; b0s[t] = l0b[t];
        w1s[t] = l1w[t]; b1s[t] = l1b[t];
        w2s[t] = l2w[t]; b2s[t] = l2b[t];
    }
    __syncthreads();
    ln_rows(B, B, w0s, b0s, t);          // B := qin = LN(x; ln0)  (own rows, in-place)
    int tx = t & 15, ty = t >> 4, r0 = ty * 4, c0 = tx * 4;
    float x1[4][4] = {};
    gemm_tile(A, W, r0, c0, x1);
    __syncthreads();                     // B(ln) visible; A/W reads done
    {
        float4 b4 = *(const float4*)&bo[c0];
        float bv[4] = {b4.x, b4.y, b4.z, b4.w};
#pragma unroll
        for (int i = 0; i < 4; ++i)
#pragma unroll
            for (int j = 0; j < 4; ++j) x1[i][j] += bv[j] + B[r0 + i][c0 + j];
    }
    __syncthreads();
#pragma unroll
    for (int i = 0; i < 4; ++i) {
        float4 o; o.x = x1[i][0]; o.y = x1[i][1]; o.z = x1[i][2]; o.w = x1[i][3];
        *(float4*)&A[r0 + i][c0] = o;
    }
    __syncthreads();
    ln_rows2(A, B, w1s, b1s, w2s, b2s, t);
    stage_wT(W1, W, t);
    __syncthreads();
    float h[4][4] = {};
    gemm_tile(A, W, r0, c0, h);
    {
        float4 b4 = *(const float4*)&b1[c0];
        float bv[4] = {b4.x, b4.y, b4.z, b4.w};
#pragma unroll
        for (int i = 0; i < 4; ++i)
#pragma unroll
            for (int j = 0; j < 4; ++j) h[i][j] = fmaxf(h[i][j] + bv[j], 0.f);
    }
    __syncthreads();
#pragma unroll
    for (int i = 0; i < 4; ++i) {
        float4 o; o.x = h[i][0]; o.y = h[i][1]; o.z = h[i][2]; o.w = h[i][3];
        *(float4*)&A[r0 + i][c0] = o;
    }
    stage_wT(W2, W, t);
    __syncthreads();
    float o3[4][4] = {};
    gemm_tile(A, W, r0, c0, o3);
    {
        float4 b4 = *(const float4*)&b2[c0];
        float bv[4] = {b4.x, b4.y, b4.z, b4.w};
#pragma unroll
        for (int i = 0; i < 4; ++i) {
            float4 o;
            o.x = o3[i][0] + bv[0] + B[r0 + i][c0 + 0];
            o.y = o3[i][1] + bv[1] + B[r0 + i][c0 + 1];
            o.z = o3[i][2] + bv[2] + B[r0 + i][c0 + 2];
            o.w = o3[i][3] + bv[3] + B[r0 + i][c0 + 3];
            *(float4*)&xout[(row0 + r0 + i) * DDIM + c0] = o;
        }
    }
}

// ---------------- MFMA flash attention, one block per (b, head), 4 waves ----------------
// Inputs q,k,v are bf16. K staged row-major, V staged transposed (stride 232).
__global__ __launch_bounds__(256) void attn_kernel(const unsigned short* __restrict__ q,
                                                   const unsigned short* __restrict__ k,
                                                   const unsigned short* __restrict__ v,
                                                   float* __restrict__ ctx) {
    __shared__ unsigned short Kb[224 * 32];    // Kb[kk][d], zero for kk>=200
    __shared__ unsigned short Vt[32 * 232];    // Vt[d][kk], zero for kk>=200
    __shared__ unsigned short Ps[4][16 * 32];  // per-wave P buffer
    int b = blockIdx.x >> 1, h = blockIdx.x & 1;
    int t = threadIdx.x;
    const long base = (long)b * (SS * DDIM) + h * HD;
    for (int i = t; i < 224 * 8; i += 256) {   // ushort4 chunks
        int kk = i >> 3, d4 = (i & 7) * 4;
        ushort4 kv = make_ushort4(0, 0, 0, 0), vv = make_ushort4(0, 0, 0, 0);
        if (kk < SS) {
            kv = *(const ushort4*)&k[base + kk * DDIM + d4];
            vv = *(const ushort4*)&v[base + kk * DDIM + d4];
        }
        *(ushort4*)&Kb[kk * 32 + d4] = kv;
        Vt[(d4 + 0) * 232 + kk] = vv.x;
        Vt[(d4 + 1) * 232 + kk] = vv.y;
        Vt[(d4 + 2) * 232 + kk] = vv.z;
        Vt[(d4 + 3) * 232 + kk] = vv.w;
    }
    __syncthreads();
    int w = t >> 6, lane = t & 63;
    int m16 = lane & 15, quad = lane >> 4;
    const float scale = 0.17677669529663687f;   // 1/sqrt(32)
    unsigned short* ps = Ps[w];
    for (int qt = w; qt < 13; qt += 4) {
        int q0 = qt * 16;
        int qrow = q0 + m16; if (qrow > SS - 1) qrow = SS - 1;
        bf16x8 qa = *(const bf16x8*)&q[base + qrow * DDIM + quad * 8];
        f32x4 o0 = {0.f, 0.f, 0.f, 0.f}, o1 = {0.f, 0.f, 0.f, 0.f};
        float mrow[4] = {-1e30f, -1e30f, -1e30f, -1e30f};
        float lrow[4] = {0.f, 0.f, 0.f, 0.f};
        int np = (qt + 2) >> 1;
        for (int pi = 0; pi < np; ++pi) {
            int p0 = pi * 32;
            bf16x8 kb0 = *(bf16x8*)&Kb[(p0 + m16) * 32 + quad * 8];
            bf16x8 kb1 = *(bf16x8*)&Kb[(p0 + 16 + m16) * 32 + quad * 8];
            f32x4 z = {0.f, 0.f, 0.f, 0.f};
            f32x4 s0 = __builtin_amdgcn_mfma_f32_16x16x32_bf16(qa, kb0, z, 0, 0, 0);
            f32x4 s1 = __builtin_amdgcn_mfma_f32_16x16x32_bf16(qa, kb1, z, 0, 0, 0);
            int col0 = p0 + m16, col1 = col0 + 16;
            float p0v[4], p1v[4];
#pragma unroll
            for (int rg = 0; rg < 4; ++rg) {
                int rglob = q0 + quad * 4 + rg;
                float v0 = (col0 <= rglob && col0 < SS) ? s0[rg] * scale : -1e30f;
                float v1 = (col1 <= rglob && col1 < SS) ? s1[rg] * scale : -1e30f;
                float mx = fmaxf(v0, v1);
#pragma unroll
                for (int o = 1; o <= 8; o <<= 1) mx = fmaxf(mx, __shfl_xor(mx, o, 64));
                float mn = fmaxf(mrow[rg], mx);
                float al = __expf(mrow[rg] - mn);
                float e0 = __expf(v0 - mn), e1 = __expf(v1 - mn);
                float sm = e0 + e1;
#pragma unroll
                for (int o = 1; o <= 8; o <<= 1) sm += __shfl_xor(sm, o, 64);
                lrow[rg] = lrow[rg] * al + sm;
                mrow[rg] = mn;
                o0[rg] *= al; o1[rg] *= al;
                p0v[rg] = e0; p1v[rg] = e1;
            }
            __builtin_amdgcn_wave_barrier();
#pragma unroll
            for (int rg = 0; rg < 4; ++rg) {
                int row = quad * 4 + rg;
                ps[row * 32 + m16] = f2b(p0v[rg]);
                ps[row * 32 + 16 + m16] = f2b(p1v[rg]);
            }
            __builtin_amdgcn_wave_barrier();
            bf16x8 pa = *(bf16x8*)&ps[m16 * 32 + quad * 8];
            bf16x8 vb0 = *(bf16x8*)&Vt[m16 * 232 + p0 + quad * 8];
            bf16x8 vb1 = *(bf16x8*)&Vt[(m16 + 16) * 232 + p0 + quad * 8];
            o0 = __builtin_amdgcn_mfma_f32_16x16x32_bf16(pa, vb0, o0, 0, 0, 0);
            o1 = __builtin_amdgcn_mfma_f32_16x16x32_bf16(pa, vb1, o1, 0, 0, 0);
        }
#pragma unroll
        for (int rg = 0; rg < 4; ++rg) {
            int rglob = q0 + quad * 4 + rg;
            if (rglob < SS) {
                float inv = 1.f / lrow[rg];
                ctx[base + rglob * DDIM + m16] = o0[rg] * inv;
                ctx[base + rglob * DDIM + 16 + m16] = o1[rg] * inv;
            }
        }
    }
}

// ---------------- Gram matrix partials ----------------
__global__ __launch_bounds__(256) void gram_kernel(const float* __restrict__ A, int nrows,
                                                   float* __restrict__ part) {
    __shared__ float rows[16][64];
    int t = threadIdx.x;
    int i = t >> 2;            // 0..63
    int jb = (t & 3) * 16;     // 0/16/32/48
    float acc[16] = {};
    for (long base = (long)blockIdx.x * 16; base < nrows; base += (long)GRAM_NB * 16) {
        {
            int rr = t >> 4, d4 = (t & 15) * 4;
            long gr = base + rr;
            float4 vv = make_float4(0.f, 0.f, 0.f, 0.f);
            if (gr < nrows) vv = *(const float4*)&A[gr * DDIM + d4];
            *(float4*)&rows[rr][d4] = vv;
        }
        __syncthreads();
#pragma unroll
        for (int rr = 0; rr < 16; ++rr) {
            float ai = rows[rr][i];
            float4 r0 = *(const float4*)&rows[rr][jb];
            float4 r1 = *(const float4*)&rows[rr][jb + 4];
            float4 r2 = *(const float4*)&rows[rr][jb + 8];
            float4 r3 = *(const float4*)&rows[rr][jb + 12];
            acc[0] += ai * r0.x; acc[1] += ai * r0.y; acc[2] += ai * r0.z; acc[3] += ai * r0.w;
            acc[4] += ai * r1.x; acc[5] += ai * r1.y; acc[6] += ai * r1.z; acc[7] += ai * r1.w;
            acc[8] += ai * r2.x; acc[9] += ai * r2.y; acc[10] += ai * r2.z; acc[11] += ai * r2.w;
            acc[12] += ai * r3.x; acc[13] += ai * r3.y; acc[14] += ai * r3.z; acc[15] += ai * r3.w;
        }
        __syncthreads();
    }
    float* slab = part + (long)blockIdx.x * 4096 + i * 64 + jb;
#pragma unroll
    for (int g = 0; g < 4; ++g) {
        float4 o; o.x = acc[g * 4]; o.y = acc[g * 4 + 1]; o.z = acc[g * 4 + 2]; o.w = acc[g * 4 + 3];
        *(float4*)&slab[g * 4] = o;
    }
}

// out[p] = sum_b part[b*4096+p]
__global__ __launch_bounds__(256) void gram_reduce(const float* __restrict__ part,
                                                   float* __restrict__ out) {
    int p = blockIdx.x * 256 + threadIdx.x;   // 16 blocks
    float s = 0.f;
    for (int b = 0; b < GRAM_NB; ++b) s += part[(long)b * 4096 + p];
    out[p] = s;
}

// ---------------- right(): per-block partial sums of (1-C)ps^2 - 2ps ----------------
__global__ __launch_bounds__(256) void right_kernel(const float* __restrict__ x,
                                                    const float* __restrict__ item_emb,
                                                    const int* __restrict__ pos_seqs,
                                                    const float* __restrict__ pred_w,
                                                    float* __restrict__ rpart) {
    __shared__ float p_s[64];
    __shared__ float red[4];
    int t = threadIdx.x;
    if (t < 64) p_s[t] = pred_w[t];
    __syncthreads();
    int w = t >> 6, lane = t & 63;
    float local = 0.f;
    for (long row = (long)blockIdx.x * 4 + w; row < NROWS; row += (long)gridDim.x * 4) {
        int pi = pos_seqs[row];
        float val = x[row * DDIM + lane] * item_emb[(long)pi * DDIM + lane] * p_s[lane];
        float ps = wave_sum(val);           // lane-uniform
        local += (1.0f - CC) * ps * ps - 2.0f * ps;   // identical on all 64 lanes
    }
    if (lane == 0) red[w] = local;
    __syncthreads();
    if (t == 0) rpart[blockIdx.x] = red[0] + red[1] + red[2] + red[3];
}

// ---------------- per-parameter sum-of-squares ----------------
struct NormEntry { const float* p; int n; };
struct NormArgs { NormEntry e[30]; };

__global__ __launch_bounds__(256) void norms_kernel(NormArgs args, float* __restrict__ norms) {
    __shared__ float red[256];
    NormEntry en = args.e[blockIdx.x];
    float s = 0.f;
    for (int i = threadIdx.x; i < en.n; i += 256) { float v = en.p[i]; s += v * v; }
    red[threadIdx.x] = s;
    for (int o = 128; o > 0; o >>= 1) {
        __syncthreads();
        if (threadIdx.x < o) red[threadIdx.x] += red[threadIdx.x + o];
    }
    __syncthreads();
    if (threadIdx.x == 0) norms[blockIdx.x] = red[0];
}

// ---------------- final scalar ----------------
__global__ __launch_bounds__(256) void final_kernel(const float* __restrict__ EE,
                                                    const float* __restrict__ FF,
                                                    const float* __restrict__ pred_w,
                                                    const float* __restrict__ rpart,
                                                    const float* __restrict__ norms,
                                                    float* __restrict__ out) {
    __shared__ float p_s[64];
    __shared__ float redL[256];
    __shared__ float redT[256];
    __shared__ float redR[256];
    int t = threadIdx.x;
    if (t < 64) p_s[t] = pred_w[t];
    __syncthreads();
    float lf = 0.f, tr = 0.f, rs = 0.f;
    for (int p = t; p < 4096; p += 256) {
        int i = p >> 6, j = p & 63;
        float ee = EE[p];
        lf += FF[p] * ee * p_s[i] * p_s[j];
        if (i == j) tr += ee;
    }
    for (int i = t; i < 1024; i += 256) rs += rpart[i];
    redL[t] = lf; redT[t] = tr; redR[t] = rs;
    for (int o = 128; o > 0; o >>= 1) {
        __syncthreads();
        if (t < o) { redL[t] += redL[t + o]; redT[t] += redT[t + o]; redR[t] += redR[t + o]; }
    }
    __syncthreads();
    if (t == 0) {
        float reg = sqrtf(redT[0]);   // ||item_emb||_F = sqrt(trace(EE))
        for (int s = 0; s < 30; ++s) reg += sqrtf(norms[s]);
        out[0] = CC * redL[0] + redR[0] + 0.1f * reg;
    }
}

// ---------------- host ----------------
struct DevPtrs { float *x, *ctx, *gpart; unsigned short *qb, *kb, *vb; };

static DevPtrs fetch_ptrs() {
    DevPtrs p;
    (void)hipGetSymbolAddress((void**)&p.x,    HIP_SYMBOL(g_x));
    (void)hipGetSymbolAddress((void**)&p.ctx,  HIP_SYMBOL(g_ctx));
    (void)hipGetSymbolAddress((void**)&p.gpart,HIP_SYMBOL(g_gpart));
    (void)hipGetSymbolAddress((void**)&p.qb,   HIP_SYMBOL(g_qb));
    (void)hipGetSymbolAddress((void**)&p.kb,   HIP_SYMBOL(g_kb));
    (void)hipGetSymbolAddress((void**)&p.vb,   HIP_SYMBOL(g_vb));
    return p;
}

extern "C" void kernel_launch(void* const* d_in, const int* in_sizes, int n_in,
                              void* d_out, int out_size, void* d_ws, size_t ws_size,
                              hipStream_t stream) {
    const int*   log_seqs = (const int*)d_in[1];
    const int*   pos_seqs = (const int*)d_in[2];
    const float* item_emb = (const float*)d_in[3];
    const float* pos_emb  = (const float*)d_in[4];
    const float* pred_w   = (const float*)d_in[5];
    const float* ln_w     = (const float*)d_in[6];
    const float* ln_b     = (const float*)d_in[7];
    const float* qkv_w    = (const float*)d_in[8];
    const float* qkv_b    = (const float*)d_in[9];
    const float* out_w    = (const float*)d_in[10];
    const float* out_b    = (const float*)d_in[11];
    const float* fc1_w    = (const float*)d_in[12];
    const float* fc1_b    = (const float*)d_in[13];
    const float* ffln_w   = (const float*)d_in[14];
    const float* ffln_b   = (const float*)d_in[15];
    const float* fc2_w    = (const float*)d_in[16];
    const float* fc2_b    = (const float*)d_in[17];
    const float* ffln2_w  = (const float*)d_in[18];
    const float* ffln2_b  = (const float*)d_in[19];

    static DevPtrs P = fetch_ptrs();   // first call is the uncaptured correctness call

    float* ws    = (float*)d_ws;
    float* rpart = ws;            // 1024
    float* nrm   = ws + 1024;     // 30
    float* EE    = ws + 2048;     // 4096
    float* FF    = ws + 6144;     // 4096

    embed_kernel<<<NROWS * 16 / 256, 256, 0, stream>>>(log_seqs, item_emb, pos_emb, P.x);

    const int GEMM_GRID = NROWS / 64;   // 1600

    for (int l = 0; l < LL; ++l) {
        const float* Wqkv = qkv_w + (long)l * 3 * 64 * 64;
        const float* Bqkv = qkv_b + (long)l * 192;
        qkv_fused<<<GEMM_GRID, 256, 0, stream>>>(
            P.x, Wqkv, Bqkv, ln_w + l * 64, ln_b + l * 64, P.qb, P.kb, P.vb);
        attn_kernel<<<BB * 2, 256, 0, stream>>>(P.qb, P.kb, P.vb, P.ctx);
        ffn_fused<<<GEMM_GRID, 256, 0, stream>>>(
            P.ctx, P.x,
            out_w + (long)l * 4096, out_b + l * 64,
            fc1_w + (long)l * 4096, fc1_b + l * 64,
            fc2_w + (long)l * 4096, fc2_b + l * 64,
            ln_w + l * 64, ln_b + l * 64,
            ffln_w + l * 64, ffln_b + l * 64,
            ffln2_w + l * 64, ffln2_b + l * 64,
            P.x);
    }

    gram_kernel<<<GRAM_NB, 256, 0, stream>>>(item_emb, 100001, P.gpart);
    gram_reduce<<<16, 256, 0, stream>>>(P.gpart, EE);
    gram_kernel<<<GRAM_NB, 256, 0, stream>>>(P.x, NROWS, P.gpart);
    gram_reduce<<<16, 256, 0, stream>>>(P.gpart, FF);
    right_kernel<<<1024, 256, 0, stream>>>(P.x, item_emb, pos_seqs, pred_w, rpart);

    NormArgs na;
    int s = 0;
    na.e[s++] = {pos_emb, (SS + 1) * DDIM};
    na.e[s++] = {pred_w, DDIM};
    for (int l = 0; l < LL; ++l) {
        na.e[s++] = {ln_w + l * 64, 64};
        na.e[s++] = {ln_b + l * 64, 64};
        na.e[s++] = {qkv_w + (long)l * 12288, 12288};
        na.e[s++] = {qkv_b + (long)l * 192, 192};
        na.e[s++] = {out_w + (long)l * 4096, 4096};
        na.e[s++] = {out_b + l * 64, 64};
        na.e[s++] = {fc1_w + (long)l * 4096, 4096};
        na.e[s++] = {fc1_b + l * 64, 64};
        na.e[s++] = {ffln_w + l * 64, 64};
        na.e[s++] = {ffln_b + l * 64, 64};
        na.e[s++] = {fc2_w + (long)l * 4096, 4096};
        na.e[s++] = {fc2_b + l * 64, 64};
        na.e[s++] = {ffln2_w + l * 64, 64};
        na.e[s++] = {ffln2_b + l * 64, 64};
    }
    norms_kernel<<<30, 256, 0, stream>>>(na, nrm);

    final_kernel<<<1, 256, 0, stream>>>(EE, FF, pred_w, rpart, nrm, (float*)d_out);
}

// Round 13
// 411.372 us; speedup vs baseline: 2.1925x; 1.2643x over previous
//
#include <hip/hip_runtime.h>
#include <math.h>

#define BB 512
#define SS 200
#define DDIM 64
#define HD 32
#define LL 2
#define NROWS (BB * SS)   // 102400
#define EPS 1e-8f
#define CC 0.001f
#define GRAM_NB 256
#define LSTRIDE 72

typedef __attribute__((ext_vector_type(8))) short bf16x8;
typedef __attribute__((ext_vector_type(4))) float f32x4;

// ---------------- static device buffers (activations) ----------------
__device__ float g_x[NROWS * DDIM];
__device__ float g_ctx[NROWS * DDIM];
__device__ unsigned short g_qb[NROWS * DDIM];
__device__ unsigned short g_kb[NROWS * DDIM];
__device__ unsigned short g_vb[NROWS * DDIM];
__device__ float g_gpart[GRAM_NB * 4096];   // gram per-block partials

// ---------------- helpers ----------------
__device__ __forceinline__ float wave_sum(float v) {
#pragma unroll
    for (int o = 32; o > 0; o >>= 1) v += __shfl_xor(v, o, 64);
    return v;
}
__device__ __forceinline__ unsigned short f2b(float f) {
    unsigned u = __float_as_uint(f);
    return (unsigned short)((u + 0x7FFFu + ((u >> 16) & 1u)) >> 16);
}
__device__ __forceinline__ float b2f(unsigned short u) {
    return __uint_as_float(((unsigned)u) << 16);
}

// ---------------- embedding (float4) ----------------
__global__ __launch_bounds__(256) void embed_kernel(const int* __restrict__ log_seqs,
                                                    const float* __restrict__ item_emb,
                                                    const float* __restrict__ pos_emb,
                                                    float* __restrict__ x) {
    int tid = blockIdx.x * 256 + threadIdx.x;   // over NROWS*16
    int row = tid >> 4, q4 = tid & 15;
    int s = row % SS;
    int li = log_seqs[row];
    int poss = li ? (s + 1) : 0;
    float4 e = *(const float4*)&item_emb[li * DDIM + q4 * 4];
    float4 p = *(const float4*)&pos_emb[poss * DDIM + q4 * 4];
    float4 o;
    o.x = e.x * 8.0f + p.x; o.y = e.y * 8.0f + p.y;
    o.z = e.z * 8.0f + p.z; o.w = e.w * 8.0f + p.w;
    *(float4*)&x[row * DDIM + q4 * 4] = o;
}

// ---------------- MFMA GEMM staging helpers (bf16 LDS, stride 72) ----------------
__device__ __forceinline__ void stage_bf16_tile(const float* __restrict__ G, unsigned short* __restrict__ L,
                                                int t, long row0) {
#pragma unroll
    for (int rep = 0; rep < 4; ++rep) {
        int idx = t + rep * 256;
        int r = idx >> 4, c4 = (idx & 15) * 4;
        float4 f = *(const float4*)&G[(row0 + r) * DDIM + c4];
        ushort4 o; o.x = f2b(f.x); o.y = f2b(f.y); o.z = f2b(f.z); o.w = f2b(f.w);
        *(ushort4*)&L[r * LSTRIDE + c4] = o;
    }
}

__device__ __forceinline__ void stage_w_bf16(const float* __restrict__ Wg, unsigned short* __restrict__ L, int t) {
#pragma unroll
    for (int rep = 0; rep < 4; ++rep) {
        int idx = t + rep * 256;
        int r = idx >> 4, c4 = (idx & 15) * 4;
        float4 f = *(const float4*)&Wg[r * DDIM + c4];
        ushort4 o; o.x = f2b(f.x); o.y = f2b(f.y); o.z = f2b(f.z); o.w = f2b(f.w);
        *(ushort4*)&L[r * LSTRIDE + c4] = o;
    }
}

// LN(x rows) -> bf16 LDS tile. thread t: row t>>2, 16-col chunk (t&3)*16.
__device__ __forceinline__ void stage_ln_bf16(const float* __restrict__ x, unsigned short* __restrict__ L,
                                              const float* __restrict__ lnw, const float* __restrict__ lnb,
                                              int t, long row0) {
    int rr = t >> 2, qd = (t & 3) * 16;
    float4 v[4];
#pragma unroll
    for (int g = 0; g < 4; ++g) v[g] = *(const float4*)&x[(row0 + rr) * DDIM + qd + g * 4];
    float s1 = 0.f, s2 = 0.f;
#pragma unroll
    for (int g = 0; g < 4; ++g) {
        s1 += (v[g].x + v[g].y) + (v[g].z + v[g].w);
        s2 += (v[g].x * v[g].x + v[g].y * v[g].y) + (v[g].z * v[g].z + v[g].w * v[g].w);
    }
    s1 += __shfl_xor(s1, 1, 64); s1 += __shfl_xor(s1, 2, 64);
    s2 += __shfl_xor(s2, 1, 64); s2 += __shfl_xor(s2, 2, 64);
    float m = s1 * (1.f / 64.f);
    float var = s2 * (1.f / 64.f) - m * m;
    float rs = rsqrtf(var + EPS);
#pragma unroll
    for (int g = 0; g < 4; ++g) {
        float4 w4 = *(const float4*)&lnw[qd + g * 4];
        float4 b4 = *(const float4*)&lnb[qd + g * 4];
        ushort4 o;
        o.x = f2b((v[g].x - m) * rs * w4.x + b4.x);
        o.y = f2b((v[g].y - m) * rs * w4.y + b4.y);
        o.z = f2b((v[g].z - m) * rs * w4.z + b4.z);
        o.w = f2b((v[g].w - m) * rs * w4.w + b4.w);
        *(ushort4*)&L[rr * LSTRIDE + qd + g * 4] = o;
    }
}

// 64x64x64 GEMM slice for wave w: out rows w16..w16+15, all 64 cols.
// A[m][k] bf16 LDS; B[k][n] = Wrow-major bf16 LDS (frag = row n, consecutive k).
__device__ __forceinline__ void mfma_gemm(const unsigned short* __restrict__ A,
                                          const unsigned short* __restrict__ B,
                                          int w16, int m16, int quad, f32x4 acc[4]) {
    bf16x8 a0 = *(const bf16x8*)&A[(w16 + m16) * LSTRIDE + quad * 8];
    bf16x8 a1 = *(const bf16x8*)&A[(w16 + m16) * LSTRIDE + 32 + quad * 8];
#pragma unroll
    for (int nt = 0; nt < 4; ++nt) {
        bf16x8 b0 = *(const bf16x8*)&B[(nt * 16 + m16) * LSTRIDE + quad * 8];
        bf16x8 b1 = *(const bf16x8*)&B[(nt * 16 + m16) * LSTRIDE + 32 + quad * 8];
        acc[nt] = __builtin_amdgcn_mfma_f32_16x16x32_bf16(a0, b0, acc[nt], 0, 0, 0);
        acc[nt] = __builtin_amdgcn_mfma_f32_16x16x32_bf16(a1, b1, acc[nt], 0, 0, 0);
    }
}

// ---------------- fused QKV (MFMA): q = LN(x)@Wq^T, k,v = x@{Wk,Wv}^T; bf16 out ----------------
__global__ __launch_bounds__(256) void qkv_fused(const float* __restrict__ x,
                                                 const float* __restrict__ Wqkv,
                                                 const float* __restrict__ Bqkv,
                                                 const float* __restrict__ lnw,
                                                 const float* __restrict__ lnb,
                                                 unsigned short* __restrict__ qo,
                                                 unsigned short* __restrict__ ko,
                                                 unsigned short* __restrict__ vo) {
    __shared__ unsigned short Ab[64 * LSTRIDE], Lb[64 * LSTRIDE];
    __shared__ unsigned short Wq[64 * LSTRIDE], Wk[64 * LSTRIDE], Wv[64 * LSTRIDE];
    int t = threadIdx.x;
    long row0 = (long)blockIdx.x * 64;
    stage_bf16_tile(x, Ab, t, row0);
    stage_ln_bf16(x, Lb, lnw, lnb, t, row0);
    stage_w_bf16(Wqkv, Wq, t);
    stage_w_bf16(Wqkv + 4096, Wk, t);
    stage_w_bf16(Wqkv + 8192, Wv, t);
    __syncthreads();
    int w16 = (t >> 6) * 16, lane = t & 63, m16 = lane & 15, quad = lane >> 4;
    f32x4 zero = {0.f, 0.f, 0.f, 0.f};
    {
        f32x4 acc[4] = {zero, zero, zero, zero};
        mfma_gemm(Lb, Wq, w16, m16, quad, acc);
#pragma unroll
        for (int nt = 0; nt < 4; ++nt) {
            int n = nt * 16 + m16;
            float bb = Bqkv[n];
#pragma unroll
            for (int rg = 0; rg < 4; ++rg)
                qo[(row0 + w16 + quad * 4 + rg) * DDIM + n] = f2b(acc[nt][rg] + bb);
        }
    }
    {
        f32x4 acc[4] = {zero, zero, zero, zero};
        mfma_gemm(Ab, Wk, w16, m16, quad, acc);
#pragma unroll
        for (int nt = 0; nt < 4; ++nt) {
            int n = nt * 16 + m16;
            float bb = Bqkv[64 + n];
#pragma unroll
            for (int rg = 0; rg < 4; ++rg)
                ko[(row0 + w16 + quad * 4 + rg) * DDIM + n] = f2b(acc[nt][rg] + bb);
        }
    }
    {
        f32x4 acc[4] = {zero, zero, zero, zero};
        mfma_gemm(Ab, Wv, w16, m16, quad, acc);
#pragma unroll
        for (int nt = 0; nt < 4; ++nt) {
            int n = nt * 16 + m16;
            float bb = Bqkv[128 + n];
#pragma unroll
            for (int rg = 0; rg < 4; ++rg)
                vo[(row0 + w16 + quad * 4 + rg) * DDIM + n] = f2b(acc[nt][rg] + bb);
        }
    }
}

// ---------------- fused out-proj + FFN (MFMA, wave-local chains) ----------------
// x1 = qin + ctx@Wo^T + bo; h = relu(LN1(x1)@W1^T + b1); x = h@W2^T + b2 + LN2(x1)
__global__ __launch_bounds__(256) void ffn_fused(const float* __restrict__ ctx,
                                                 const float* __restrict__ x,
                                                 const float* __restrict__ Wo, const float* __restrict__ bo,
                                                 const float* __restrict__ W1, const float* __restrict__ b1,
                                                 const float* __restrict__ W2, const float* __restrict__ b2,
                                                 const float* __restrict__ l0w, const float* __restrict__ l0b,
                                                 const float* __restrict__ l1w, const float* __restrict__ l1b,
                                                 const float* __restrict__ l2w, const float* __restrict__ l2b,
                                                 float* __restrict__ xout) {
    __shared__ unsigned short Cb[64 * LSTRIDE], Qb[64 * LSTRIDE];
    __shared__ unsigned short W0s[64 * LSTRIDE], W1s[64 * LSTRIDE], W2s[64 * LSTRIDE];
    __shared__ float vecs[7][64];   // bo,b1,b2,l1w,l1b,l2w,l2b
    int t = threadIdx.x;
    long row0 = (long)blockIdx.x * 64;
    stage_bf16_tile(ctx, Cb, t, row0);
    stage_ln_bf16(x, Qb, l0w, l0b, t, row0);   // qin = LN(x; ln0), bf16
    stage_w_bf16(Wo, W0s, t);
    stage_w_bf16(W1, W1s, t);
    stage_w_bf16(W2, W2s, t);
    if (t < 64) {
        vecs[0][t] = bo[t]; vecs[1][t] = b1[t]; vecs[2][t] = b2[t];
        vecs[3][t] = l1w[t]; vecs[4][t] = l1b[t]; vecs[5][t] = l2w[t]; vecs[6][t] = l2b[t];
    }
    __syncthreads();
    int w16 = (t >> 6) * 16, lane = t & 63, m16 = lane & 15, quad = lane >> 4;
    f32x4 zero = {0.f, 0.f, 0.f, 0.f};
    // GEMM1: x1 = ctx@Wo + bo + qin
    f32x4 acc1[4] = {zero, zero, zero, zero};
    mfma_gemm(Cb, W0s, w16, m16, quad, acc1);
    float x1[4][4];
#pragma unroll
    for (int nt = 0; nt < 4; ++nt) {
        int n = nt * 16 + m16;
        float bb = vecs[0][n];
#pragma unroll
        for (int rg = 0; rg < 4; ++rg) {
            int m = w16 + quad * 4 + rg;
            x1[nt][rg] = acc1[nt][rg] + bb + b2f(Qb[m * LSTRIDE + n]);
        }
    }
    // dual LN of x1 (row stats via quad shfl over m16 bits)
    float ln1v[4][4], ln2v[4][4];
#pragma unroll
    for (int rg = 0; rg < 4; ++rg) {
        float s1 = (x1[0][rg] + x1[1][rg]) + (x1[2][rg] + x1[3][rg]);
        float s2 = x1[0][rg] * x1[0][rg] + x1[1][rg] * x1[1][rg]
                 + x1[2][rg] * x1[2][rg] + x1[3][rg] * x1[3][rg];
#pragma unroll
        for (int o = 1; o <= 8; o <<= 1) { s1 += __shfl_xor(s1, o, 64); s2 += __shfl_xor(s2, o, 64); }
        float mean = s1 * (1.f / 64.f);
        float var = s2 * (1.f / 64.f) - mean * mean;
        float rs = rsqrtf(var + EPS);
#pragma unroll
        for (int nt = 0; nt < 4; ++nt) {
            int n = nt * 16 + m16;
            float core = (x1[nt][rg] - mean) * rs;
            ln1v[nt][rg] = core * vecs[3][n] + vecs[4][n];
            ln2v[nt][rg] = core * vecs[5][n] + vecs[6][n];
        }
    }
    // write LN1 -> Cb (own rows only; wave-local ordering)
    __builtin_amdgcn_wave_barrier();
#pragma unroll
    for (int nt = 0; nt < 4; ++nt)
#pragma unroll
        for (int rg = 0; rg < 4; ++rg)
            Cb[(w16 + quad * 4 + rg) * LSTRIDE + nt * 16 + m16] = f2b(ln1v[nt][rg]);
    __builtin_amdgcn_wave_barrier();
    // GEMM2: h = relu(LN1@W1 + b1) -> Qb (own rows)
    f32x4 acc2[4] = {zero, zero, zero, zero};
    mfma_gemm(Cb, W1s, w16, m16, quad, acc2);
    __builtin_amdgcn_wave_barrier();
#pragma unroll
    for (int nt = 0; nt < 4; ++nt) {
        int n = nt * 16 + m16;
        float bb = vecs[1][n];
#pragma unroll
        for (int rg = 0; rg < 4; ++rg)
            Qb[(w16 + quad * 4 + rg) * LSTRIDE + n] = f2b(fmaxf(acc2[nt][rg] + bb, 0.f));
    }
    __builtin_amdgcn_wave_barrier();
    // GEMM3: x = h@W2 + b2 + LN2(x1)
    f32x4 acc3[4] = {zero, zero, zero, zero};
    mfma_gemm(Qb, W2s, w16, m16, quad, acc3);
#pragma unroll
    for (int nt = 0; nt < 4; ++nt) {
        int n = nt * 16 + m16;
        float bb = vecs[2][n];
#pragma unroll
        for (int rg = 0; rg < 4; ++rg) {
            int m = w16 + quad * 4 + rg;
            xout[(row0 + m) * DDIM + n] = acc3[nt][rg] + bb + ln2v[nt][rg];
        }
    }
}

// ---------------- MFMA flash attention, one block per (b, head), 4 waves ----------------
__global__ __launch_bounds__(256) void attn_kernel(const unsigned short* __restrict__ q,
                                                   const unsigned short* __restrict__ k,
                                                   const unsigned short* __restrict__ v,
                                                   float* __restrict__ ctx) {
    __shared__ unsigned short Kb[224 * 32];    // Kb[kk][d], zero for kk>=200
    __shared__ unsigned short Vt[32 * 232];    // Vt[d][kk], zero for kk>=200
    __shared__ unsigned short Ps[4][16 * 32];  // per-wave P buffer
    int b = blockIdx.x >> 1, h = blockIdx.x & 1;
    int t = threadIdx.x;
    const long base = (long)b * (SS * DDIM) + h * HD;
    for (int i = t; i < 224 * 8; i += 256) {   // ushort4 chunks
        int kk = i >> 3, d4 = (i & 7) * 4;
        ushort4 kv = make_ushort4(0, 0, 0, 0), vv = make_ushort4(0, 0, 0, 0);
        if (kk < SS) {
            kv = *(const ushort4*)&k[base + kk * DDIM + d4];
            vv = *(const ushort4*)&v[base + kk * DDIM + d4];
        }
        *(ushort4*)&Kb[kk * 32 + d4] = kv;
        Vt[(d4 + 0) * 232 + kk] = vv.x;
        Vt[(d4 + 1) * 232 + kk] = vv.y;
        Vt[(d4 + 2) * 232 + kk] = vv.z;
        Vt[(d4 + 3) * 232 + kk] = vv.w;
    }
    __syncthreads();
    int w = t >> 6, lane = t & 63;
    int m16 = lane & 15, quad = lane >> 4;
    const float scale = 0.17677669529663687f;   // 1/sqrt(32)
    unsigned short* ps = Ps[w];
    for (int qt = w; qt < 13; qt += 4) {
        int q0 = qt * 16;
        int qrow = q0 + m16; if (qrow > SS - 1) qrow = SS - 1;
        bf16x8 qa = *(const bf16x8*)&q[base + qrow * DDIM + quad * 8];
        f32x4 o0 = {0.f, 0.f, 0.f, 0.f}, o1 = {0.f, 0.f, 0.f, 0.f};
        float mrow[4] = {-1e30f, -1e30f, -1e30f, -1e30f};
        float lrow[4] = {0.f, 0.f, 0.f, 0.f};
        int np = (qt + 2) >> 1;
        for (int pi = 0; pi < np; ++pi) {
            int p0 = pi * 32;
            bf16x8 kb0 = *(bf16x8*)&Kb[(p0 + m16) * 32 + quad * 8];
            bf16x8 kb1 = *(bf16x8*)&Kb[(p0 + 16 + m16) * 32 + quad * 8];
            f32x4 z = {0.f, 0.f, 0.f, 0.f};
            f32x4 s0 = __builtin_amdgcn_mfma_f32_16x16x32_bf16(qa, kb0, z, 0, 0, 0);
            f32x4 s1 = __builtin_amdgcn_mfma_f32_16x16x32_bf16(qa, kb1, z, 0, 0, 0);
            int col0 = p0 + m16, col1 = col0 + 16;
            float p0v[4], p1v[4];
#pragma unroll
            for (int rg = 0; rg < 4; ++rg) {
                int rglob = q0 + quad * 4 + rg;
                float v0 = (col0 <= rglob && col0 < SS) ? s0[rg] * scale : -1e30f;
                float v1 = (col1 <= rglob && col1 < SS) ? s1[rg] * scale : -1e30f;
                float mx = fmaxf(v0, v1);
#pragma unroll
                for (int o = 1; o <= 8; o <<= 1) mx = fmaxf(mx, __shfl_xor(mx, o, 64));
                float mn = fmaxf(mrow[rg], mx);
                float al = __expf(mrow[rg] - mn);
                float e0 = __expf(v0 - mn), e1 = __expf(v1 - mn);
                float sm = e0 + e1;
#pragma unroll
                for (int o = 1; o <= 8; o <<= 1) sm += __shfl_xor(sm, o, 64);
                lrow[rg] = lrow[rg] * al + sm;
                mrow[rg] = mn;
                o0[rg] *= al; o1[rg] *= al;
                p0v[rg] = e0; p1v[rg] = e1;
            }
            __builtin_amdgcn_wave_barrier();
#pragma unroll
            for (int rg = 0; rg < 4; ++rg) {
                int row = quad * 4 + rg;
                ps[row * 32 + m16] = f2b(p0v[rg]);
                ps[row * 32 + 16 + m16] = f2b(p1v[rg]);
            }
            __builtin_amdgcn_wave_barrier();
            bf16x8 pa = *(bf16x8*)&ps[m16 * 32 + quad * 8];
            bf16x8 vb0 = *(bf16x8*)&Vt[m16 * 232 + p0 + quad * 8];
            bf16x8 vb1 = *(bf16x8*)&Vt[(m16 + 16) * 232 + p0 + quad * 8];
            o0 = __builtin_amdgcn_mfma_f32_16x16x32_bf16(pa, vb0, o0, 0, 0, 0);
            o1 = __builtin_amdgcn_mfma_f32_16x16x32_bf16(pa, vb1, o1, 0, 0, 0);
        }
#pragma unroll
        for (int rg = 0; rg < 4; ++rg) {
            int rglob = q0 + quad * 4 + rg;
            if (rglob < SS) {
                float inv = 1.f / lrow[rg];
                ctx[base + rglob * DDIM + m16] = o0[rg] * inv;
                ctx[base + rglob * DDIM + 16 + m16] = o1[rg] * inv;
            }
        }
    }
}

// ---------------- Gram matrix partials ----------------
__global__ __launch_bounds__(256) void gram_kernel(const float* __restrict__ A, int nrows,
                                                   float* __restrict__ part) {
    __shared__ float rows[16][64];
    int t = threadIdx.x;
    int i = t >> 2;            // 0..63
    int jb = (t & 3) * 16;     // 0/16/32/48
    float acc[16] = {};
    for (long base = (long)blockIdx.x * 16; base < nrows; base += (long)GRAM_NB * 16) {
        {
            int rr = t >> 4, d4 = (t & 15) * 4;
            long gr = base + rr;
            float4 vv = make_float4(0.f, 0.f, 0.f, 0.f);
            if (gr < nrows) vv = *(const float4*)&A[gr * DDIM + d4];
            *(float4*)&rows[rr][d4] = vv;
        }
        __syncthreads();
#pragma unroll
        for (int rr = 0; rr < 16; ++rr) {
            float ai = rows[rr][i];
            float4 r0 = *(const float4*)&rows[rr][jb];
            float4 r1 = *(const float4*)&rows[rr][jb + 4];
            float4 r2 = *(const float4*)&rows[rr][jb + 8];
            float4 r3 = *(const float4*)&rows[rr][jb + 12];
            acc[0] += ai * r0.x; acc[1] += ai * r0.y; acc[2] += ai * r0.z; acc[3] += ai * r0.w;
            acc[4] += ai * r1.x; acc[5] += ai * r1.y; acc[6] += ai * r1.z; acc[7] += ai * r1.w;
            acc[8] += ai * r2.x; acc[9] += ai * r2.y; acc[10] += ai * r2.z; acc[11] += ai * r2.w;
            acc[12] += ai * r3.x; acc[13] += ai * r3.y; acc[14] += ai * r3.z; acc[15] += ai * r3.w;
        }
        __syncthreads();
    }
    float* slab = part + (long)blockIdx.x * 4096 + i * 64 + jb;
#pragma unroll
    for (int g = 0; g < 4; ++g) {
        float4 o; o.x = acc[g * 4]; o.y = acc[g * 4 + 1]; o.z = acc[g * 4 + 2]; o.w = acc[g * 4 + 3];
        *(float4*)&slab[g * 4] = o;
    }
}

// out[p] = sum_b part[b*4096+p]
__global__ __launch_bounds__(256) void gram_reduce(const float* __restrict__ part,
                                                   float* __restrict__ out) {
    int p = blockIdx.x * 256 + threadIdx.x;   // 16 blocks
    float s = 0.f;
    for (int b = 0; b < GRAM_NB; ++b) s += part[(long)b * 4096 + p];
    out[p] = s;
}

// ---------------- right(): per-block partial sums of (1-C)ps^2 - 2ps ----------------
__global__ __launch_bounds__(256) void right_kernel(const float* __restrict__ x,
                                                    const float* __restrict__ item_emb,
                                                    const int* __restrict__ pos_seqs,
                                                    const float* __restrict__ pred_w,
                                                    float* __restrict__ rpart) {
    __shared__ float p_s[64];
    __shared__ float red[4];
    int t = threadIdx.x;
    if (t < 64) p_s[t] = pred_w[t];
    __syncthreads();
    int w = t >> 6, lane = t & 63;
    float local = 0.f;
    for (long row = (long)blockIdx.x * 4 + w; row < NROWS; row += (long)gridDim.x * 4) {
        int pi = pos_seqs[row];
        float val = x[row * DDIM + lane] * item_emb[(long)pi * DDIM + lane] * p_s[lane];
        float ps = wave_sum(val);           // lane-uniform
        local += (1.0f - CC) * ps * ps - 2.0f * ps;   // identical on all 64 lanes
    }
    if (lane == 0) red[w] = local;
    __syncthreads();
    if (t == 0) rpart[blockIdx.x] = red[0] + red[1] + red[2] + red[3];
}

// ---------------- per-parameter sum-of-squares ----------------
struct NormEntry { const float* p; int n; };
struct NormArgs { NormEntry e[30]; };

__global__ __launch_bounds__(256) void norms_kernel(NormArgs args, float* __restrict__ norms) {
    __shared__ float red[256];
    NormEntry en = args.e[blockIdx.x];
    float s = 0.f;
    for (int i = threadIdx.x; i < en.n; i += 256) { float v = en.p[i]; s += v * v; }
    red[threadIdx.x] = s;
    for (int o = 128; o > 0; o >>= 1) {
        __syncthreads();
        if (threadIdx.x < o) red[threadIdx.x] += red[threadIdx.x + o];
    }
    __syncthreads();
    if (threadIdx.x == 0) norms[blockIdx.x] = red[0];
}

// ---------------- final scalar ----------------
__global__ __launch_bounds__(256) void final_kernel(const float* __restrict__ EE,
                                                    const float* __restrict__ FF,
                                                    const float* __restrict__ pred_w,
                                                    const float* __restrict__ rpart,
                                                    const float* __restrict__ norms,
                                                    float* __restrict__ out) {
    __shared__ float p_s[64];
    __shared__ float redL[256];
    __shared__ float redT[256];
    __shared__ float redR[256];
    int t = threadIdx.x;
    if (t < 64) p_s[t] = pred_w[t];
    __syncthreads();
    float lf = 0.f, tr = 0.f, rs = 0.f;
    for (int p = t; p < 4096; p += 256) {
        int i = p >> 6, j = p & 63;
        float ee = EE[p];
        lf += FF[p] * ee * p_s[i] * p_s[j];
        if (i == j) tr += ee;
    }
    for (int i = t; i < 1024; i += 256) rs += rpart[i];
    redL[t] = lf; redT[t] = tr; redR[t] = rs;
    for (int o = 128; o > 0; o >>= 1) {
        __syncthreads();
        if (t < o) { redL[t] += redL[t + o]; redT[t] += redT[t + o]; redR[t] += redR[t + o]; }
    }
    __syncthreads();
    if (t == 0) {
        float reg = sqrtf(redT[0]);   // ||item_emb||_F = sqrt(trace(EE))
        for (int s = 0; s < 30; ++s) reg += sqrtf(norms[s]);
        out[0] = CC * redL[0] + redR[0] + 0.1f * reg;
    }
}

// ---------------- host ----------------
struct DevPtrs { float *x, *ctx, *gpart; unsigned short *qb, *kb, *vb; };

static DevPtrs fetch_ptrs() {
    DevPtrs p;
    (void)hipGetSymbolAddress((void**)&p.x,    HIP_SYMBOL(g_x));
    (void)hipGetSymbolAddress((void**)&p.ctx,  HIP_SYMBOL(g_ctx));
    (void)hipGetSymbolAddress((void**)&p.gpart,HIP_SYMBOL(g_gpart));
    (void)hipGetSymbolAddress((void**)&p.qb,   HIP_SYMBOL(g_qb));
    (void)hipGetSymbolAddress((void**)&p.kb,   HIP_SYMBOL(g_kb));
    (void)hipGetSymbolAddress((void**)&p.vb,   HIP_SYMBOL(g_vb));
    return p;
}

extern "C" void kernel_launch(void* const* d_in, const int* in_sizes, int n_in,
                              void* d_out, int out_size, void* d_ws, size_t ws_size,
                              hipStream_t stream) {
    const int*   log_seqs = (const int*)d_in[1];
    const int*   pos_seqs = (const int*)d_in[2];
    const float* item_emb = (const float*)d_in[3];
    const float* pos_emb  = (const float*)d_in[4];
    const float* pred_w   = (const float*)d_in[5];
    const float* ln_w     = (const float*)d_in[6];
    const float* ln_b     = (const float*)d_in[7];
    const float* qkv_w    = (const float*)d_in[8];
    const float* qkv_b    = (const float*)d_in[9];
    const float* out_w    = (const float*)d_in[10];
    const float* out_b    = (const float*)d_in[11];
    const float* fc1_w    = (const float*)d_in[12];
    const float* fc1_b    = (const float*)d_in[13];
    const float* ffln_w   = (const float*)d_in[14];
    const float* ffln_b   = (const float*)d_in[15];
    const float* fc2_w    = (const float*)d_in[16];
    const float* fc2_b    = (const float*)d_in[17];
    const float* ffln2_w  = (const float*)d_in[18];
    const float* ffln2_b  = (const float*)d_in[19];

    static DevPtrs P = fetch_ptrs();   // first call is the uncaptured correctness call

    float* ws    = (float*)d_ws;
    float* rpart = ws;            // 1024
    float* nrm   = ws + 1024;     // 30
    float* EE    = ws + 2048;     // 4096
    float* FF    = ws + 6144;     // 4096

    embed_kernel<<<NROWS * 16 / 256, 256, 0, stream>>>(log_seqs, item_emb, pos_emb, P.x);

    const int GEMM_GRID = NROWS / 64;   // 1600

    for (int l = 0; l < LL; ++l) {
        const float* Wqkv = qkv_w + (long)l * 3 * 64 * 64;
        const float* Bqkv = qkv_b + (long)l * 192;
        qkv_fused<<<GEMM_GRID, 256, 0, stream>>>(
            P.x, Wqkv, Bqkv, ln_w + l * 64, ln_b + l * 64, P.qb, P.kb, P.vb);
        attn_kernel<<<BB * 2, 256, 0, stream>>>(P.qb, P.kb, P.vb, P.ctx);
        ffn_fused<<<GEMM_GRID, 256, 0, stream>>>(
            P.ctx, P.x,
            out_w + (long)l * 4096, out_b + l * 64,
            fc1_w + (long)l * 4096, fc1_b + l * 64,
            fc2_w + (long)l * 4096, fc2_b + l * 64,
            ln_w + l * 64, ln_b + l * 64,
            ffln_w + l * 64, ffln_b + l * 64,
            ffln2_w + l * 64, ffln2_b + l * 64,
            P.x);
    }

    gram_kernel<<<GRAM_NB, 256, 0, stream>>>(item_emb, 100001, P.gpart);
    gram_reduce<<<16, 256, 0, stream>>>(P.gpart, EE);
    gram_kernel<<<GRAM_NB, 256, 0, stream>>>(P.x, NROWS, P.gpart);
    gram_reduce<<<16, 256, 0, stream>>>(P.gpart, FF);
    right_kernel<<<1024, 256, 0, stream>>>(P.x, item_emb, pos_seqs, pred_w, rpart);

    NormArgs na;
    int s = 0;
    na.e[s++] = {pos_emb, (SS + 1) * DDIM};
    na.e[s++] = {pred_w, DDIM};
    for (int l = 0; l < LL; ++l) {
        na.e[s++] = {ln_w + l * 64, 64};
        na.e[s++] = {ln_b + l * 64, 64};
        na.e[s++] = {qkv_w + (long)l * 12288, 12288};
        na.e[s++] = {qkv_b + (long)l * 192, 192};
        na.e[s++] = {out_w + (long)l * 4096, 4096};
        na.e[s++] = {out_b + l * 64, 64};
        na.e[s++] = {fc1_w + (long)l * 4096, 4096};
        na.e[s++] = {fc1_b + l * 64, 64};
        na.e[s++] = {ffln_w + l * 64, 64};
        na.e[s++] = {ffln_b + l * 64, 64};
        na.e[s++] = {fc2_w + (long)l * 4096, 4096};
        na.e[s++] = {fc2_b + l * 64, 64};
        na.e[s++] = {ffln2_w + l * 64, 64};
        na.e[s++] = {ffln2_b + l * 64, 64};
    }
    norms_kernel<<<30, 256, 0, stream>>>(na, nrm);

    final_kernel<<<1, 256, 0, stream>>>(EE, FF, pred_w, rpart, nrm, (float*)d_out);
}

// Round 14
// 384.132 us; speedup vs baseline: 2.3480x; 1.0709x over previous
//
#include <hip/hip_runtime.h>
#include <math.h>

#define BB 512
#define SS 200
#define DDIM 64
#define HD 32
#define LL 2
#define NROWS (BB * SS)   // 102400
#define EPS 1e-8f
#define CC 0.001f
#define GRAM_NB 512
#define LSTRIDE 72

typedef __attribute__((ext_vector_type(8))) short bf16x8;
typedef __attribute__((ext_vector_type(4))) float f32x4;

// ---------------- static device buffers (activations) ----------------
__device__ float g_x[NROWS * DDIM];
__device__ float g_ctx[NROWS * DDIM];
__device__ unsigned short g_qb[NROWS * DDIM];
__device__ unsigned short g_kb[NROWS * DDIM];
__device__ unsigned short g_vb[NROWS * DDIM];
__device__ float g_gpart[GRAM_NB * 4096];   // gram per-block partials

// ---------------- helpers ----------------
__device__ __forceinline__ float wave_sum(float v) {
#pragma unroll
    for (int o = 32; o > 0; o >>= 1) v += __shfl_xor(v, o, 64);
    return v;
}
__device__ __forceinline__ unsigned short f2b(float f) {
    unsigned u = __float_as_uint(f);
    return (unsigned short)((u + 0x7FFFu + ((u >> 16) & 1u)) >> 16);
}
__device__ __forceinline__ float b2f(unsigned short u) {
    return __uint_as_float(((unsigned)u) << 16);
}

// ---------------- embedding (float4) ----------------
__global__ __launch_bounds__(256) void embed_kernel(const int* __restrict__ log_seqs,
                                                    const float* __restrict__ item_emb,
                                                    const float* __restrict__ pos_emb,
                                                    float* __restrict__ x) {
    int tid = blockIdx.x * 256 + threadIdx.x;   // over NROWS*16
    int row = tid >> 4, q4 = tid & 15;
    int s = row % SS;
    int li = log_seqs[row];
    int poss = li ? (s + 1) : 0;
    float4 e = *(const float4*)&item_emb[li * DDIM + q4 * 4];
    float4 p = *(const float4*)&pos_emb[poss * DDIM + q4 * 4];
    float4 o;
    o.x = e.x * 8.0f + p.x; o.y = e.y * 8.0f + p.y;
    o.z = e.z * 8.0f + p.z; o.w = e.w * 8.0f + p.w;
    *(float4*)&x[row * DDIM + q4 * 4] = o;
}

// ---------------- MFMA GEMM staging helpers (bf16 LDS, stride 72) ----------------
__device__ __forceinline__ void stage_bf16_tile(const float* __restrict__ G, unsigned short* __restrict__ L,
                                                int t, long row0) {
#pragma unroll
    for (int rep = 0; rep < 4; ++rep) {
        int idx = t + rep * 256;
        int r = idx >> 4, c4 = (idx & 15) * 4;
        float4 f = *(const float4*)&G[(row0 + r) * DDIM + c4];
        ushort4 o; o.x = f2b(f.x); o.y = f2b(f.y); o.z = f2b(f.z); o.w = f2b(f.w);
        *(ushort4*)&L[r * LSTRIDE + c4] = o;
    }
}

__device__ __forceinline__ void stage_w_bf16(const float* __restrict__ Wg, unsigned short* __restrict__ L, int t) {
#pragma unroll
    for (int rep = 0; rep < 4; ++rep) {
        int idx = t + rep * 256;
        int r = idx >> 4, c4 = (idx & 15) * 4;
        float4 f = *(const float4*)&Wg[r * DDIM + c4];
        ushort4 o; o.x = f2b(f.x); o.y = f2b(f.y); o.z = f2b(f.z); o.w = f2b(f.w);
        *(ushort4*)&L[r * LSTRIDE + c4] = o;
    }
}

// LN(x rows) -> bf16 LDS tile. thread t: row t>>2, 16-col chunk (t&3)*16.
__device__ __forceinline__ void stage_ln_bf16(const float* __restrict__ x, unsigned short* __restrict__ L,
                                              const float* __restrict__ lnw, const float* __restrict__ lnb,
                                              int t, long row0) {
    int rr = t >> 2, qd = (t & 3) * 16;
    float4 v[4];
#pragma unroll
    for (int g = 0; g < 4; ++g) v[g] = *(const float4*)&x[(row0 + rr) * DDIM + qd + g * 4];
    float s1 = 0.f, s2 = 0.f;
#pragma unroll
    for (int g = 0; g < 4; ++g) {
        s1 += (v[g].x + v[g].y) + (v[g].z + v[g].w);
        s2 += (v[g].x * v[g].x + v[g].y * v[g].y) + (v[g].z * v[g].z + v[g].w * v[g].w);
    }
    s1 += __shfl_xor(s1, 1, 64); s1 += __shfl_xor(s1, 2, 64);
    s2 += __shfl_xor(s2, 1, 64); s2 += __shfl_xor(s2, 2, 64);
    float m = s1 * (1.f / 64.f);
    float var = s2 * (1.f / 64.f) - m * m;
    float rs = rsqrtf(var + EPS);
#pragma unroll
    for (int g = 0; g < 4; ++g) {
        float4 w4 = *(const float4*)&lnw[qd + g * 4];
        float4 b4 = *(const float4*)&lnb[qd + g * 4];
        ushort4 o;
        o.x = f2b((v[g].x - m) * rs * w4.x + b4.x);
        o.y = f2b((v[g].y - m) * rs * w4.y + b4.y);
        o.z = f2b((v[g].z - m) * rs * w4.z + b4.z);
        o.w = f2b((v[g].w - m) * rs * w4.w + b4.w);
        *(ushort4*)&L[rr * LSTRIDE + qd + g * 4] = o;
    }
}

// 64x64x64 GEMM slice for wave w: out rows w16..w16+15, all 64 cols.
__device__ __forceinline__ void mfma_gemm(const unsigned short* __restrict__ A,
                                          const unsigned short* __restrict__ B,
                                          int w16, int m16, int quad, f32x4 acc[4]) {
    bf16x8 a0 = *(const bf16x8*)&A[(w16 + m16) * LSTRIDE + quad * 8];
    bf16x8 a1 = *(const bf16x8*)&A[(w16 + m16) * LSTRIDE + 32 + quad * 8];
#pragma unroll
    for (int nt = 0; nt < 4; ++nt) {
        bf16x8 b0 = *(const bf16x8*)&B[(nt * 16 + m16) * LSTRIDE + quad * 8];
        bf16x8 b1 = *(const bf16x8*)&B[(nt * 16 + m16) * LSTRIDE + 32 + quad * 8];
        acc[nt] = __builtin_amdgcn_mfma_f32_16x16x32_bf16(a0, b0, acc[nt], 0, 0, 0);
        acc[nt] = __builtin_amdgcn_mfma_f32_16x16x32_bf16(a1, b1, acc[nt], 0, 0, 0);
    }
}

// ---------------- fused QKV (MFMA) ----------------
__global__ __launch_bounds__(256) void qkv_fused(const float* __restrict__ x,
                                                 const float* __restrict__ Wqkv,
                                                 const float* __restrict__ Bqkv,
                                                 const float* __restrict__ lnw,
                                                 const float* __restrict__ lnb,
                                                 unsigned short* __restrict__ qo,
                                                 unsigned short* __restrict__ ko,
                                                 unsigned short* __restrict__ vo) {
    __shared__ unsigned short Ab[64 * LSTRIDE], Lb[64 * LSTRIDE];
    __shared__ unsigned short Wq[64 * LSTRIDE], Wk[64 * LSTRIDE], Wv[64 * LSTRIDE];
    int t = threadIdx.x;
    long row0 = (long)blockIdx.x * 64;
    stage_bf16_tile(x, Ab, t, row0);
    stage_ln_bf16(x, Lb, lnw, lnb, t, row0);
    stage_w_bf16(Wqkv, Wq, t);
    stage_w_bf16(Wqkv + 4096, Wk, t);
    stage_w_bf16(Wqkv + 8192, Wv, t);
    __syncthreads();
    int w16 = (t >> 6) * 16, lane = t & 63, m16 = lane & 15, quad = lane >> 4;
    f32x4 zero = {0.f, 0.f, 0.f, 0.f};
    {
        f32x4 acc[4] = {zero, zero, zero, zero};
        mfma_gemm(Lb, Wq, w16, m16, quad, acc);
#pragma unroll
        for (int nt = 0; nt < 4; ++nt) {
            int n = nt * 16 + m16;
            float bb = Bqkv[n];
#pragma unroll
            for (int rg = 0; rg < 4; ++rg)
                qo[(row0 + w16 + quad * 4 + rg) * DDIM + n] = f2b(acc[nt][rg] + bb);
        }
    }
    {
        f32x4 acc[4] = {zero, zero, zero, zero};
        mfma_gemm(Ab, Wk, w16, m16, quad, acc);
#pragma unroll
        for (int nt = 0; nt < 4; ++nt) {
            int n = nt * 16 + m16;
            float bb = Bqkv[64 + n];
#pragma unroll
            for (int rg = 0; rg < 4; ++rg)
                ko[(row0 + w16 + quad * 4 + rg) * DDIM + n] = f2b(acc[nt][rg] + bb);
        }
    }
    {
        f32x4 acc[4] = {zero, zero, zero, zero};
        mfma_gemm(Ab, Wv, w16, m16, quad, acc);
#pragma unroll
        for (int nt = 0; nt < 4; ++nt) {
            int n = nt * 16 + m16;
            float bb = Bqkv[128 + n];
#pragma unroll
            for (int rg = 0; rg < 4; ++rg)
                vo[(row0 + w16 + quad * 4 + rg) * DDIM + n] = f2b(acc[nt][rg] + bb);
        }
    }
}

// ---------------- fused out-proj + FFN (MFMA, wave-local chains) ----------------
__global__ __launch_bounds__(256) void ffn_fused(const float* __restrict__ ctx,
                                                 const float* __restrict__ x,
                                                 const float* __restrict__ Wo, const float* __restrict__ bo,
                                                 const float* __restrict__ W1, const float* __restrict__ b1,
                                                 const float* __restrict__ W2, const float* __restrict__ b2,
                                                 const float* __restrict__ l0w, const float* __restrict__ l0b,
                                                 const float* __restrict__ l1w, const float* __restrict__ l1b,
                                                 const float* __restrict__ l2w, const float* __restrict__ l2b,
                                                 float* __restrict__ xout) {
    __shared__ unsigned short Cb[64 * LSTRIDE], Qb[64 * LSTRIDE];
    __shared__ unsigned short W0s[64 * LSTRIDE], W1s[64 * LSTRIDE], W2s[64 * LSTRIDE];
    __shared__ float vecs[7][64];   // bo,b1,b2,l1w,l1b,l2w,l2b
    int t = threadIdx.x;
    long row0 = (long)blockIdx.x * 64;
    stage_bf16_tile(ctx, Cb, t, row0);
    stage_ln_bf16(x, Qb, l0w, l0b, t, row0);   // qin = LN(x; ln0), bf16
    stage_w_bf16(Wo, W0s, t);
    stage_w_bf16(W1, W1s, t);
    stage_w_bf16(W2, W2s, t);
    if (t < 64) {
        vecs[0][t] = bo[t]; vecs[1][t] = b1[t]; vecs[2][t] = b2[t];
        vecs[3][t] = l1w[t]; vecs[4][t] = l1b[t]; vecs[5][t] = l2w[t]; vecs[6][t] = l2b[t];
    }
    __syncthreads();
    int w16 = (t >> 6) * 16, lane = t & 63, m16 = lane & 15, quad = lane >> 4;
    f32x4 zero = {0.f, 0.f, 0.f, 0.f};
    f32x4 acc1[4] = {zero, zero, zero, zero};
    mfma_gemm(Cb, W0s, w16, m16, quad, acc1);
    float x1[4][4];
#pragma unroll
    for (int nt = 0; nt < 4; ++nt) {
        int n = nt * 16 + m16;
        float bb = vecs[0][n];
#pragma unroll
        for (int rg = 0; rg < 4; ++rg) {
            int m = w16 + quad * 4 + rg;
            x1[nt][rg] = acc1[nt][rg] + bb + b2f(Qb[m * LSTRIDE + n]);
        }
    }
    float ln1v[4][4], ln2v[4][4];
#pragma unroll
    for (int rg = 0; rg < 4; ++rg) {
        float s1 = (x1[0][rg] + x1[1][rg]) + (x1[2][rg] + x1[3][rg]);
        float s2 = x1[0][rg] * x1[0][rg] + x1[1][rg] * x1[1][rg]
                 + x1[2][rg] * x1[2][rg] + x1[3][rg] * x1[3][rg];
#pragma unroll
        for (int o = 1; o <= 8; o <<= 1) { s1 += __shfl_xor(s1, o, 64); s2 += __shfl_xor(s2, o, 64); }
        float mean = s1 * (1.f / 64.f);
        float var = s2 * (1.f / 64.f) - mean * mean;
        float rs = rsqrtf(var + EPS);
#pragma unroll
        for (int nt = 0; nt < 4; ++nt) {
            int n = nt * 16 + m16;
            float core = (x1[nt][rg] - mean) * rs;
            ln1v[nt][rg] = core * vecs[3][n] + vecs[4][n];
            ln2v[nt][rg] = core * vecs[5][n] + vecs[6][n];
        }
    }
    __builtin_amdgcn_wave_barrier();
#pragma unroll
    for (int nt = 0; nt < 4; ++nt)
#pragma unroll
        for (int rg = 0; rg < 4; ++rg)
            Cb[(w16 + quad * 4 + rg) * LSTRIDE + nt * 16 + m16] = f2b(ln1v[nt][rg]);
    __builtin_amdgcn_wave_barrier();
    f32x4 acc2[4] = {zero, zero, zero, zero};
    mfma_gemm(Cb, W1s, w16, m16, quad, acc2);
    __builtin_amdgcn_wave_barrier();
#pragma unroll
    for (int nt = 0; nt < 4; ++nt) {
        int n = nt * 16 + m16;
        float bb = vecs[1][n];
#pragma unroll
        for (int rg = 0; rg < 4; ++rg)
            Qb[(w16 + quad * 4 + rg) * LSTRIDE + n] = f2b(fmaxf(acc2[nt][rg] + bb, 0.f));
    }
    __builtin_amdgcn_wave_barrier();
    f32x4 acc3[4] = {zero, zero, zero, zero};
    mfma_gemm(Qb, W2s, w16, m16, quad, acc3);
#pragma unroll
    for (int nt = 0; nt < 4; ++nt) {
        int n = nt * 16 + m16;
        float bb = vecs[2][n];
#pragma unroll
        for (int rg = 0; rg < 4; ++rg) {
            int m = w16 + quad * 4 + rg;
            xout[(row0 + m) * DDIM + n] = acc3[nt][rg] + bb + ln2v[nt][rg];
        }
    }
}

// ---------------- MFMA flash attention, one block per (b, head), 4 waves ----------------
__global__ __launch_bounds__(256) void attn_kernel(const unsigned short* __restrict__ q,
                                                   const unsigned short* __restrict__ k,
                                                   const unsigned short* __restrict__ v,
                                                   float* __restrict__ ctx) {
    __shared__ unsigned short Kb[224 * 32];    // Kb[kk][d], zero for kk>=200
    __shared__ unsigned short Vt[32 * 232];    // Vt[d][kk], zero for kk>=200
    __shared__ unsigned short Ps[4][16 * 32];  // per-wave P buffer
    int b = blockIdx.x >> 1, h = blockIdx.x & 1;
    int t = threadIdx.x;
    const long base = (long)b * (SS * DDIM) + h * HD;
    for (int i = t; i < 224 * 8; i += 256) {   // ushort4 chunks
        int kk = i >> 3, d4 = (i & 7) * 4;
        ushort4 kv = make_ushort4(0, 0, 0, 0), vv = make_ushort4(0, 0, 0, 0);
        if (kk < SS) {
            kv = *(const ushort4*)&k[base + kk * DDIM + d4];
            vv = *(const ushort4*)&v[base + kk * DDIM + d4];
        }
        *(ushort4*)&Kb[kk * 32 + d4] = kv;
        Vt[(d4 + 0) * 232 + kk] = vv.x;
        Vt[(d4 + 1) * 232 + kk] = vv.y;
        Vt[(d4 + 2) * 232 + kk] = vv.z;
        Vt[(d4 + 3) * 232 + kk] = vv.w;
    }
    __syncthreads();
    int w = t >> 6, lane = t & 63;
    int m16 = lane & 15, quad = lane >> 4;
    const float scale = 0.17677669529663687f;   // 1/sqrt(32)
    unsigned short* ps = Ps[w];
    for (int qt = w; qt < 13; qt += 4) {
        int q0 = qt * 16;
        int qrow = q0 + m16; if (qrow > SS - 1) qrow = SS - 1;
        bf16x8 qa = *(const bf16x8*)&q[base + qrow * DDIM + quad * 8];
        f32x4 o0 = {0.f, 0.f, 0.f, 0.f}, o1 = {0.f, 0.f, 0.f, 0.f};
        float mrow[4] = {-1e30f, -1e30f, -1e30f, -1e30f};
        float lrow[4] = {0.f, 0.f, 0.f, 0.f};
        int np = (qt + 2) >> 1;
        for (int pi = 0; pi < np; ++pi) {
            int p0 = pi * 32;
            bf16x8 kb0 = *(bf16x8*)&Kb[(p0 + m16) * 32 + quad * 8];
            bf16x8 kb1 = *(bf16x8*)&Kb[(p0 + 16 + m16) * 32 + quad * 8];
            f32x4 z = {0.f, 0.f, 0.f, 0.f};
            f32x4 s0 = __builtin_amdgcn_mfma_f32_16x16x32_bf16(qa, kb0, z, 0, 0, 0);
            f32x4 s1 = __builtin_amdgcn_mfma_f32_16x16x32_bf16(qa, kb1, z, 0, 0, 0);
            int col0 = p0 + m16, col1 = col0 + 16;
            float p0v[4], p1v[4];
#pragma unroll
            for (int rg = 0; rg < 4; ++rg) {
                int rglob = q0 + quad * 4 + rg;
                float v0 = (col0 <= rglob && col0 < SS) ? s0[rg] * scale : -1e30f;
                float v1 = (col1 <= rglob && col1 < SS) ? s1[rg] * scale : -1e30f;
                float mx = fmaxf(v0, v1);
#pragma unroll
                for (int o = 1; o <= 8; o <<= 1) mx = fmaxf(mx, __shfl_xor(mx, o, 64));
                float mn = fmaxf(mrow[rg], mx);
                float al = __expf(mrow[rg] - mn);
                float e0 = __expf(v0 - mn), e1 = __expf(v1 - mn);
                float sm = e0 + e1;
#pragma unroll
                for (int o = 1; o <= 8; o <<= 1) sm += __shfl_xor(sm, o, 64);
                lrow[rg] = lrow[rg] * al + sm;
                mrow[rg] = mn;
                o0[rg] *= al; o1[rg] *= al;
                p0v[rg] = e0; p1v[rg] = e1;
            }
            __builtin_amdgcn_wave_barrier();
#pragma unroll
            for (int rg = 0; rg < 4; ++rg) {
                int row = quad * 4 + rg;
                ps[row * 32 + m16] = f2b(p0v[rg]);
                ps[row * 32 + 16 + m16] = f2b(p1v[rg]);
            }
            __builtin_amdgcn_wave_barrier();
            bf16x8 pa = *(bf16x8*)&ps[m16 * 32 + quad * 8];
            bf16x8 vb0 = *(bf16x8*)&Vt[m16 * 232 + p0 + quad * 8];
            bf16x8 vb1 = *(bf16x8*)&Vt[(m16 + 16) * 232 + p0 + quad * 8];
            o0 = __builtin_amdgcn_mfma_f32_16x16x32_bf16(pa, vb0, o0, 0, 0, 0);
            o1 = __builtin_amdgcn_mfma_f32_16x16x32_bf16(pa, vb1, o1, 0, 0, 0);
        }
#pragma unroll
        for (int rg = 0; rg < 4; ++rg) {
            int rglob = q0 + quad * 4 + rg;
            if (rglob < SS) {
                float inv = 1.f / lrow[rg];
                ctx[base + rglob * DDIM + m16] = o0[rg] * inv;
                ctx[base + rglob * DDIM + 16 + m16] = o1[rg] * inv;
            }
        }
    }
}

// ---------------- MFMA Gram: part[b] = chunk-sum A^T A (bf16 in, fp32 acc) ----------------
// Both operands come from the SAME transposed LDS tile At[c][r]:
// A-frag (A^T)[m][k] = At[m][k]; B-frag B[k][n] = At[n][k] — both row-contiguous.
__global__ __launch_bounds__(256) void gram_kernel(const float* __restrict__ A, int nrows,
                                                   float* __restrict__ part) {
    __shared__ unsigned short At[64 * LSTRIDE];   // At[c][r]
    int t = threadIdx.x;
    int w16 = (t >> 6) * 16, lane = t & 63, m16 = lane & 15, quad = lane >> 4;
    int bi = t & 15, bj = t >> 4;   // bi: col-block of A, bj: row-block
    f32x4 zero = {0.f, 0.f, 0.f, 0.f};
    f32x4 acc[4] = {zero, zero, zero, zero};
    for (long base = (long)blockIdx.x * 64; base < nrows; base += (long)GRAM_NB * 64) {
        __syncthreads();   // protect At reads from previous iteration
        float rv[4][4];
#pragma unroll
        for (int e = 0; e < 4; ++e) {
            long gr = base + bj * 4 + e;
            float4 f = make_float4(0.f, 0.f, 0.f, 0.f);
            if (gr < nrows) f = *(const float4*)&A[gr * DDIM + bi * 4];
            rv[e][0] = f.x; rv[e][1] = f.y; rv[e][2] = f.z; rv[e][3] = f.w;
        }
#pragma unroll
        for (int e = 0; e < 4; ++e) {
            ushort4 o;
            o.x = f2b(rv[0][e]); o.y = f2b(rv[1][e]); o.z = f2b(rv[2][e]); o.w = f2b(rv[3][e]);
            *(ushort4*)&At[(bi * 4 + e) * LSTRIDE + bj * 4] = o;
        }
        __syncthreads();
#pragma unroll
        for (int ks = 0; ks < 2; ++ks) {
            bf16x8 a = *(const bf16x8*)&At[(w16 + m16) * LSTRIDE + ks * 32 + quad * 8];
#pragma unroll
            for (int nt = 0; nt < 4; ++nt) {
                bf16x8 bfr = *(const bf16x8*)&At[(nt * 16 + m16) * LSTRIDE + ks * 32 + quad * 8];
                acc[nt] = __builtin_amdgcn_mfma_f32_16x16x32_bf16(a, bfr, acc[nt], 0, 0, 0);
            }
        }
    }
    float* slab = part + (long)blockIdx.x * 4096;
#pragma unroll
    for (int nt = 0; nt < 4; ++nt) {
        int n = nt * 16 + m16;
#pragma unroll
        for (int rg = 0; rg < 4; ++rg) {
            int m = w16 + quad * 4 + rg;
            slab[m * 64 + n] = acc[nt][rg];
        }
    }
}

// out[p] = sum_b part[b*4096+p]
__global__ __launch_bounds__(256) void gram_reduce(const float* __restrict__ part,
                                                   float* __restrict__ out) {
    int p = blockIdx.x * 256 + threadIdx.x;   // 16 blocks
    float s = 0.f;
    for (int b = 0; b < GRAM_NB; ++b) s += part[(long)b * 4096 + p];
    out[p] = s;
}

// ---------------- right(): per-block partial sums of (1-C)ps^2 - 2ps ----------------
__global__ __launch_bounds__(256) void right_kernel(const float* __restrict__ x,
                                                    const float* __restrict__ item_emb,
                                                    const int* __restrict__ pos_seqs,
                                                    const float* __restrict__ pred_w,
                                                    float* __restrict__ rpart) {
    __shared__ float p_s[64];
    __shared__ float red[4];
    int t = threadIdx.x;
    if (t < 64) p_s[t] = pred_w[t];
    __syncthreads();
    int w = t >> 6, lane = t & 63;
    float local = 0.f;
    for (long row = (long)blockIdx.x * 4 + w; row < NROWS; row += (long)gridDim.x * 4) {
        int pi = pos_seqs[row];
        float val = x[row * DDIM + lane] * item_emb[(long)pi * DDIM + lane] * p_s[lane];
        float ps = wave_sum(val);           // lane-uniform
        local += (1.0f - CC) * ps * ps - 2.0f * ps;   // identical on all 64 lanes
    }
    if (lane == 0) red[w] = local;
    __syncthreads();
    if (t == 0) rpart[blockIdx.x] = red[0] + red[1] + red[2] + red[3];
}

// ---------------- per-parameter sum-of-squares ----------------
struct NormEntry { const float* p; int n; };
struct NormArgs { NormEntry e[30]; };

__global__ __launch_bounds__(256) void norms_kernel(NormArgs args, float* __restrict__ norms) {
    __shared__ float red[256];
    NormEntry en = args.e[blockIdx.x];
    float s = 0.f;
    for (int i = threadIdx.x; i < en.n; i += 256) { float v = en.p[i]; s += v * v; }
    red[threadIdx.x] = s;
    for (int o = 128; o > 0; o >>= 1) {
        __syncthreads();
        if (threadIdx.x < o) red[threadIdx.x] += red[threadIdx.x + o];
    }
    __syncthreads();
    if (threadIdx.x == 0) norms[blockIdx.x] = red[0];
}

// ---------------- final scalar ----------------
__global__ __launch_bounds__(256) void final_kernel(const float* __restrict__ EE,
                                                    const float* __restrict__ FF,
                                                    const float* __restrict__ pred_w,
                                                    const float* __restrict__ rpart,
                                                    const float* __restrict__ norms,
                                                    float* __restrict__ out) {
    __shared__ float p_s[64];
    __shared__ float redL[256];
    __shared__ float redT[256];
    __shared__ float redR[256];
    int t = threadIdx.x;
    if (t < 64) p_s[t] = pred_w[t];
    __syncthreads();
    float lf = 0.f, tr = 0.f, rs = 0.f;
    for (int p = t; p < 4096; p += 256) {
        int i = p >> 6, j = p & 63;
        float ee = EE[p];
        lf += FF[p] * ee * p_s[i] * p_s[j];
        if (i == j) tr += ee;
    }
    for (int i = t; i < 1024; i += 256) rs += rpart[i];
    redL[t] = lf; redT[t] = tr; redR[t] = rs;
    for (int o = 128; o > 0; o >>= 1) {
        __syncthreads();
        if (t < o) { redL[t] += redL[t + o]; redT[t] += redT[t + o]; redR[t] += redR[t + o]; }
    }
    __syncthreads();
    if (t == 0) {
        float reg = sqrtf(redT[0]);   // ||item_emb||_F = sqrt(trace(EE))
        for (int s = 0; s < 30; ++s) reg += sqrtf(norms[s]);
        out[0] = CC * redL[0] + redR[0] + 0.1f * reg;
    }
}

// ---------------- host ----------------
struct DevPtrs { float *x, *ctx, *gpart; unsigned short *qb, *kb, *vb; };

static DevPtrs fetch_ptrs() {
    DevPtrs p;
    (void)hipGetSymbolAddress((void**)&p.x,    HIP_SYMBOL(g_x));
    (void)hipGetSymbolAddress((void**)&p.ctx,  HIP_SYMBOL(g_ctx));
    (void)hipGetSymbolAddress((void**)&p.gpart,HIP_SYMBOL(g_gpart));
    (void)hipGetSymbolAddress((void**)&p.qb,   HIP_SYMBOL(g_qb));
    (void)hipGetSymbolAddress((void**)&p.kb,   HIP_SYMBOL(g_kb));
    (void)hipGetSymbolAddress((void**)&p.vb,   HIP_SYMBOL(g_vb));
    return p;
}

extern "C" void kernel_launch(void* const* d_in, const int* in_sizes, int n_in,
                              void* d_out, int out_size, void* d_ws, size_t ws_size,
                              hipStream_t stream) {
    const int*   log_seqs = (const int*)d_in[1];
    const int*   pos_seqs = (const int*)d_in[2];
    const float* item_emb = (const float*)d_in[3];
    const float* pos_emb  = (const float*)d_in[4];
    const float* pred_w   = (const float*)d_in[5];
    const float* ln_w     = (const float*)d_in[6];
    const float* ln_b     = (const float*)d_in[7];
    const float* qkv_w    = (const float*)d_in[8];
    const float* qkv_b    = (const float*)d_in[9];
    const float* out_w    = (const float*)d_in[10];
    const float* out_b    = (const float*)d_in[11];
    const float* fc1_w    = (const float*)d_in[12];
    const float* fc1_b    = (const float*)d_in[13];
    const float* ffln_w   = (const float*)d_in[14];
    const float* ffln_b   = (const float*)d_in[15];
    const float* fc2_w    = (const float*)d_in[16];
    const float* fc2_b    = (const float*)d_in[17];
    const float* ffln2_w  = (const float*)d_in[18];
    const float* ffln2_b  = (const float*)d_in[19];

    static DevPtrs P = fetch_ptrs();   // first call is the uncaptured correctness call

    float* ws    = (float*)d_ws;
    float* rpart = ws;            // 1024
    float* nrm   = ws + 1024;     // 30
    float* EE    = ws + 2048;     // 4096
    float* FF    = ws + 6144;     // 4096

    embed_kernel<<<NROWS * 16 / 256, 256, 0, stream>>>(log_seqs, item_emb, pos_emb, P.x);

    const int GEMM_GRID = NROWS / 64;   // 1600

    for (int l = 0; l < LL; ++l) {
        const float* Wqkv = qkv_w + (long)l * 3 * 64 * 64;
        const float* Bqkv = qkv_b + (long)l * 192;
        qkv_fused<<<GEMM_GRID, 256, 0, stream>>>(
            P.x, Wqkv, Bqkv, ln_w + l * 64, ln_b + l * 64, P.qb, P.kb, P.vb);
        attn_kernel<<<BB * 2, 256, 0, stream>>>(P.qb, P.kb, P.vb, P.ctx);
        ffn_fused<<<GEMM_GRID, 256, 0, stream>>>(
            P.ctx, P.x,
            out_w + (long)l * 4096, out_b + l * 64,
            fc1_w + (long)l * 4096, fc1_b + l * 64,
            fc2_w + (long)l * 4096, fc2_b + l * 64,
            ln_w + l * 64, ln_b + l * 64,
            ffln_w + l * 64, ffln_b + l * 64,
            ffln2_w + l * 64, ffln2_b + l * 64,
            P.x);
    }

    gram_kernel<<<GRAM_NB, 256, 0, stream>>>(item_emb, 100001, P.gpart);
    gram_reduce<<<16, 256, 0, stream>>>(P.gpart, EE);
    gram_kernel<<<GRAM_NB, 256, 0, stream>>>(P.x, NROWS, P.gpart);
    gram_reduce<<<16, 256, 0, stream>>>(P.gpart, FF);
    right_kernel<<<1024, 256, 0, stream>>>(P.x, item_emb, pos_seqs, pred_w, rpart);

    NormArgs na;
    int s = 0;
    na.e[s++] = {pos_emb, (SS + 1) * DDIM};
    na.e[s++] = {pred_w, DDIM};
    for (int l = 0; l < LL; ++l) {
        na.e[s++] = {ln_w + l * 64, 64};
        na.e[s++] = {ln_b + l * 64, 64};
        na.e[s++] = {qkv_w + (long)l * 12288, 12288};
        na.e[s++] = {qkv_b + (long)l * 192, 192};
        na.e[s++] = {out_w + (long)l * 4096, 4096};
        na.e[s++] = {out_b + l * 64, 64};
        na.e[s++] = {fc1_w + (long)l * 4096, 4096};
        na.e[s++] = {fc1_b + l * 64, 64};
        na.e[s++] = {ffln_w + l * 64, 64};
        na.e[s++] = {ffln_b + l * 64, 64};
        na.e[s++] = {fc2_w + (long)l * 4096, 4096};
        na.e[s++] = {fc2_b + l * 64, 64};
        na.e[s++] = {ffln2_w + l * 64, 64};
        na.e[s++] = {ffln2_b + l * 64, 64};
    }
    norms_kernel<<<30, 256, 0, stream>>>(na, nrm);

    final_kernel<<<1, 256, 0, stream>>>(EE, FF, pred_w, rpart, nrm, (float*)d_out);
}

// Round 15
// 366.605 us; speedup vs baseline: 2.4602x; 1.0478x over previous
//
#include <hip/hip_runtime.h>
#include <math.h>

#define BB 512
#define SS 200
#define DDIM 64
#define HD 32
#define LL 2
#define NROWS (BB * SS)   // 102400
#define EPS 1e-8f
#define CC 0.001f
#define GRAM_NB 512
#define LSTRIDE 72

typedef __attribute__((ext_vector_type(8))) short bf16x8;
typedef __attribute__((ext_vector_type(4))) float f32x4;

// ---------------- static device buffers (activations) ----------------
__device__ float g_x[NROWS * DDIM];
__device__ unsigned short g_ctx[NROWS * DDIM];
__device__ unsigned short g_qb[NROWS * DDIM];
__device__ unsigned short g_kb[NROWS * DDIM];
__device__ unsigned short g_vb[NROWS * DDIM];
__device__ float g_gpart[GRAM_NB * 4096];   // gram per-block partials

// ---------------- helpers ----------------
__device__ __forceinline__ float wave_sum(float v) {
#pragma unroll
    for (int o = 32; o > 0; o >>= 1) v += __shfl_xor(v, o, 64);
    return v;
}
__device__ __forceinline__ unsigned short f2b(float f) {
    unsigned u = __float_as_uint(f);
    return (unsigned short)((u + 0x7FFFu + ((u >> 16) & 1u)) >> 16);
}
__device__ __forceinline__ float b2f(unsigned short u) {
    return __uint_as_float(((unsigned)u) << 16);
}

// ---------------- embedding (float4) ----------------
__global__ __launch_bounds__(256) void embed_kernel(const int* __restrict__ log_seqs,
                                                    const float* __restrict__ item_emb,
                                                    const float* __restrict__ pos_emb,
                                                    float* __restrict__ x) {
    int tid = blockIdx.x * 256 + threadIdx.x;   // over NROWS*16
    int row = tid >> 4, q4 = tid & 15;
    int s = row % SS;
    int li = log_seqs[row];
    int poss = li ? (s + 1) : 0;
    float4 e = *(const float4*)&item_emb[li * DDIM + q4 * 4];
    float4 p = *(const float4*)&pos_emb[poss * DDIM + q4 * 4];
    float4 o;
    o.x = e.x * 8.0f + p.x; o.y = e.y * 8.0f + p.y;
    o.z = e.z * 8.0f + p.z; o.w = e.w * 8.0f + p.w;
    *(float4*)&x[row * DDIM + q4 * 4] = o;
}

// ---------------- MFMA GEMM staging helpers (bf16 LDS, stride 72) ----------------
__device__ __forceinline__ void stage_bf16_tile(const float* __restrict__ G, unsigned short* __restrict__ L,
                                                int t, long row0) {
#pragma unroll
    for (int rep = 0; rep < 4; ++rep) {
        int idx = t + rep * 256;
        int r = idx >> 4, c4 = (idx & 15) * 4;
        float4 f = *(const float4*)&G[(row0 + r) * DDIM + c4];
        ushort4 o; o.x = f2b(f.x); o.y = f2b(f.y); o.z = f2b(f.z); o.w = f2b(f.w);
        *(ushort4*)&L[r * LSTRIDE + c4] = o;
    }
}

// copy a bf16 global tile into LDS (stride 72)
__device__ __forceinline__ void stage_bf16_copy(const unsigned short* __restrict__ G, unsigned short* __restrict__ L,
                                                int t, long row0) {
#pragma unroll
    for (int rep = 0; rep < 4; ++rep) {
        int idx = t + rep * 256;
        int r = idx >> 4, c4 = (idx & 15) * 4;
        *(ushort4*)&L[r * LSTRIDE + c4] = *(const ushort4*)&G[(row0 + r) * DDIM + c4];
    }
}

__device__ __forceinline__ void stage_w_bf16(const float* __restrict__ Wg, unsigned short* __restrict__ L, int t) {
#pragma unroll
    for (int rep = 0; rep < 4; ++rep) {
        int idx = t + rep * 256;
        int r = idx >> 4, c4 = (idx & 15) * 4;
        float4 f = *(const float4*)&Wg[r * DDIM + c4];
        ushort4 o; o.x = f2b(f.x); o.y = f2b(f.y); o.z = f2b(f.z); o.w = f2b(f.w);
        *(ushort4*)&L[r * LSTRIDE + c4] = o;
    }
}

// LN(x rows) -> bf16 LDS tile. thread t: row t>>2, 16-col chunk (t&3)*16.
__device__ __forceinline__ void stage_ln_bf16(const float* __restrict__ x, unsigned short* __restrict__ L,
                                              const float* __restrict__ lnw, const float* __restrict__ lnb,
                                              int t, long row0) {
    int rr = t >> 2, qd = (t & 3) * 16;
    float4 v[4];
#pragma unroll
    for (int g = 0; g < 4; ++g) v[g] = *(const float4*)&x[(row0 + rr) * DDIM + qd + g * 4];
    float s1 = 0.f, s2 = 0.f;
#pragma unroll
    for (int g = 0; g < 4; ++g) {
        s1 += (v[g].x + v[g].y) + (v[g].z + v[g].w);
        s2 += (v[g].x * v[g].x + v[g].y * v[g].y) + (v[g].z * v[g].z + v[g].w * v[g].w);
    }
    s1 += __shfl_xor(s1, 1, 64); s1 += __shfl_xor(s1, 2, 64);
    s2 += __shfl_xor(s2, 1, 64); s2 += __shfl_xor(s2, 2, 64);
    float m = s1 * (1.f / 64.f);
    float var = s2 * (1.f / 64.f) - m * m;
    float rs = rsqrtf(var + EPS);
#pragma unroll
    for (int g = 0; g < 4; ++g) {
        float4 w4 = *(const float4*)&lnw[qd + g * 4];
        float4 b4 = *(const float4*)&lnb[qd + g * 4];
        ushort4 o;
        o.x = f2b((v[g].x - m) * rs * w4.x + b4.x);
        o.y = f2b((v[g].y - m) * rs * w4.y + b4.y);
        o.z = f2b((v[g].z - m) * rs * w4.z + b4.z);
        o.w = f2b((v[g].w - m) * rs * w4.w + b4.w);
        *(ushort4*)&L[rr * LSTRIDE + qd + g * 4] = o;
    }
}

// 64x64x64 GEMM slice for wave w: out rows w16..w16+15, all 64 cols.
__device__ __forceinline__ void mfma_gemm(const unsigned short* __restrict__ A,
                                          const unsigned short* __restrict__ B,
                                          int w16, int m16, int quad, f32x4 acc[4]) {
    bf16x8 a0 = *(const bf16x8*)&A[(w16 + m16) * LSTRIDE + quad * 8];
    bf16x8 a1 = *(const bf16x8*)&A[(w16 + m16) * LSTRIDE + 32 + quad * 8];
#pragma unroll
    for (int nt = 0; nt < 4; ++nt) {
        bf16x8 b0 = *(const bf16x8*)&B[(nt * 16 + m16) * LSTRIDE + quad * 8];
        bf16x8 b1 = *(const bf16x8*)&B[(nt * 16 + m16) * LSTRIDE + 32 + quad * 8];
        acc[nt] = __builtin_amdgcn_mfma_f32_16x16x32_bf16(a0, b0, acc[nt], 0, 0, 0);
        acc[nt] = __builtin_amdgcn_mfma_f32_16x16x32_bf16(a1, b1, acc[nt], 0, 0, 0);
    }
}

// ---------------- fused QKV (MFMA) ----------------
__global__ __launch_bounds__(256) void qkv_fused(const float* __restrict__ x,
                                                 const float* __restrict__ Wqkv,
                                                 const float* __restrict__ Bqkv,
                                                 const float* __restrict__ lnw,
                                                 const float* __restrict__ lnb,
                                                 unsigned short* __restrict__ qo,
                                                 unsigned short* __restrict__ ko,
                                                 unsigned short* __restrict__ vo) {
    __shared__ unsigned short Ab[64 * LSTRIDE], Lb[64 * LSTRIDE];
    __shared__ unsigned short Wq[64 * LSTRIDE], Wk[64 * LSTRIDE], Wv[64 * LSTRIDE];
    int t = threadIdx.x;
    long row0 = (long)blockIdx.x * 64;
    stage_bf16_tile(x, Ab, t, row0);
    stage_ln_bf16(x, Lb, lnw, lnb, t, row0);
    stage_w_bf16(Wqkv, Wq, t);
    stage_w_bf16(Wqkv + 4096, Wk, t);
    stage_w_bf16(Wqkv + 8192, Wv, t);
    __syncthreads();
    int w16 = (t >> 6) * 16, lane = t & 63, m16 = lane & 15, quad = lane >> 4;
    f32x4 zero = {0.f, 0.f, 0.f, 0.f};
    {
        f32x4 acc[4] = {zero, zero, zero, zero};
        mfma_gemm(Lb, Wq, w16, m16, quad, acc);
#pragma unroll
        for (int nt = 0; nt < 4; ++nt) {
            int n = nt * 16 + m16;
            float bb = Bqkv[n];
#pragma unroll
            for (int rg = 0; rg < 4; ++rg)
                qo[(row0 + w16 + quad * 4 + rg) * DDIM + n] = f2b(acc[nt][rg] + bb);
        }
    }
    {
        f32x4 acc[4] = {zero, zero, zero, zero};
        mfma_gemm(Ab, Wk, w16, m16, quad, acc);
#pragma unroll
        for (int nt = 0; nt < 4; ++nt) {
            int n = nt * 16 + m16;
            float bb = Bqkv[64 + n];
#pragma unroll
            for (int rg = 0; rg < 4; ++rg)
                ko[(row0 + w16 + quad * 4 + rg) * DDIM + n] = f2b(acc[nt][rg] + bb);
        }
    }
    {
        f32x4 acc[4] = {zero, zero, zero, zero};
        mfma_gemm(Ab, Wv, w16, m16, quad, acc);
#pragma unroll
        for (int nt = 0; nt < 4; ++nt) {
            int n = nt * 16 + m16;
            float bb = Bqkv[128 + n];
#pragma unroll
            for (int rg = 0; rg < 4; ++rg)
                vo[(row0 + w16 + quad * 4 + rg) * DDIM + n] = f2b(acc[nt][rg] + bb);
        }
    }
}

// ---------------- fused out-proj + FFN (MFMA, wave-local chains) ----------------
__global__ __launch_bounds__(256) void ffn_fused(const unsigned short* __restrict__ ctx,
                                                 const float* __restrict__ x,
                                                 const float* __restrict__ Wo, const float* __restrict__ bo,
                                                 const float* __restrict__ W1, const float* __restrict__ b1,
                                                 const float* __restrict__ W2, const float* __restrict__ b2,
                                                 const float* __restrict__ l0w, const float* __restrict__ l0b,
                                                 const float* __restrict__ l1w, const float* __restrict__ l1b,
                                                 const float* __restrict__ l2w, const float* __restrict__ l2b,
                                                 float* __restrict__ xout) {
    __shared__ unsigned short Cb[64 * LSTRIDE], Qb[64 * LSTRIDE];
    __shared__ unsigned short W0s[64 * LSTRIDE], W1s[64 * LSTRIDE], W2s[64 * LSTRIDE];
    __shared__ float vecs[7][64];   // bo,b1,b2,l1w,l1b,l2w,l2b
    int t = threadIdx.x;
    long row0 = (long)blockIdx.x * 64;
    stage_bf16_copy(ctx, Cb, t, row0);
    stage_ln_bf16(x, Qb, l0w, l0b, t, row0);   // qin = LN(x; ln0), bf16
    stage_w_bf16(Wo, W0s, t);
    stage_w_bf16(W1, W1s, t);
    stage_w_bf16(W2, W2s, t);
    if (t < 64) {
        vecs[0][t] = bo[t]; vecs[1][t] = b1[t]; vecs[2][t] = b2[t];
        vecs[3][t] = l1w[t]; vecs[4][t] = l1b[t]; vecs[5][t] = l2w[t]; vecs[6][t] = l2b[t];
    }
    __syncthreads();
    int w16 = (t >> 6) * 16, lane = t & 63, m16 = lane & 15, quad = lane >> 4;
    f32x4 zero = {0.f, 0.f, 0.f, 0.f};
    f32x4 acc1[4] = {zero, zero, zero, zero};
    mfma_gemm(Cb, W0s, w16, m16, quad, acc1);
    float x1[4][4];
#pragma unroll
    for (int nt = 0; nt < 4; ++nt) {
        int n = nt * 16 + m16;
        float bb = vecs[0][n];
#pragma unroll
        for (int rg = 0; rg < 4; ++rg) {
            int m = w16 + quad * 4 + rg;
            x1[nt][rg] = acc1[nt][rg] + bb + b2f(Qb[m * LSTRIDE + n]);
        }
    }
    float ln1v[4][4], ln2v[4][4];
#pragma unroll
    for (int rg = 0; rg < 4; ++rg) {
        float s1 = (x1[0][rg] + x1[1][rg]) + (x1[2][rg] + x1[3][rg]);
        float s2 = x1[0][rg] * x1[0][rg] + x1[1][rg] * x1[1][rg]
                 + x1[2][rg] * x1[2][rg] + x1[3][rg] * x1[3][rg];
#pragma unroll
        for (int o = 1; o <= 8; o <<= 1) { s1 += __shfl_xor(s1, o, 64); s2 += __shfl_xor(s2, o, 64); }
        float mean = s1 * (1.f / 64.f);
        float var = s2 * (1.f / 64.f) - mean * mean;
        float rs = rsqrtf(var + EPS);
#pragma unroll
        for (int nt = 0; nt < 4; ++nt) {
            int n = nt * 16 + m16;
            float core = (x1[nt][rg] - mean) * rs;
            ln1v[nt][rg] = core * vecs[3][n] + vecs[4][n];
            ln2v[nt][rg] = core * vecs[5][n] + vecs[6][n];
        }
    }
    __builtin_amdgcn_wave_barrier();
#pragma unroll
    for (int nt = 0; nt < 4; ++nt)
#pragma unroll
        for (int rg = 0; rg < 4; ++rg)
            Cb[(w16 + quad * 4 + rg) * LSTRIDE + nt * 16 + m16] = f2b(ln1v[nt][rg]);
    __builtin_amdgcn_wave_barrier();
    f32x4 acc2[4] = {zero, zero, zero, zero};
    mfma_gemm(Cb, W1s, w16, m16, quad, acc2);
    __builtin_amdgcn_wave_barrier();
#pragma unroll
    for (int nt = 0; nt < 4; ++nt) {
        int n = nt * 16 + m16;
        float bb = vecs[1][n];
#pragma unroll
        for (int rg = 0; rg < 4; ++rg)
            Qb[(w16 + quad * 4 + rg) * LSTRIDE + n] = f2b(fmaxf(acc2[nt][rg] + bb, 0.f));
    }
    __builtin_amdgcn_wave_barrier();
    f32x4 acc3[4] = {zero, zero, zero, zero};
    mfma_gemm(Qb, W2s, w16, m16, quad, acc3);
#pragma unroll
    for (int nt = 0; nt < 4; ++nt) {
        int n = nt * 16 + m16;
        float bb = vecs[2][n];
#pragma unroll
        for (int rg = 0; rg < 4; ++rg) {
            int m = w16 + quad * 4 + rg;
            xout[(row0 + m) * DDIM + n] = acc3[nt][rg] + bb + ln2v[nt][rg];
        }
    }
}

// ---------------- MFMA flash attention, single-pass softmax ----------------
// Scores for a whole row (<=7 pairs) held in registers; one max reduce, one
// exp pass, one sum reduce per row. ctx written bf16.
__global__ __launch_bounds__(256) void attn_kernel(const unsigned short* __restrict__ q,
                                                   const unsigned short* __restrict__ k,
                                                   const unsigned short* __restrict__ v,
                                                   unsigned short* __restrict__ ctx) {
    __shared__ unsigned short Kb[224 * 32];    // Kb[kk][d], zero for kk>=200
    __shared__ unsigned short Vt[32 * 232];    // Vt[d][kk], zero for kk>=200
    __shared__ unsigned short Ps[4][16 * 32];  // per-wave P buffer
    int b = blockIdx.x >> 1, h = blockIdx.x & 1;
    int t = threadIdx.x;
    const long base = (long)b * (SS * DDIM) + h * HD;
    for (int i = t; i < 224 * 8; i += 256) {   // ushort4 chunks
        int kk = i >> 3, d4 = (i & 7) * 4;
        ushort4 kv = make_ushort4(0, 0, 0, 0), vv = make_ushort4(0, 0, 0, 0);
        if (kk < SS) {
            kv = *(const ushort4*)&k[base + kk * DDIM + d4];
            vv = *(const ushort4*)&v[base + kk * DDIM + d4];
        }
        *(ushort4*)&Kb[kk * 32 + d4] = kv;
        Vt[(d4 + 0) * 232 + kk] = vv.x;
        Vt[(d4 + 1) * 232 + kk] = vv.y;
        Vt[(d4 + 2) * 232 + kk] = vv.z;
        Vt[(d4 + 3) * 232 + kk] = vv.w;
    }
    __syncthreads();
    int w = t >> 6, lane = t & 63;
    int m16 = lane & 15, quad = lane >> 4;
    const float scale = 0.17677669529663687f;   // 1/sqrt(32)
    unsigned short* ps = Ps[w];
    for (int qt = w; qt < 13; qt += 4) {
        int q0 = qt * 16;
        int qrow = q0 + m16; if (qrow > SS - 1) qrow = SS - 1;
        bf16x8 qa = *(const bf16x8*)&q[base + qrow * DDIM + quad * 8];
        f32x4 o0 = {0.f, 0.f, 0.f, 0.f}, o1 = {0.f, 0.f, 0.f, 0.f};
        f32x4 s0a[7], s1a[7];
        float vmax[4] = {-1e30f, -1e30f, -1e30f, -1e30f};
        int np = (qt + 2) >> 1;
        // pass 1: all QK scores into registers, local max only
#pragma unroll
        for (int pi = 0; pi < 7; ++pi) {
            if (pi < np) {
                int p0 = pi * 32;
                bf16x8 kb0 = *(bf16x8*)&Kb[(p0 + m16) * 32 + quad * 8];
                bf16x8 kb1 = *(bf16x8*)&Kb[(p0 + 16 + m16) * 32 + quad * 8];
                f32x4 z = {0.f, 0.f, 0.f, 0.f};
                f32x4 s0 = __builtin_amdgcn_mfma_f32_16x16x32_bf16(qa, kb0, z, 0, 0, 0);
                f32x4 s1 = __builtin_amdgcn_mfma_f32_16x16x32_bf16(qa, kb1, z, 0, 0, 0);
                int col0 = p0 + m16, col1 = col0 + 16;
#pragma unroll
                for (int rg = 0; rg < 4; ++rg) {
                    int rglob = q0 + quad * 4 + rg;
                    float v0 = (col0 <= rglob && col0 < SS) ? s0[rg] * scale : -1e30f;
                    float v1 = (col1 <= rglob && col1 < SS) ? s1[rg] * scale : -1e30f;
                    s0a[pi][rg] = v0; s1a[pi][rg] = v1;
                    vmax[rg] = fmaxf(vmax[rg], fmaxf(v0, v1));
                }
            }
        }
        // row max reduce (once)
#pragma unroll
        for (int rg = 0; rg < 4; ++rg)
#pragma unroll
            for (int o = 1; o <= 8; o <<= 1) vmax[rg] = fmaxf(vmax[rg], __shfl_xor(vmax[rg], o, 64));
        // pass 2: exp, local sum, P -> LDS, PV MFMAs
        float lsum[4] = {0.f, 0.f, 0.f, 0.f};
#pragma unroll
        for (int pi = 0; pi < 7; ++pi) {
            if (pi < np) {
                int p0 = pi * 32;
                float e0[4], e1[4];
#pragma unroll
                for (int rg = 0; rg < 4; ++rg) {
                    e0[rg] = __expf(s0a[pi][rg] - vmax[rg]);
                    e1[rg] = __expf(s1a[pi][rg] - vmax[rg]);
                    lsum[rg] += e0[rg] + e1[rg];
                }
                __builtin_amdgcn_wave_barrier();
#pragma unroll
                for (int rg = 0; rg < 4; ++rg) {
                    int row = quad * 4 + rg;
                    ps[row * 32 + m16] = f2b(e0[rg]);
                    ps[row * 32 + 16 + m16] = f2b(e1[rg]);
                }
                __builtin_amdgcn_wave_barrier();
                bf16x8 pa = *(bf16x8*)&ps[m16 * 32 + quad * 8];
                bf16x8 vb0 = *(bf16x8*)&Vt[m16 * 232 + p0 + quad * 8];
                bf16x8 vb1 = *(bf16x8*)&Vt[(m16 + 16) * 232 + p0 + quad * 8];
                o0 = __builtin_amdgcn_mfma_f32_16x16x32_bf16(pa, vb0, o0, 0, 0, 0);
                o1 = __builtin_amdgcn_mfma_f32_16x16x32_bf16(pa, vb1, o1, 0, 0, 0);
            }
        }
        // row sum reduce (once)
#pragma unroll
        for (int rg = 0; rg < 4; ++rg)
#pragma unroll
            for (int o = 1; o <= 8; o <<= 1) lsum[rg] += __shfl_xor(lsum[rg], o, 64);
#pragma unroll
        for (int rg = 0; rg < 4; ++rg) {
            int rglob = q0 + quad * 4 + rg;
            if (rglob < SS) {
                float inv = 1.f / lsum[rg];
                ctx[base + rglob * DDIM + m16] = f2b(o0[rg] * inv);
                ctx[base + rglob * DDIM + 16 + m16] = f2b(o1[rg] * inv);
            }
        }
    }
}

// ---------------- MFMA Gram: part[b] = chunk-sum A^T A (bf16 in, fp32 acc) ----------------
__global__ __launch_bounds__(256) void gram_kernel(const float* __restrict__ A, int nrows,
                                                   float* __restrict__ part) {
    __shared__ unsigned short At[64 * LSTRIDE];   // At[c][r]
    int t = threadIdx.x;
    int w16 = (t >> 6) * 16, lane = t & 63, m16 = lane & 15, quad = lane >> 4;
    int bi = t & 15, bj = t >> 4;   // bi: col-block of A, bj: row-block
    f32x4 zero = {0.f, 0.f, 0.f, 0.f};
    f32x4 acc[4] = {zero, zero, zero, zero};
    for (long base = (long)blockIdx.x * 64; base < nrows; base += (long)GRAM_NB * 64) {
        __syncthreads();   // protect At reads from previous iteration
        float rv[4][4];
#pragma unroll
        for (int e = 0; e < 4; ++e) {
            long gr = base + bj * 4 + e;
            float4 f = make_float4(0.f, 0.f, 0.f, 0.f);
            if (gr < nrows) f = *(const float4*)&A[gr * DDIM + bi * 4];
            rv[e][0] = f.x; rv[e][1] = f.y; rv[e][2] = f.z; rv[e][3] = f.w;
        }
#pragma unroll
        for (int e = 0; e < 4; ++e) {
            ushort4 o;
            o.x = f2b(rv[0][e]); o.y = f2b(rv[1][e]); o.z = f2b(rv[2][e]); o.w = f2b(rv[3][e]);
            *(ushort4*)&At[(bi * 4 + e) * LSTRIDE + bj * 4] = o;
        }
        __syncthreads();
#pragma unroll
        for (int ks = 0; ks < 2; ++ks) {
            bf16x8 a = *(const bf16x8*)&At[(w16 + m16) * LSTRIDE + ks * 32 + quad * 8];
#pragma unroll
            for (int nt = 0; nt < 4; ++nt) {
                bf16x8 bfr = *(const bf16x8*)&At[(nt * 16 + m16) * LSTRIDE + ks * 32 + quad * 8];
                acc[nt] = __builtin_amdgcn_mfma_f32_16x16x32_bf16(a, bfr, acc[nt], 0, 0, 0);
            }
        }
    }
    float* slab = part + (long)blockIdx.x * 4096;
#pragma unroll
    for (int nt = 0; nt < 4; ++nt) {
        int n = nt * 16 + m16;
#pragma unroll
        for (int rg = 0; rg < 4; ++rg) {
            int m = w16 + quad * 4 + rg;
            slab[m * 64 + n] = acc[nt][rg];
        }
    }
}

// out[p] = sum_b part[b*4096+p]
__global__ __launch_bounds__(256) void gram_reduce(const float* __restrict__ part,
                                                   float* __restrict__ out) {
    int p = blockIdx.x * 256 + threadIdx.x;   // 16 blocks
    float s = 0.f;
    for (int b = 0; b < GRAM_NB; ++b) s += part[(long)b * 4096 + p];
    out[p] = s;
}

// ---------------- right(): per-block partial sums of (1-C)ps^2 - 2ps ----------------
__global__ __launch_bounds__(256) void right_kernel(const float* __restrict__ x,
                                                    const float* __restrict__ item_emb,
                                                    const int* __restrict__ pos_seqs,
                                                    const float* __restrict__ pred_w,
                                                    float* __restrict__ rpart) {
    __shared__ float p_s[64];
    __shared__ float red[4];
    int t = threadIdx.x;
    if (t < 64) p_s[t] = pred_w[t];
    __syncthreads();
    int w = t >> 6, lane = t & 63;
    float local = 0.f;
    for (long row = (long)blockIdx.x * 4 + w; row < NROWS; row += (long)gridDim.x * 4) {
        int pi = pos_seqs[row];
        float val = x[row * DDIM + lane] * item_emb[(long)pi * DDIM + lane] * p_s[lane];
        float ps = wave_sum(val);           // lane-uniform
        local += (1.0f - CC) * ps * ps - 2.0f * ps;   // identical on all 64 lanes
    }
    if (lane == 0) red[w] = local;
    __syncthreads();
    if (t == 0) rpart[blockIdx.x] = red[0] + red[1] + red[2] + red[3];
}

// ---------------- per-parameter sum-of-squares ----------------
struct NormEntry { const float* p; int n; };
struct NormArgs { NormEntry e[30]; };

__global__ __launch_bounds__(256) void norms_kernel(NormArgs args, float* __restrict__ norms) {
    __shared__ float red[256];
    NormEntry en = args.e[blockIdx.x];
    float s = 0.f;
    for (int i = threadIdx.x; i < en.n; i += 256) { float v = en.p[i]; s += v * v; }
    red[threadIdx.x] = s;
    for (int o = 128; o > 0; o >>= 1) {
        __syncthreads();
        if (threadIdx.x < o) red[threadIdx.x] += red[threadIdx.x + o];
    }
    __syncthreads();
    if (threadIdx.x == 0) norms[blockIdx.x] = red[0];
}

// ---------------- final scalar ----------------
__global__ __launch_bounds__(256) void final_kernel(const float* __restrict__ EE,
                                                    const float* __restrict__ FF,
                                                    const float* __restrict__ pred_w,
                                                    const float* __restrict__ rpart,
                                                    const float* __restrict__ norms,
                                                    float* __restrict__ out) {
    __shared__ float p_s[64];
    __shared__ float redL[256];
    __shared__ float redT[256];
    __shared__ float redR[256];
    int t = threadIdx.x;
    if (t < 64) p_s[t] = pred_w[t];
    __syncthreads();
    float lf = 0.f, tr = 0.f, rs = 0.f;
    for (int p = t; p < 4096; p += 256) {
        int i = p >> 6, j = p & 63;
        float ee = EE[p];
        lf += FF[p] * ee * p_s[i] * p_s[j];
        if (i == j) tr += ee;
    }
    for (int i = t; i < 1024; i += 256) rs += rpart[i];
    redL[t] = lf; redT[t] = tr; redR[t] = rs;
    for (int o = 128; o > 0; o >>= 1) {
        __syncthreads();
        if (t < o) { redL[t] += redL[t + o]; redT[t] += redT[t + o]; redR[t] += redR[t + o]; }
    }
    __syncthreads();
    if (t == 0) {
        float reg = sqrtf(redT[0]);   // ||item_emb||_F = sqrt(trace(EE))
        for (int s = 0; s < 30; ++s) reg += sqrtf(norms[s]);
        out[0] = CC * redL[0] + redR[0] + 0.1f * reg;
    }
}

// ---------------- host ----------------
struct DevPtrs { float *x, *gpart; unsigned short *ctx, *qb, *kb, *vb; };

static DevPtrs fetch_ptrs() {
    DevPtrs p;
    (void)hipGetSymbolAddress((void**)&p.x,    HIP_SYMBOL(g_x));
    (void)hipGetSymbolAddress((void**)&p.ctx,  HIP_SYMBOL(g_ctx));
    (void)hipGetSymbolAddress((void**)&p.gpart,HIP_SYMBOL(g_gpart));
    (void)hipGetSymbolAddress((void**)&p.qb,   HIP_SYMBOL(g_qb));
    (void)hipGetSymbolAddress((void**)&p.kb,   HIP_SYMBOL(g_kb));
    (void)hipGetSymbolAddress((void**)&p.vb,   HIP_SYMBOL(g_vb));
    return p;
}

extern "C" void kernel_launch(void* const* d_in, const int* in_sizes, int n_in,
                              void* d_out, int out_size, void* d_ws, size_t ws_size,
                              hipStream_t stream) {
    const int*   log_seqs = (const int*)d_in[1];
    const int*   pos_seqs = (const int*)d_in[2];
    const float* item_emb = (const float*)d_in[3];
    const float* pos_emb  = (const float*)d_in[4];
    const float* pred_w   = (const float*)d_in[5];
    const float* ln_w     = (const float*)d_in[6];
    const float* ln_b     = (const float*)d_in[7];
    const float* qkv_w    = (const float*)d_in[8];
    const float* qkv_b    = (const float*)d_in[9];
    const float* out_w    = (const float*)d_in[10];
    const float* out_b    = (const float*)d_in[11];
    const float* fc1_w    = (const float*)d_in[12];
    const float* fc1_b    = (const float*)d_in[13];
    const float* ffln_w   = (const float*)d_in[14];
    const float* ffln_b   = (const float*)d_in[15];
    const float* fc2_w    = (const float*)d_in[16];
    const float* fc2_b    = (const float*)d_in[17];
    const float* ffln2_w  = (const float*)d_in[18];
    const float* ffln2_b  = (const float*)d_in[19];

    static DevPtrs P = fetch_ptrs();   // first call is the uncaptured correctness call

    float* ws    = (float*)d_ws;
    float* rpart = ws;            // 1024
    float* nrm   = ws + 1024;     // 30
    float* EE    = ws + 2048;     // 4096
    float* FF    = ws + 6144;     // 4096

    embed_kernel<<<NROWS * 16 / 256, 256, 0, stream>>>(log_seqs, item_emb, pos_emb, P.x);

    const int GEMM_GRID = NROWS / 64;   // 1600

    for (int l = 0; l < LL; ++l) {
        const float* Wqkv = qkv_w + (long)l * 3 * 64 * 64;
        const float* Bqkv = qkv_b + (long)l * 192;
        qkv_fused<<<GEMM_GRID, 256, 0, stream>>>(
            P.x, Wqkv, Bqkv, ln_w + l * 64, ln_b + l * 64, P.qb, P.kb, P.vb);
        attn_kernel<<<BB * 2, 256, 0, stream>>>(P.qb, P.kb, P.vb, P.ctx);
        ffn_fused<<<GEMM_GRID, 256, 0, stream>>>(
            P.ctx, P.x,
            out_w + (long)l * 4096, out_b + l * 64,
            fc1_w + (long)l * 4096, fc1_b + l * 64,
            fc2_w + (long)l * 4096, fc2_b + l * 64,
            ln_w + l * 64, ln_b + l * 64,
            ffln_w + l * 64, ffln_b + l * 64,
            ffln2_w + l * 64, ffln2_b + l * 64,
            P.x);
    }

    gram_kernel<<<GRAM_NB, 256, 0, stream>>>(item_emb, 100001, P.gpart);
    gram_reduce<<<16, 256, 0, stream>>>(P.gpart, EE);
    gram_kernel<<<GRAM_NB, 256, 0, stream>>>(P.x, NROWS, P.gpart);
    gram_reduce<<<16, 256, 0, stream>>>(P.gpart, FF);
    right_kernel<<<1024, 256, 0, stream>>>(P.x, item_emb, pos_seqs, pred_w, rpart);

    NormArgs na;
    int s = 0;
    na.e[s++] = {pos_emb, (SS + 1) * DDIM};
    na.e[s++] = {pred_w, DDIM};
    for (int l = 0; l < LL; ++l) {
        na.e[s++] = {ln_w + l * 64, 64};
        na.e[s++] = {ln_b + l * 64, 64};
        na.e[s++] = {qkv_w + (long)l * 12288, 12288};
        na.e[s++] = {qkv_b + (long)l * 192, 192};
        na.e[s++] = {out_w + (long)l * 4096, 4096};
        na.e[s++] = {out_b + l * 64, 64};
        na.e[s++] = {fc1_w + (long)l * 4096, 4096};
        na.e[s++] = {fc1_b + l * 64, 64};
        na.e[s++] = {ffln_w + l * 64, 64};
        na.e[s++] = {ffln_b + l * 64, 64};
        na.e[s++] = {fc2_w + (long)l * 4096, 4096};
        na.e[s++] = {fc2_b + l * 64, 64};
        na.e[s++] = {ffln2_w + l * 64, 64};
        na.e[s++] = {ffln2_b + l * 64, 64};
    }
    norms_kernel<<<30, 256, 0, stream>>>(na, nrm);

    final_kernel<<<1, 256, 0, stream>>>(EE, FF, pred_w, rpart, nrm, (float*)d_out);
}

// Round 16
// 317.395 us; speedup vs baseline: 2.8416x; 1.1550x over previous
//
#include <hip/hip_runtime.h>
#include <math.h>

#define BB 512
#define SS 200
#define DDIM 64
#define HD 32
#define LL 2
#define NROWS (BB * SS)   // 102400
#define EPS 1e-8f
#define CC 0.001f
#define GRAM_NB 512       // blocks PER INPUT; combined kernel launches 2*GRAM_NB
#define LSTRIDE 72

typedef __attribute__((ext_vector_type(8))) short bf16x8;
typedef __attribute__((ext_vector_type(4))) float f32x4;

// ---------------- static device buffers (activations) ----------------
__device__ float g_x[NROWS * DDIM];
__device__ unsigned short g_ctx[NROWS * DDIM];
__device__ unsigned short g_qb[NROWS * DDIM];
__device__ unsigned short g_kb[NROWS * DDIM];
__device__ unsigned short g_vb[NROWS * DDIM];
__device__ float g_gpart[2 * GRAM_NB * 4096];   // gram per-block partials (EE slabs then FF slabs)

// ---------------- helpers ----------------
__device__ __forceinline__ float wave_sum(float v) {
#pragma unroll
    for (int o = 32; o > 0; o >>= 1) v += __shfl_xor(v, o, 64);
    return v;
}
__device__ __forceinline__ unsigned short f2b(float f) {
    unsigned u = __float_as_uint(f);
    return (unsigned short)((u + 0x7FFFu + ((u >> 16) & 1u)) >> 16);
}
__device__ __forceinline__ float b2f(unsigned short u) {
    return __uint_as_float(((unsigned)u) << 16);
}

// ---------------- embedding (float4) ----------------
__global__ __launch_bounds__(256) void embed_kernel(const int* __restrict__ log_seqs,
                                                    const float* __restrict__ item_emb,
                                                    const float* __restrict__ pos_emb,
                                                    float* __restrict__ x) {
    int tid = blockIdx.x * 256 + threadIdx.x;   // over NROWS*16
    int row = tid >> 4, q4 = tid & 15;
    int s = row % SS;
    int li = log_seqs[row];
    int poss = li ? (s + 1) : 0;
    float4 e = *(const float4*)&item_emb[li * DDIM + q4 * 4];
    float4 p = *(const float4*)&pos_emb[poss * DDIM + q4 * 4];
    float4 o;
    o.x = e.x * 8.0f + p.x; o.y = e.y * 8.0f + p.y;
    o.z = e.z * 8.0f + p.z; o.w = e.w * 8.0f + p.w;
    *(float4*)&x[row * DDIM + q4 * 4] = o;
}

// ---------------- MFMA GEMM staging helpers (bf16 LDS, stride 72) ----------------
__device__ __forceinline__ void stage_bf16_tile(const float* __restrict__ G, unsigned short* __restrict__ L,
                                                int t, long row0) {
#pragma unroll
    for (int rep = 0; rep < 4; ++rep) {
        int idx = t + rep * 256;
        int r = idx >> 4, c4 = (idx & 15) * 4;
        float4 f = *(const float4*)&G[(row0 + r) * DDIM + c4];
        ushort4 o; o.x = f2b(f.x); o.y = f2b(f.y); o.z = f2b(f.z); o.w = f2b(f.w);
        *(ushort4*)&L[r * LSTRIDE + c4] = o;
    }
}

// copy a bf16 global tile into LDS (stride 72)
__device__ __forceinline__ void stage_bf16_copy(const unsigned short* __restrict__ G, unsigned short* __restrict__ L,
                                                int t, long row0) {
#pragma unroll
    for (int rep = 0; rep < 4; ++rep) {
        int idx = t + rep * 256;
        int r = idx >> 4, c4 = (idx & 15) * 4;
        *(ushort4*)&L[r * LSTRIDE + c4] = *(const ushort4*)&G[(row0 + r) * DDIM + c4];
    }
}

__device__ __forceinline__ void stage_w_bf16(const float* __restrict__ Wg, unsigned short* __restrict__ L, int t) {
#pragma unroll
    for (int rep = 0; rep < 4; ++rep) {
        int idx = t + rep * 256;
        int r = idx >> 4, c4 = (idx & 15) * 4;
        float4 f = *(const float4*)&Wg[r * DDIM + c4];
        ushort4 o; o.x = f2b(f.x); o.y = f2b(f.y); o.z = f2b(f.z); o.w = f2b(f.w);
        *(ushort4*)&L[r * LSTRIDE + c4] = o;
    }
}

// LN(x rows) -> bf16 LDS tile. thread t: row t>>2, 16-col chunk (t&3)*16.
__device__ __forceinline__ void stage_ln_bf16(const float* __restrict__ x, unsigned short* __restrict__ L,
                                              const float* __restrict__ lnw, const float* __restrict__ lnb,
                                              int t, long row0) {
    int rr = t >> 2, qd = (t & 3) * 16;
    float4 v[4];
#pragma unroll
    for (int g = 0; g < 4; ++g) v[g] = *(const float4*)&x[(row0 + rr) * DDIM + qd + g * 4];
    float s1 = 0.f, s2 = 0.f;
#pragma unroll
    for (int g = 0; g < 4; ++g) {
        s1 += (v[g].x + v[g].y) + (v[g].z + v[g].w);
        s2 += (v[g].x * v[g].x + v[g].y * v[g].y) + (v[g].z * v[g].z + v[g].w * v[g].w);
    }
    s1 += __shfl_xor(s1, 1, 64); s1 += __shfl_xor(s1, 2, 64);
    s2 += __shfl_xor(s2, 1, 64); s2 += __shfl_xor(s2, 2, 64);
    float m = s1 * (1.f / 64.f);
    float var = s2 * (1.f / 64.f) - m * m;
    float rs = rsqrtf(var + EPS);
#pragma unroll
    for (int g = 0; g < 4; ++g) {
        float4 w4 = *(const float4*)&lnw[qd + g * 4];
        float4 b4 = *(const float4*)&lnb[qd + g * 4];
        ushort4 o;
        o.x = f2b((v[g].x - m) * rs * w4.x + b4.x);
        o.y = f2b((v[g].y - m) * rs * w4.y + b4.y);
        o.z = f2b((v[g].z - m) * rs * w4.z + b4.z);
        o.w = f2b((v[g].w - m) * rs * w4.w + b4.w);
        *(ushort4*)&L[rr * LSTRIDE + qd + g * 4] = o;
    }
}

// 64x64x64 GEMM slice for wave w: out rows w16..w16+15, all 64 cols.
__device__ __forceinline__ void mfma_gemm(const unsigned short* __restrict__ A,
                                          const unsigned short* __restrict__ B,
                                          int w16, int m16, int quad, f32x4 acc[4]) {
    bf16x8 a0 = *(const bf16x8*)&A[(w16 + m16) * LSTRIDE + quad * 8];
    bf16x8 a1 = *(const bf16x8*)&A[(w16 + m16) * LSTRIDE + 32 + quad * 8];
#pragma unroll
    for (int nt = 0; nt < 4; ++nt) {
        bf16x8 b0 = *(const bf16x8*)&B[(nt * 16 + m16) * LSTRIDE + quad * 8];
        bf16x8 b1 = *(const bf16x8*)&B[(nt * 16 + m16) * LSTRIDE + 32 + quad * 8];
        acc[nt] = __builtin_amdgcn_mfma_f32_16x16x32_bf16(a0, b0, acc[nt], 0, 0, 0);
        acc[nt] = __builtin_amdgcn_mfma_f32_16x16x32_bf16(a1, b1, acc[nt], 0, 0, 0);
    }
}

// ---------------- fused QKV (MFMA) ----------------
__global__ __launch_bounds__(256) void qkv_fused(const float* __restrict__ x,
                                                 const float* __restrict__ Wqkv,
                                                 const float* __restrict__ Bqkv,
                                                 const float* __restrict__ lnw,
                                                 const float* __restrict__ lnb,
                                                 unsigned short* __restrict__ qo,
                                                 unsigned short* __restrict__ ko,
                                                 unsigned short* __restrict__ vo) {
    __shared__ unsigned short Ab[64 * LSTRIDE], Lb[64 * LSTRIDE];
    __shared__ unsigned short Wq[64 * LSTRIDE], Wk[64 * LSTRIDE], Wv[64 * LSTRIDE];
    int t = threadIdx.x;
    long row0 = (long)blockIdx.x * 64;
    stage_bf16_tile(x, Ab, t, row0);
    stage_ln_bf16(x, Lb, lnw, lnb, t, row0);
    stage_w_bf16(Wqkv, Wq, t);
    stage_w_bf16(Wqkv + 4096, Wk, t);
    stage_w_bf16(Wqkv + 8192, Wv, t);
    __syncthreads();
    int w16 = (t >> 6) * 16, lane = t & 63, m16 = lane & 15, quad = lane >> 4;
    f32x4 zero = {0.f, 0.f, 0.f, 0.f};
    {
        f32x4 acc[4] = {zero, zero, zero, zero};
        mfma_gemm(Lb, Wq, w16, m16, quad, acc);
#pragma unroll
        for (int nt = 0; nt < 4; ++nt) {
            int n = nt * 16 + m16;
            float bb = Bqkv[n];
#pragma unroll
            for (int rg = 0; rg < 4; ++rg)
                qo[(row0 + w16 + quad * 4 + rg) * DDIM + n] = f2b(acc[nt][rg] + bb);
        }
    }
    {
        f32x4 acc[4] = {zero, zero, zero, zero};
        mfma_gemm(Ab, Wk, w16, m16, quad, acc);
#pragma unroll
        for (int nt = 0; nt < 4; ++nt) {
            int n = nt * 16 + m16;
            float bb = Bqkv[64 + n];
#pragma unroll
            for (int rg = 0; rg < 4; ++rg)
                ko[(row0 + w16 + quad * 4 + rg) * DDIM + n] = f2b(acc[nt][rg] + bb);
        }
    }
    {
        f32x4 acc[4] = {zero, zero, zero, zero};
        mfma_gemm(Ab, Wv, w16, m16, quad, acc);
#pragma unroll
        for (int nt = 0; nt < 4; ++nt) {
            int n = nt * 16 + m16;
            float bb = Bqkv[128 + n];
#pragma unroll
            for (int rg = 0; rg < 4; ++rg)
                vo[(row0 + w16 + quad * 4 + rg) * DDIM + n] = f2b(acc[nt][rg] + bb);
        }
    }
}

// ---------------- fused out-proj + FFN (MFMA, wave-local chains) ----------------
__global__ __launch_bounds__(256) void ffn_fused(const unsigned short* __restrict__ ctx,
                                                 const float* __restrict__ x,
                                                 const float* __restrict__ Wo, const float* __restrict__ bo,
                                                 const float* __restrict__ W1, const float* __restrict__ b1,
                                                 const float* __restrict__ W2, const float* __restrict__ b2,
                                                 const float* __restrict__ l0w, const float* __restrict__ l0b,
                                                 const float* __restrict__ l1w, const float* __restrict__ l1b,
                                                 const float* __restrict__ l2w, const float* __restrict__ l2b,
                                                 float* __restrict__ xout) {
    __shared__ unsigned short Cb[64 * LSTRIDE], Qb[64 * LSTRIDE];
    __shared__ unsigned short W0s[64 * LSTRIDE], W1s[64 * LSTRIDE], W2s[64 * LSTRIDE];
    __shared__ float vecs[7][64];   // bo,b1,b2,l1w,l1b,l2w,l2b
    int t = threadIdx.x;
    long row0 = (long)blockIdx.x * 64;
    stage_bf16_copy(ctx, Cb, t, row0);
    stage_ln_bf16(x, Qb, l0w, l0b, t, row0);   // qin = LN(x; ln0), bf16
    stage_w_bf16(Wo, W0s, t);
    stage_w_bf16(W1, W1s, t);
    stage_w_bf16(W2, W2s, t);
    if (t < 64) {
        vecs[0][t] = bo[t]; vecs[1][t] = b1[t]; vecs[2][t] = b2[t];
        vecs[3][t] = l1w[t]; vecs[4][t] = l1b[t]; vecs[5][t] = l2w[t]; vecs[6][t] = l2b[t];
    }
    __syncthreads();
    int w16 = (t >> 6) * 16, lane = t & 63, m16 = lane & 15, quad = lane >> 4;
    f32x4 zero = {0.f, 0.f, 0.f, 0.f};
    f32x4 acc1[4] = {zero, zero, zero, zero};
    mfma_gemm(Cb, W0s, w16, m16, quad, acc1);
    float x1[4][4];
#pragma unroll
    for (int nt = 0; nt < 4; ++nt) {
        int n = nt * 16 + m16;
        float bb = vecs[0][n];
#pragma unroll
        for (int rg = 0; rg < 4; ++rg) {
            int m = w16 + quad * 4 + rg;
            x1[nt][rg] = acc1[nt][rg] + bb + b2f(Qb[m * LSTRIDE + n]);
        }
    }
    float ln1v[4][4], ln2v[4][4];
#pragma unroll
    for (int rg = 0; rg < 4; ++rg) {
        float s1 = (x1[0][rg] + x1[1][rg]) + (x1[2][rg] + x1[3][rg]);
        float s2 = x1[0][rg] * x1[0][rg] + x1[1][rg] * x1[1][rg]
                 + x1[2][rg] * x1[2][rg] + x1[3][rg] * x1[3][rg];
#pragma unroll
        for (int o = 1; o <= 8; o <<= 1) { s1 += __shfl_xor(s1, o, 64); s2 += __shfl_xor(s2, o, 64); }
        float mean = s1 * (1.f / 64.f);
        float var = s2 * (1.f / 64.f) - mean * mean;
        float rs = rsqrtf(var + EPS);
#pragma unroll
        for (int nt = 0; nt < 4; ++nt) {
            int n = nt * 16 + m16;
            float core = (x1[nt][rg] - mean) * rs;
            ln1v[nt][rg] = core * vecs[3][n] + vecs[4][n];
            ln2v[nt][rg] = core * vecs[5][n] + vecs[6][n];
        }
    }
    __builtin_amdgcn_wave_barrier();
#pragma unroll
    for (int nt = 0; nt < 4; ++nt)
#pragma unroll
        for (int rg = 0; rg < 4; ++rg)
            Cb[(w16 + quad * 4 + rg) * LSTRIDE + nt * 16 + m16] = f2b(ln1v[nt][rg]);
    __builtin_amdgcn_wave_barrier();
    f32x4 acc2[4] = {zero, zero, zero, zero};
    mfma_gemm(Cb, W1s, w16, m16, quad, acc2);
    __builtin_amdgcn_wave_barrier();
#pragma unroll
    for (int nt = 0; nt < 4; ++nt) {
        int n = nt * 16 + m16;
        float bb = vecs[1][n];
#pragma unroll
        for (int rg = 0; rg < 4; ++rg)
            Qb[(w16 + quad * 4 + rg) * LSTRIDE + n] = f2b(fmaxf(acc2[nt][rg] + bb, 0.f));
    }
    __builtin_amdgcn_wave_barrier();
    f32x4 acc3[4] = {zero, zero, zero, zero};
    mfma_gemm(Qb, W2s, w16, m16, quad, acc3);
#pragma unroll
    for (int nt = 0; nt < 4; ++nt) {
        int n = nt * 16 + m16;
        float bb = vecs[2][n];
#pragma unroll
        for (int rg = 0; rg < 4; ++rg) {
            int m = w16 + quad * 4 + rg;
            xout[(row0 + m) * DDIM + n] = acc3[nt][rg] + bb + ln2v[nt][rg];
        }
    }
}

// ---------------- MFMA flash attention, single-pass softmax ----------------
__global__ __launch_bounds__(256) void attn_kernel(const unsigned short* __restrict__ q,
                                                   const unsigned short* __restrict__ k,
                                                   const unsigned short* __restrict__ v,
                                                   unsigned short* __restrict__ ctx) {
    __shared__ unsigned short Kb[224 * 32];    // Kb[kk][d], zero for kk>=200
    __shared__ unsigned short Vt[32 * 232];    // Vt[d][kk], zero for kk>=200
    __shared__ unsigned short Ps[4][16 * 32];  // per-wave P buffer
    int b = blockIdx.x >> 1, h = blockIdx.x & 1;
    int t = threadIdx.x;
    const long base = (long)b * (SS * DDIM) + h * HD;
    for (int i = t; i < 224 * 4; i += 256) {   // 16B chunks (8 bf16)
        int kk = i >> 2, d8 = (i & 3) * 8;
        uint4 kv = make_uint4(0, 0, 0, 0), vv = make_uint4(0, 0, 0, 0);
        if (kk < SS) {
            kv = *(const uint4*)&k[base + kk * DDIM + d8];
            vv = *(const uint4*)&v[base + kk * DDIM + d8];
        }
        *(uint4*)&Kb[kk * 32 + d8] = kv;
        const unsigned short* vp = (const unsigned short*)&vv;
#pragma unroll
        for (int j = 0; j < 8; ++j) Vt[(d8 + j) * 232 + kk] = vp[j];
    }
    __syncthreads();
    int w = t >> 6, lane = t & 63;
    int m16 = lane & 15, quad = lane >> 4;
    const float scale = 0.17677669529663687f;   // 1/sqrt(32)
    unsigned short* ps = Ps[w];
    for (int qt = w; qt < 13; qt += 4) {
        int q0 = qt * 16;
        int qrow = q0 + m16; if (qrow > SS - 1) qrow = SS - 1;
        bf16x8 qa = *(const bf16x8*)&q[base + qrow * DDIM + quad * 8];
        f32x4 o0 = {0.f, 0.f, 0.f, 0.f}, o1 = {0.f, 0.f, 0.f, 0.f};
        f32x4 s0a[7], s1a[7];
        float vmax[4] = {-1e30f, -1e30f, -1e30f, -1e30f};
        int np = (qt + 2) >> 1;
        // pass 1: all QK scores into registers, local max only
#pragma unroll
        for (int pi = 0; pi < 7; ++pi) {
            if (pi < np) {
                int p0 = pi * 32;
                bf16x8 kb0 = *(bf16x8*)&Kb[(p0 + m16) * 32 + quad * 8];
                bf16x8 kb1 = *(bf16x8*)&Kb[(p0 + 16 + m16) * 32 + quad * 8];
                f32x4 z = {0.f, 0.f, 0.f, 0.f};
                f32x4 s0 = __builtin_amdgcn_mfma_f32_16x16x32_bf16(qa, kb0, z, 0, 0, 0);
                f32x4 s1 = __builtin_amdgcn_mfma_f32_16x16x32_bf16(qa, kb1, z, 0, 0, 0);
                int col0 = p0 + m16, col1 = col0 + 16;
#pragma unroll
                for (int rg = 0; rg < 4; ++rg) {
                    int rglob = q0 + quad * 4 + rg;
                    float v0 = (col0 <= rglob && col0 < SS) ? s0[rg] * scale : -1e30f;
                    float v1 = (col1 <= rglob && col1 < SS) ? s1[rg] * scale : -1e30f;
                    s0a[pi][rg] = v0; s1a[pi][rg] = v1;
                    vmax[rg] = fmaxf(vmax[rg], fmaxf(v0, v1));
                }
            }
        }
        // row max reduce (once)
#pragma unroll
        for (int rg = 0; rg < 4; ++rg)
#pragma unroll
            for (int o = 1; o <= 8; o <<= 1) vmax[rg] = fmaxf(vmax[rg], __shfl_xor(vmax[rg], o, 64));
        // pass 2: exp, local sum, P -> LDS, PV MFMAs
        float lsum[4] = {0.f, 0.f, 0.f, 0.f};
#pragma unroll
        for (int pi = 0; pi < 7; ++pi) {
            if (pi < np) {
                int p0 = pi * 32;
                float e0[4], e1[4];
#pragma unroll
                for (int rg = 0; rg < 4; ++rg) {
                    e0[rg] = __expf(s0a[pi][rg] - vmax[rg]);
                    e1[rg] = __expf(s1a[pi][rg] - vmax[rg]);
                    lsum[rg] += e0[rg] + e1[rg];
                }
                __builtin_amdgcn_wave_barrier();
#pragma unroll
                for (int rg = 0; rg < 4; ++rg) {
                    int row = quad * 4 + rg;
                    ps[row * 32 + m16] = f2b(e0[rg]);
                    ps[row * 32 + 16 + m16] = f2b(e1[rg]);
                }
                __builtin_amdgcn_wave_barrier();
                bf16x8 pa = *(bf16x8*)&ps[m16 * 32 + quad * 8];
                bf16x8 vb0 = *(bf16x8*)&Vt[m16 * 232 + p0 + quad * 8];
                bf16x8 vb1 = *(bf16x8*)&Vt[(m16 + 16) * 232 + p0 + quad * 8];
                o0 = __builtin_amdgcn_mfma_f32_16x16x32_bf16(pa, vb0, o0, 0, 0, 0);
                o1 = __builtin_amdgcn_mfma_f32_16x16x32_bf16(pa, vb1, o1, 0, 0, 0);
            }
        }
        // row sum reduce (once)
#pragma unroll
        for (int rg = 0; rg < 4; ++rg)
#pragma unroll
            for (int o = 1; o <= 8; o <<= 1) lsum[rg] += __shfl_xor(lsum[rg], o, 64);
#pragma unroll
        for (int rg = 0; rg < 4; ++rg) {
            int rglob = q0 + quad * 4 + rg;
            if (rglob < SS) {
                float inv = 1.f / lsum[rg];
                ctx[base + rglob * DDIM + m16] = f2b(o0[rg] * inv);
                ctx[base + rglob * DDIM + 16 + m16] = f2b(o1[rg] * inv);
            }
        }
    }
}

// ---------------- MFMA Gram (combined EE+FF): blocks 0..511 -> A0, 512..1023 -> A1 ----------------
__global__ __launch_bounds__(256) void gram_kernel(const float* __restrict__ A0, int n0,
                                                   const float* __restrict__ A1, int n1,
                                                   float* __restrict__ part) {
    __shared__ unsigned short At[64 * LSTRIDE];   // At[c][r]
    int t = threadIdx.x;
    const float* A; int nrows; int bid = blockIdx.x;
    if (bid < GRAM_NB) { A = A0; nrows = n0; } else { A = A1; nrows = n1; bid -= GRAM_NB; }
    int w16 = (t >> 6) * 16, lane = t & 63, m16 = lane & 15, quad = lane >> 4;
    int bi = t & 15, bj = t >> 4;   // bi: col-block of A, bj: row-block
    f32x4 zero = {0.f, 0.f, 0.f, 0.f};
    f32x4 acc[4] = {zero, zero, zero, zero};
    for (long base = (long)bid * 64; base < nrows; base += (long)GRAM_NB * 64) {
        __syncthreads();   // protect At reads from previous iteration
        float rv[4][4];
#pragma unroll
        for (int e = 0; e < 4; ++e) {
            long gr = base + bj * 4 + e;
            float4 f = make_float4(0.f, 0.f, 0.f, 0.f);
            if (gr < nrows) f = *(const float4*)&A[gr * DDIM + bi * 4];
            rv[e][0] = f.x; rv[e][1] = f.y; rv[e][2] = f.z; rv[e][3] = f.w;
        }
#pragma unroll
        for (int e = 0; e < 4; ++e) {
            ushort4 o;
            o.x = f2b(rv[0][e]); o.y = f2b(rv[1][e]); o.z = f2b(rv[2][e]); o.w = f2b(rv[3][e]);
            *(ushort4*)&At[(bi * 4 + e) * LSTRIDE + bj * 4] = o;
        }
        __syncthreads();
#pragma unroll
        for (int ks = 0; ks < 2; ++ks) {
            bf16x8 a = *(const bf16x8*)&At[(w16 + m16) * LSTRIDE + ks * 32 + quad * 8];
#pragma unroll
            for (int nt = 0; nt < 4; ++nt) {
                bf16x8 bfr = *(const bf16x8*)&At[(nt * 16 + m16) * LSTRIDE + ks * 32 + quad * 8];
                acc[nt] = __builtin_amdgcn_mfma_f32_16x16x32_bf16(a, bfr, acc[nt], 0, 0, 0);
            }
        }
    }
    float* slab = part + (long)blockIdx.x * 4096;
#pragma unroll
    for (int nt = 0; nt < 4; ++nt) {
        int n = nt * 16 + m16;
#pragma unroll
        for (int rg = 0; rg < 4; ++rg) {
            int m = w16 + quad * 4 + rg;
            slab[m * 64 + n] = acc[nt][rg];
        }
    }
}

// combined reduce: blocks 0..15 -> EE (slabs 0..511), 16..31 -> FF (slabs 512..1023)
__global__ __launch_bounds__(256) void gram_reduce(const float* __restrict__ part,
                                                   float* __restrict__ EE, float* __restrict__ FF) {
    int blk = blockIdx.x;
    int which = blk >> 4;
    int p = (blk & 15) * 256 + threadIdx.x;
    const float* basep = part + (long)which * GRAM_NB * 4096;
    float s = 0.f;
    for (int b = 0; b < GRAM_NB; ++b) s += basep[(long)b * 4096 + p];
    (which ? FF : EE)[p] = s;
}

// ---------------- right(): 4 rows in flight per wave, float4 lanes ----------------
__global__ __launch_bounds__(256) void right_kernel(const float* __restrict__ x,
                                                    const float* __restrict__ item_emb,
                                                    const int* __restrict__ pos_seqs,
                                                    const float* __restrict__ pred_w,
                                                    float* __restrict__ rpart) {
    __shared__ float p_s[64];
    __shared__ float red[4];
    int t = threadIdx.x;
    if (t < 64) p_s[t] = pred_w[t];
    __syncthreads();
    int w = t >> 6, lane = t & 63;
    int sub = lane >> 4, l16 = lane & 15;
    float4 p4 = *(const float4*)&p_s[l16 * 4];
    float local = 0.f;
    for (long row0 = (long)blockIdx.x * 16 + w * 4; row0 < NROWS; row0 += (long)gridDim.x * 16) {
        long row = row0 + sub;
        float val = 0.f;
        if (row < NROWS) {
            int pi = pos_seqs[row];
            float4 xv = *(const float4*)&x[row * DDIM + l16 * 4];
            float4 iv = *(const float4*)&item_emb[(long)pi * DDIM + l16 * 4];
            val = xv.x * iv.x * p4.x + xv.y * iv.y * p4.y + xv.z * iv.z * p4.z + xv.w * iv.w * p4.w;
        }
#pragma unroll
        for (int o = 1; o <= 8; o <<= 1) val += __shfl_xor(val, o, 64);
        // val = ps for this row (uniform within 16-lane cluster)
        if (row < NROWS) local += (1.0f - CC) * val * val - 2.0f * val;
    }
    float contrib = (l16 == 0) ? local : 0.f;
    contrib = wave_sum(contrib);            // sums the 4 clusters
    if (lane == 0) red[w] = contrib;
    __syncthreads();
    if (t == 0) rpart[blockIdx.x] = red[0] + red[1] + red[2] + red[3];
}

// ---------------- per-parameter sum-of-squares ----------------
struct NormEntry { const float* p; int n; };
struct NormArgs { NormEntry e[30]; };

__global__ __launch_bounds__(256) void norms_kernel(NormArgs args, float* __restrict__ norms) {
    __shared__ float red[256];
    NormEntry en = args.e[blockIdx.x];
    float s = 0.f;
    for (int i = threadIdx.x; i < en.n; i += 256) { float v = en.p[i]; s += v * v; }
    red[threadIdx.x] = s;
    for (int o = 128; o > 0; o >>= 1) {
        __syncthreads();
        if (threadIdx.x < o) red[threadIdx.x] += red[threadIdx.x + o];
    }
    __syncthreads();
    if (threadIdx.x == 0) norms[blockIdx.x] = red[0];
}

// ---------------- final scalar ----------------
__global__ __launch_bounds__(256) void final_kernel(const float* __restrict__ EE,
                                                    const float* __restrict__ FF,
                                                    const float* __restrict__ pred_w,
                                                    const float* __restrict__ rpart,
                                                    const float* __restrict__ norms,
                                                    float* __restrict__ out) {
    __shared__ float p_s[64];
    __shared__ float redL[256];
    __shared__ float redT[256];
    __shared__ float redR[256];
    int t = threadIdx.x;
    if (t < 64) p_s[t] = pred_w[t];
    __syncthreads();
    float lf = 0.f, tr = 0.f, rs = 0.f;
    for (int p = t; p < 4096; p += 256) {
        int i = p >> 6, j = p & 63;
        float ee = EE[p];
        lf += FF[p] * ee * p_s[i] * p_s[j];
        if (i == j) tr += ee;
    }
    for (int i = t; i < 1024; i += 256) rs += rpart[i];
    redL[t] = lf; redT[t] = tr; redR[t] = rs;
    for (int o = 128; o > 0; o >>= 1) {
        __syncthreads();
        if (t < o) { redL[t] += redL[t + o]; redT[t] += redT[t + o]; redR[t] += redR[t + o]; }
    }
    __syncthreads();
    if (t == 0) {
        float reg = sqrtf(redT[0]);   // ||item_emb||_F = sqrt(trace(EE))
        for (int s = 0; s < 30; ++s) reg += sqrtf(norms[s]);
        out[0] = CC * redL[0] + redR[0] + 0.1f * reg;
    }
}

// ---------------- host ----------------
struct DevPtrs { float *x, *gpart; unsigned short *ctx, *qb, *kb, *vb; };

static DevPtrs fetch_ptrs() {
    DevPtrs p;
    (void)hipGetSymbolAddress((void**)&p.x,    HIP_SYMBOL(g_x));
    (void)hipGetSymbolAddress((void**)&p.ctx,  HIP_SYMBOL(g_ctx));
    (void)hipGetSymbolAddress((void**)&p.gpart,HIP_SYMBOL(g_gpart));
    (void)hipGetSymbolAddress((void**)&p.qb,   HIP_SYMBOL(g_qb));
    (void)hipGetSymbolAddress((void**)&p.kb,   HIP_SYMBOL(g_kb));
    (void)hipGetSymbolAddress((void**)&p.vb,   HIP_SYMBOL(g_vb));
    return p;
}

extern "C" void kernel_launch(void* const* d_in, const int* in_sizes, int n_in,
                              void* d_out, int out_size, void* d_ws, size_t ws_size,
                              hipStream_t stream) {
    const int*   log_seqs = (const int*)d_in[1];
    const int*   pos_seqs = (const int*)d_in[2];
    const float* item_emb = (const float*)d_in[3];
    const float* pos_emb  = (const float*)d_in[4];
    const float* pred_w   = (const float*)d_in[5];
    const float* ln_w     = (const float*)d_in[6];
    const float* ln_b     = (const float*)d_in[7];
    const float* qkv_w    = (const float*)d_in[8];
    const float* qkv_b    = (const float*)d_in[9];
    const float* out_w    = (const float*)d_in[10];
    const float* out_b    = (const float*)d_in[11];
    const float* fc1_w    = (const float*)d_in[12];
    const float* fc1_b    = (const float*)d_in[13];
    const float* ffln_w   = (const float*)d_in[14];
    const float* ffln_b   = (const float*)d_in[15];
    const float* fc2_w    = (const float*)d_in[16];
    const float* fc2_b    = (const float*)d_in[17];
    const float* ffln2_w  = (const float*)d_in[18];
    const float* ffln2_b  = (const float*)d_in[19];

    static DevPtrs P = fetch_ptrs();   // first call is the uncaptured correctness call

    float* ws    = (float*)d_ws;
    float* rpart = ws;            // 1024
    float* nrm   = ws + 1024;     // 30
    float* EE    = ws + 2048;     // 4096
    float* FF    = ws + 6144;     // 4096

    embed_kernel<<<NROWS * 16 / 256, 256, 0, stream>>>(log_seqs, item_emb, pos_emb, P.x);

    const int GEMM_GRID = NROWS / 64;   // 1600

    for (int l = 0; l < LL; ++l) {
        const float* Wqkv = qkv_w + (long)l * 3 * 64 * 64;
        const float* Bqkv = qkv_b + (long)l * 192;
        qkv_fused<<<GEMM_GRID, 256, 0, stream>>>(
            P.x, Wqkv, Bqkv, ln_w + l * 64, ln_b + l * 64, P.qb, P.kb, P.vb);
        attn_kernel<<<BB * 2, 256, 0, stream>>>(P.qb, P.kb, P.vb, P.ctx);
        ffn_fused<<<GEMM_GRID, 256, 0, stream>>>(
            P.ctx, P.x,
            out_w + (long)l * 4096, out_b + l * 64,
            fc1_w + (long)l * 4096, fc1_b + l * 64,
            fc2_w + (long)l * 4096, fc2_b + l * 64,
            ln_w + l * 64, ln_b + l * 64,
            ffln_w + l * 64, ffln_b + l * 64,
            ffln2_w + l * 64, ffln2_b + l * 64,
            P.x);
    }

    gram_kernel<<<2 * GRAM_NB, 256, 0, stream>>>(item_emb, 100001, P.x, NROWS, P.gpart);
    gram_reduce<<<32, 256, 0, stream>>>(P.gpart, EE, FF);
    right_kernel<<<1024, 256, 0, stream>>>(P.x, item_emb, pos_seqs, pred_w, rpart);

    NormArgs na;
    int s = 0;
    na.e[s++] = {pos_emb, (SS + 1) * DDIM};
    na.e[s++] = {pred_w, DDIM};
    for (int l = 0; l < LL; ++l) {
        na.e[s++] = {ln_w + l * 64, 64};
        na.e[s++] = {ln_b + l * 64, 64};
        na.e[s++] = {qkv_w + (long)l * 12288, 12288};
        na.e[s++] = {qkv_b + (long)l * 192, 192};
        na.e[s++] = {out_w + (long)l * 4096, 4096};
        na.e[s++] = {out_b + l * 64, 64};
        na.e[s++] = {fc1_w + (long)l * 4096, 4096};
        na.e[s++] = {fc1_b + l * 64, 64};
        na.e[s++] = {ffln_w + l * 64, 64};
        na.e[s++] = {ffln_b + l * 64, 64};
        na.e[s++] = {fc2_w + (long)l * 4096, 4096};
        na.e[s++] = {fc2_b + l * 64, 64};
        na.e[s++] = {ffln2_w + l * 64, 64};
        na.e[s++] = {ffln2_b + l * 64, 64};
    }
    norms_kernel<<<30, 256, 0, stream>>>(na, nrm);

    final_kernel<<<1, 256, 0, stream>>>(EE, FF, pred_w, rpart, nrm, (float*)d_out);
}